// Round 5
// baseline (798.226 us; speedup 1.0000x reference)
//
#include <hip/hip_runtime.h>
#include <math.h>

#define BB 256
#define LL 20
#define HH 128
#define NH 8
#define D2C 64
#define NTY 4
#define NRL 4
#define CHILDN 30001
#define PARENTN 500
#define N1SN 50000
#define N1DN 20000
#define E1N 300000
#define N2N 20000
#define E2N 200000
#define TT (BB*LL)
#define N4DN 5000
#define E4N 150000
#define EC2PN 8000
#define TDSTRIDE 2304

typedef __attribute__((ext_vector_type(8))) short bfrag;   // 8 bf16 in 4 VGPRs
typedef __attribute__((ext_vector_type(4))) float ffrag;   // MFMA accumulator

__device__ __forceinline__ unsigned fenc(float f){ unsigned u=__float_as_uint(f); return (u&0x80000000u)? ~u : (u|0x80000000u); }
__device__ __forceinline__ float fdec(unsigned u){ return (u&0x80000000u)? __uint_as_float(u^0x80000000u) : __uint_as_float(~u); }
__device__ __forceinline__ float sigfast(float x){ return 1.f/(1.f+__expf(-x)); }
__device__ __forceinline__ float tanhfast(float x){ float e = __expf(-2.f*x); return (1.f-e)/(1.f+e); }
__device__ __forceinline__ short f2bf(float f){
  unsigned u = __float_as_uint(f);
  unsigned r = u + 0x7FFFu + ((u>>16)&1u);   // round-to-nearest-even
  return (short)(r>>16);
}

// ---------------- upfront init: all zero/poison buffers in one launch ----------------
__global__ void k_init(float* hist2, float* cnt, unsigned* amax, float* aden,
                       float* psum, float* pcnt, int* cntall,
                       int* icnt1, int* icnt2, int* icnt3){
  int i = blockIdx.x*256 + threadIdx.x;
  if(i < CHILDN*HH) hist2[i] = 0.f;
  if(i < CHILDN){ cnt[i] = 0.f; aden[i] = 0.f; amax[i] = 0x007FFFFFu; }
  if(i < PARENTN*HH) psum[i] = 0.f;
  if(i < PARENTN) pcnt[i] = 0.f;
  if(i < 5*NTY) cntall[i] = 0;
  if(i < N1DN) icnt1[i] = 0;
  if(i < TT)   icnt2[i] = 0;
  if(i < N4DN) icnt3[i] = 0;
}

// sin(dia_w + dia_b) per child node, cols 64..127 — shared by all 4 convs
__global__ void k_sindia(const float* __restrict__ dia_w, const float* __restrict__ dia_b,
                         float* __restrict__ sdia){
  int i = blockIdx.x*256 + threadIdx.x;
  if(i >= CHILDN*64) return;
  int c = i >> 6, k = (i & 63) + 64;
  sdia[i] = __sinf(dia_w[(size_t)c*HH+k] + dia_b[(size_t)c*HH+k]);
}

// ---------------- Stage A: feature expansion (tiled: 32 tokens/block) ----------------
__global__ __launch_bounds__(512) void k_featx2(const int* __restrict__ seq, const int* __restrict__ dur,
                        const int* __restrict__ stime, const int* __restrict__ etime,
                        const float* __restrict__ emb, const float* __restrict__ dia_w, const float* __restrict__ dia_b,
                        const float* __restrict__ t2v_w, const float* __restrict__ t2v_b,
                        const float* __restrict__ exp_W, const float* __restrict__ exp_b, float* __restrict__ xout){
  __shared__ float feat[32*273];           // [st(128) | et(128) | tv(16)] per token, stride 273
  int base = blockIdx.x*32;
  int j = threadIdx.x >> 4;                // token 0..31
  int p = threadIdx.x & 15;                // 16 threads/token, 8 cols each
  int row = base + j;
  int node = seq[row];
  float ts = (float)stime[row], te = (float)etime[row];
  const float* ep = emb + (size_t)node*HH;
  float* fr = feat + j*273;
  int o0 = p*8;
  #pragma unroll
  for(int ii=0; ii<8; ii+=4){
    int o = o0 + ii;
    float4 e = *(const float4*)(ep + o);
    float4 st = e, et = e;
    if(o >= D2C){
      float4 w = *(const float4*)(dia_w + (size_t)node*HH + o);
      float4 b = *(const float4*)(dia_b + (size_t)node*HH + o);
      st.x = e.x*__sinf(w.x*ts+b.x); st.y = e.y*__sinf(w.y*ts+b.y);
      st.z = e.z*__sinf(w.z*ts+b.z); st.w = e.w*__sinf(w.w*ts+b.w);
      et.x = e.x*__sinf(w.x*te+b.x); et.y = e.y*__sinf(w.y*te+b.y);
      et.z = e.z*__sinf(w.z*te+b.z); et.w = e.w*__sinf(w.w*te+b.w);
    }
    fr[o] = st.x; fr[o+1] = st.y; fr[o+2] = st.z; fr[o+3] = st.w;
    fr[128+o] = et.x; fr[128+o+1] = et.y; fr[128+o+2] = et.z; fr[128+o+3] = et.w;
  }
  if(p == 0){
    float td = (float)dur[row];
    #pragma unroll
    for(int i=0;i<16;i++){
      float w = t2v_w[i], b = t2v_b[i];
      fr[256+i] = (i==0) ? (w*td + b) : __sinf(w*td + b);
    }
  }
  __syncthreads();
  // GEMM: 32x272 @ 272x128, each thread: 2 rows x 4 cols
  int oc = (threadIdx.x & 31)*4;
  int jg = threadIdx.x >> 5;               // 0..15
  const float* f0 = feat + (jg*2)*273;
  const float* f1 = feat + (jg*2+1)*273;
  float4 a0 = {0,0,0,0}, a1 = {0,0,0,0};
  for(int k=0;k<272;k++){
    float4 w = *(const float4*)(exp_W + (size_t)k*HH + oc);
    float x0 = f0[k], x1 = f1[k];
    a0.x += x0*w.x; a0.y += x0*w.y; a0.z += x0*w.z; a0.w += x0*w.w;
    a1.x += x1*w.x; a1.y += x1*w.y; a1.z += x1*w.z; a1.w += x1*w.w;
  }
  float4 bv = *(const float4*)(exp_b + oc);
  a0.x = fmaxf(a0.x+bv.x, 0.f); a0.y = fmaxf(a0.y+bv.y, 0.f);
  a0.z = fmaxf(a0.z+bv.z, 0.f); a0.w = fmaxf(a0.w+bv.w, 0.f);
  a1.x = fmaxf(a1.x+bv.x, 0.f); a1.y = fmaxf(a1.y+bv.y, 0.f);
  a1.z = fmaxf(a1.z+bv.z, 0.f); a1.w = fmaxf(a1.w+bv.w, 0.f);
  *(float4*)(xout + (size_t)(base + jg*2  )*HH + oc) = a0;
  *(float4*)(xout + (size_t)(base + jg*2+1)*HH + oc) = a1;
}

// tiled x @ Wi + b -> gpre: 16 rows x 512 cols per block; perm=1 reads x in (l*BB+b) layout
__global__ void k_xwi2(const float* x, const float* Wi, const float* bias, float* gpre, int rows, int perm){
  int base = blockIdx.x*16;
  __shared__ float xs[128*17];
  int tid = threadIdx.x;
  #pragma unroll
  for(int s=0;s<8;s++){
    int elem = tid + 256*s;
    int k = elem & 127, j = elem >> 7;
    int r = base + j;
    int src = r;
    if(perm) src = (r % LL)*BB + (r / LL);
    xs[k*17 + j] = (r < rows) ? x[(size_t)src*HH + k] : 0.f;
  }
  __syncthreads();
  int o4 = (tid & 127)*4;
  int ng = tid >> 7;
  float4 a[8];
  #pragma unroll
  for(int j=0;j<8;j++) a[j]=make_float4(0,0,0,0);
  for(int k=0;k<HH;k++){
    float4 w = *(const float4*)(Wi + (size_t)k*512 + o4);
    const float* xr = xs + k*17 + ng*8;
    #pragma unroll
    for(int j=0;j<8;j++){
      float xv = xr[j];
      a[j].x += xv*w.x; a[j].y += xv*w.y; a[j].z += xv*w.z; a[j].w += xv*w.w;
    }
  }
  float4 bv = *(const float4*)(bias + o4);
  #pragma unroll
  for(int j=0;j<8;j++){
    int r = base + ng*8 + j;
    if(r < rows){
      float4 v = a[j];
      v.x += bv.x; v.y += bv.y; v.z += bv.z; v.w += bv.w;
      *(float4*)(gpre + (size_t)r*512 + o4) = v;
    }
  }
}

// fused 20-step LSTM: one block per batch row, Wh column in registers, gpre
// prefetched into registers, activations spread across all 512 threads.
__global__ __launch_bounds__(512, 2) void k_lstm_fused(const float* __restrict__ gpre,
                                                       const float* __restrict__ Wh,
                                                       float* __restrict__ hout,
                                                       float* __restrict__ hout2){
  int b = blockIdx.x;
  int o = threadIdx.x;
  __shared__ float hs[HH];
  __shared__ float act[512];
  float wr[HH];
  #pragma unroll
  for(int h=0;h<HH;h++) wr[h] = Wh[(size_t)h*512 + o];
  float gv[LL];
  const float* gp = gpre + (size_t)b*LL*512 + o;
  #pragma unroll
  for(int l=0;l<LL;l++) gv[l] = gp[(size_t)l*512];
  if(o < HH) hs[o] = 0.f;
  float cc = 0.f;
  int quad = o >> 7;                        // 0=i, 1=f, 2=g, 3=o
  __syncthreads();
  for(int l=0;l<LL;l++){
    float a0=0.f,a1=0.f,a2=0.f,a3=0.f;
    #pragma unroll
    for(int h=0;h<HH;h+=4){
      float4 hv = *(const float4*)&hs[h];
      a0 += hv.x*wr[h];   a1 += hv.y*wr[h+1];
      a2 += hv.z*wr[h+2]; a3 += hv.w*wr[h+3];
    }
    float g = gv[l] + ((a0+a1)+(a2+a3));
    act[o] = (quad==2) ? tanhfast(g) : sigfast(g);
    __syncthreads();
    if(o < HH){
      cc = act[HH+o]*cc + act[o]*act[2*HH+o];
      float hh = act[3*HH+o]*tanhfast(cc);
      hs[o] = hh;
      size_t bi = ((size_t)b*LL + l)*HH + o;
      hout[bi] = hh;
      if(hout2) hout2[bi] = hh;
    }
    __syncthreads();
  }
}

// ---------------- token prep + type scatter (merged) ----------------
__global__ void k_tokprep(const int* __restrict__ seq, const int* __restrict__ seq_nt,
                          int* __restrict__ tokid, int* __restrict__ toknt,
                          int* __restrict__ cnts, int* __restrict__ idxb){
  __shared__ int h[NTY];
  __shared__ int bs[NTY];
  int i = blockIdx.x*256 + threadIdx.x;
  if(threadIdx.x < NTY) h[threadIdx.x] = 0;
  __syncthreads();
  int nt = 0, r = 0;
  bool act = (i < TT);
  if(act){
    int b = i % BB, l = i / BB;
    tokid[i] = seq[b*LL+l];
    nt = seq_nt[b*LL+l];
    toknt[i] = nt;
    r = atomicAdd(&h[nt], 1);
  }
  __syncthreads();
  if(threadIdx.x < NTY && h[threadIdx.x] > 0)
    bs[threadIdx.x] = atomicAdd(&cnts[threadIdx.x], h[threadIdx.x]);
  __syncthreads();
  if(act) idxb[nt*TT + bs[nt] + r] = i;
}

// conv2 src prep + type scatter (merged)
__global__ void k_prep2scat(const int* __restrict__ sel, const int* __restrict__ g1_nid,
                            const int* __restrict__ g1_nt, int* __restrict__ gnid2,
                            int* __restrict__ cnts, int* __restrict__ idxb){
  __shared__ int h[NTY];
  __shared__ int bs[NTY];
  int i = blockIdx.x*256 + threadIdx.x;
  if(threadIdx.x < NTY) h[threadIdx.x] = 0;
  __syncthreads();
  int nt = 0, r = 0;
  bool act = (i < N2N);
  if(act){
    int s = sel[i];
    gnid2[i] = g1_nid[s];
    nt = g1_nt[s];
    r = atomicAdd(&h[nt], 1);
  }
  __syncthreads();
  if(threadIdx.x < NTY && h[threadIdx.x] > 0)
    bs[threadIdx.x] = atomicAdd(&cnts[threadIdx.x], h[threadIdx.x]);
  __syncthreads();
  if(act) idxb[nt*N2N + bs[nt] + r] = i;
}

__global__ void k_dst2(const int* tok_sel, const float* xg, const float* h1, float* dst2){
  int t = blockIdx.x; int o = threadIdx.x;
  int b = t % BB, l = t / BB;
  dst2[t*HH+o] = xg[tok_sel[t]*HH+o] + h1[(b*LL+l)*HH+o];
}

__global__ void k_x0(const int* nid, const int* ntype, const float* emb, const float* hist2,
                     const float* skip, float* srcbuf){
  int i = blockIdx.x; int o = threadIdx.x;
  float a = sigfast(skip[ntype[i]]);
  int nd = nid[i];
  srcbuf[i*HH+o] = emb[nd*HH+o]*a + hist2[nd*HH+o]*(1.f-a);
}

// 3-way type scatter of g1_nt for prefixes N1SN / N1DN / N4DN in one pass
__global__ void k_scatter3(const int* __restrict__ types,
                           int* cnts1, int* idx1, int* cnts2, int* idx2, int* cnts3, int* idx3){
  __shared__ int h[3][NTY];
  __shared__ int bs[3][NTY];
  int i = blockIdx.x*256 + threadIdx.x;
  if(threadIdx.x < 3*NTY) (&h[0][0])[threadIdx.x] = 0;
  __syncthreads();
  int t = 0, r1 = 0, r2 = 0, r3 = 0;
  bool a1 = (i < N1SN), a2 = (i < N1DN), a3 = (i < N4DN);
  if(a1){
    t = types[i];
    r1 = atomicAdd(&h[0][t], 1);
    if(a2) r2 = atomicAdd(&h[1][t], 1);
    if(a3) r3 = atomicAdd(&h[2][t], 1);
  }
  __syncthreads();
  if(threadIdx.x < NTY){
    int ty = threadIdx.x;
    if(h[0][ty] > 0) bs[0][ty] = atomicAdd(&cnts1[ty], h[0][ty]);
    if(h[1][ty] > 0) bs[1][ty] = atomicAdd(&cnts2[ty], h[1][ty]);
    if(h[2][ty] > 0) bs[2][ty] = atomicAdd(&cnts3[ty], h[2][ty]);
  }
  __syncthreads();
  if(a1) idx1[t*N1SN + bs[0][t] + r1] = i;
  if(a2) idx2[t*N1DN + bs[1][t] + r2] = i;
  if(a3) idx3[t*N4DN + bs[2][t] + r3] = i;
}

// ---- tile-descriptor builder: compacted work lists for the 3 unique conv configs.
// cfg0 (conv1/conv3): src=grp0 (N1SN), dst=grp1 (N1DN)
// cfg1 (conv2):       src=grp2 (N2N),  dst=grp3 (TT)
// cfg2 (conv4):       src=grp1 (N1DN), dst=grp4 (N4DN)
// desc = (z<<31)|(t<<28)|rowbase ; tcnt[cfg*2+{0,1}] = {#kv tiles, #q tiles}
__global__ void k_mktiles(const int* __restrict__ cntall, int* __restrict__ tdesc, int* __restrict__ tcnt){
  __shared__ int start[3][2][NTY];
  if(threadIdx.x == 0){
    const int srcg[3] = {0,2,1};
    const int dstg[3] = {1,3,4};
    for(int c=0;c<3;c++){
      int acc = 0;
      for(int z=0;z<2;z++){
        int g = (z==0) ? srcg[c] : dstg[c];
        int zacc = 0;
        for(int t=0;t<NTY;t++){
          start[c][z][t] = acc;
          int tiles = (cntall[g*NTY+t]+31)>>5;
          acc += tiles; zacc += tiles;
        }
        tcnt[c*2+z] = zacc;
      }
    }
  }
  __syncthreads();
  const int srcg[3] = {0,2,1};
  const int dstg[3] = {1,3,4};
  for(int c=0;c<3;c++){
    for(int z=0;z<2;z++){
      int g = (z==0) ? srcg[c] : dstg[c];
      for(int t=0;t<NTY;t++){
        int tiles = (cntall[g*NTY+t]+31)>>5;
        for(int i=threadIdx.x; i<tiles; i+=blockDim.x)
          tdesc[c*TDSTRIDE + start[c][z][t] + i] = (int)(((unsigned)z<<31) | ((unsigned)t<<28) | (unsigned)(i<<5));
      }
    }
  }
}

// ---- weight prepack: fp32 -> bf16 + MFMA B-fragment swizzle.
__global__ void k_prepack(const float* convK, const float* convV, const float* convQ,
                          const float* convO, short* Wsw){
  int m = blockIdx.x;          // 0..63
  int fam = m >> 4;
  int lt = m & 15;             // layer*4 + type
  const float* src = (fam==0?convK:fam==1?convV:fam==2?convQ:convO) + (size_t)lt*HH*HH;
  short* dst = Wsw + (size_t)m*16384;
  for(int s=0;s<64;s++){
    int i = threadIdx.x + 256*s;
    int j = i & 7, lane = (i>>3)&63, kc = (i>>9)&3, nt = i>>11;
    int k = kc*32 + (lane>>4)*8 + j;
    int n = nt*16 + (lane&15);
    dst[i] = f2bf(src[k*HH+n]);
  }
}

// ---- fused KV + Q projection via MFMA; compacted 1-D tile list, float4 staging,
// warp-level LN reduce, fused sdia time-mod. One dispatch per conv.
__global__ __launch_bounds__(256) void k_gemm_kvq(
    const int* __restrict__ tdesc, const int* __restrict__ tcnt,
    const float* __restrict__ Xs, const int* __restrict__ src_nid, const int* __restrict__ smap,
    const float* __restrict__ sdia,
    const int* __restrict__ idxs, const int* __restrict__ cnts_s, int stride_s,
    const bfrag* __restrict__ WK, const bfrag* __restrict__ WV, unsigned* __restrict__ KVp,
    const float* __restrict__ Xq, const int* __restrict__ qmap,
    const int* __restrict__ idxd, const int* __restrict__ cnts_d, int stride_d,
    const bfrag* __restrict__ WQ, float* __restrict__ Qbuf){
  __shared__ float xs[32*132];
  __shared__ float mean_s[32], inv_s[32];
  __shared__ int sid[32], nid[32], xrow[32];
  int ntk = tcnt[0], ntq = tcnt[1];
  int bid = blockIdx.x;
  if(bid >= ntk + ntq) return;
  unsigned ud = (unsigned)tdesc[bid];
  int isQ = ud >> 31;
  int t = (ud >> 28) & 7;
  int base = ud & 0x0FFFFFFF;
  int tid = threadIdx.x;
  int cnt = isQ ? cnts_d[t] : cnts_s[t];
  if(base >= cnt) return;
  int nn = min(32, cnt - base);
  const float* X = isQ ? Xq : Xs;
  const int* map = isQ ? qmap : smap;
  const int* ids = (isQ ? idxd + (size_t)t*stride_d : idxs + (size_t)t*stride_s) + base;
  if(tid < 32){
    int s_ = (tid < nn) ? ids[tid] : ids[0];
    sid[tid] = s_;
    if(!isQ) nid[tid] = src_nid[s_];
    xrow[tid] = map ? map[s_] : s_;
  }
  __syncthreads();
  // float4 staging: 1024 float4 = 32 rows x 128 cols
  #pragma unroll
  for(int s=0;s<4;s++){
    int e4 = tid + 256*s;
    int j = e4 >> 5, c4 = (e4 & 31)*4;
    *(float4*)&xs[j*132 + c4] = *(const float4*)&X[(size_t)xrow[j]*HH + c4];
  }
  __syncthreads();
  // warp-level LN reduce: 8 lanes per row, shfl_xor over p
  {
    int wid = tid >> 6, lane = tid & 63;
    int row = wid*8 + (lane>>3), p = lane & 7;
    const float* xr = xs + row*132 + p*16;
    float sm=0.f, sq=0.f;
    #pragma unroll
    for(int i=0;i<16;i++){ float v = xr[i]; sm += v; sq += v*v; }
    sm += __shfl_xor(sm, 1, 64); sq += __shfl_xor(sq, 1, 64);
    sm += __shfl_xor(sm, 2, 64); sq += __shfl_xor(sq, 2, 64);
    sm += __shfl_xor(sm, 4, 64); sq += __shfl_xor(sq, 4, 64);
    if(p == 0){
      float mean = sm*(1.f/128.f);
      float var = sq*(1.f/128.f) - mean*mean;
      mean_s[row] = mean;
      inv_s[row] = 1.f/sqrtf(fmaxf(var,0.f)+1e-5f);
    }
  }
  __syncthreads();
  if(!isQ){
    #pragma unroll
    for(int s=0;s<16;s++){
      int elem = tid + 256*s;
      int k = elem & 127, j = elem >> 7;
      float v = (xs[j*132+k] - mean_s[j]) * inv_s[j];
      if(k >= D2C) v *= sdia[(size_t)nid[j]*64 + (k - D2C)];
      xs[j*132+k] = v;
    }
  } else {
    #pragma unroll
    for(int s=0;s<16;s++){
      int elem = tid + 256*s;
      int k = elem & 127, j = elem >> 7;
      xs[j*132+k] = (xs[j*132+k] - mean_s[j]) * inv_s[j];
    }
  }
  __syncthreads();
  int lane = tid & 63, w = tid >> 6;
  int mt = w & 1, ng0 = (w>>1)*4;
  int arow = mt*16 + (lane & 15);
  int koff = (lane >> 4)*8;
  int tb = t*2048;
  if(!isQ){
    ffrag aK[4], aV[4];
    #pragma unroll
    for(int i=0;i<4;i++){ aK[i] = (ffrag){0.f,0.f,0.f,0.f}; aV[i] = (ffrag){0.f,0.f,0.f,0.f}; }
    #pragma unroll
    for(int kc=0;kc<4;kc++){
      const float* ap = xs + arow*132 + kc*32 + koff;
      bfrag a;
      #pragma unroll
      for(int j=0;j<8;j++) a[j] = f2bf(ap[j]);
      #pragma unroll
      for(int nt=0;nt<4;nt++){
        int fi = tb + ((ng0+nt)*4 + kc)*64 + lane;
        bfrag bk = WK[fi];
        bfrag bv = WV[fi];
        aK[nt] = __builtin_amdgcn_mfma_f32_16x16x32_bf16(a, bk, aK[nt], 0, 0, 0);
        aV[nt] = __builtin_amdgcn_mfma_f32_16x16x32_bf16(a, bv, aV[nt], 0, 0, 0);
      }
    }
    int col0 = lane & 15;
    int rb = mt*16 + (lane>>4)*4;
    #pragma unroll
    for(int nt=0;nt<4;nt++){
      int col = (ng0+nt)*16 + col0;
      #pragma unroll
      for(int i=0;i<4;i++){
        int n = rb + i;
        if(n < nn){
          unsigned pk = (unsigned short)f2bf(aK[nt][i]);
          unsigned pv = (unsigned short)f2bf(aV[nt][i]);
          KVp[(size_t)sid[n]*HH + col] = (pv<<16) | pk;
        }
      }
    }
  } else {
    ffrag acc[4];
    #pragma unroll
    for(int i=0;i<4;i++) acc[i] = (ffrag){0.f,0.f,0.f,0.f};
    #pragma unroll
    for(int kc=0;kc<4;kc++){
      const float* ap = xs + arow*132 + kc*32 + koff;
      bfrag a;
      #pragma unroll
      for(int j=0;j<8;j++) a[j] = f2bf(ap[j]);
      #pragma unroll
      for(int nt=0;nt<4;nt++){
        bfrag b = WQ[tb + ((ng0+nt)*4 + kc)*64 + lane];
        acc[nt] = __builtin_amdgcn_mfma_f32_16x16x32_bf16(a, b, acc[nt], 0, 0, 0);
      }
    }
    int col0 = lane & 15;
    int rb = mt*16 + (lane>>4)*4;
    #pragma unroll
    for(int nt=0;nt<4;nt++){
      int col = (ng0+nt)*16 + col0;
      #pragma unroll
      for(int i=0;i<4;i++){
        int n = rb + i;
        if(n < nn) Qbuf[(size_t)sid[n]*HH + col] = acc[nt][i];
      }
    }
  }
}

// ---- O projection via MFMA (resid+relu, optional copy); compacted dst tile list.
__global__ __launch_bounds__(256) void k_gemm_t5(
    const int* __restrict__ tdesc, const int* __restrict__ tcnt,
    const float* X, const int* idxb, const int* cnts, int stride,
    const bfrag* W, const float* resid, const int* rmap, float* Y, float* Y2,
    int relu){
  __shared__ float xs[32*132];
  __shared__ int sid[32], rrow[32];
  int ntk = tcnt[0], ntq = tcnt[1];
  if(blockIdx.x >= ntq) return;
  unsigned ud = (unsigned)tdesc[ntk + blockIdx.x];
  int t = (ud >> 28) & 7;
  int base = ud & 0x0FFFFFFF;
  int cnt = cnts[t];
  if(base >= cnt) return;
  int nn = min(32, cnt - base);
  const int* ids = idxb + (size_t)t*stride + base;
  int tid = threadIdx.x;
  if(tid < 32){
    int s_ = (tid < nn) ? ids[tid] : ids[0];
    sid[tid] = s_;
    rrow[tid] = rmap ? rmap[s_] : s_;
  }
  __syncthreads();
  #pragma unroll
  for(int s=0;s<4;s++){
    int e4 = tid + 256*s;
    int j = e4 >> 5, c4 = (e4 & 31)*4;
    *(float4*)&xs[j*132 + c4] = *(const float4*)&X[(size_t)sid[j]*HH + c4];
  }
  __syncthreads();
  int lane = tid & 63, w = tid >> 6;
  int mt = w & 1, ng0 = (w>>1)*4;
  int arow = mt*16 + (lane & 15);
  int koff = (lane >> 4)*8;
  int tb = t*2048;
  ffrag acc[4];
  #pragma unroll
  for(int i=0;i<4;i++) acc[i] = (ffrag){0.f,0.f,0.f,0.f};
  #pragma unroll
  for(int kc=0;kc<4;kc++){
    const float* ap = xs + arow*132 + kc*32 + koff;
    bfrag a;
    #pragma unroll
    for(int j=0;j<8;j++) a[j] = f2bf(ap[j]);
    #pragma unroll
    for(int nt=0;nt<4;nt++){
      bfrag b = W[tb + ((ng0+nt)*4 + kc)*64 + lane];
      acc[nt] = __builtin_amdgcn_mfma_f32_16x16x32_bf16(a, b, acc[nt], 0, 0, 0);
    }
  }
  int col0 = lane & 15;
  int rb = mt*16 + (lane>>4)*4;
  #pragma unroll
  for(int nt=0;nt<4;nt++){
    int col = (ng0+nt)*16 + col0;
    #pragma unroll
    for(int i=0;i<4;i++){
      int n = rb + i;
      if(n < nn){
        size_t r = (size_t)sid[n]*HH + col;
        float v = acc[nt][i];
        if(resid){
          v += resid[(size_t)rrow[n]*HH + col];
          if(relu) v = fmaxf(v, 0.f);
        }
        Y[r] = v;
        if(Y2) Y2[r] = v;
      }
    }
  }
}

// EW2all[layer][50][128] = edge_emb @ convE[layer]
__global__ void k_edge_tab4(const float* edge_emb, const float* convE, float* EW2all){
  int r = blockIdx.x; int layer = blockIdx.y; int o = threadIdx.x;
  const float* EWp = convE + (size_t)layer*32*HH;
  float acc = 0.f;
  for(int j=0;j<32;j++) acc += edge_emb[r*32+j]*EWp[j*HH+o];
  EW2all[((size_t)layer*50 + r)*HH + o] = acc;
}

// ---------------- CSR build (batched over 3 graphs) ----------------
__global__ void k_hist_dst(const int* edst, int E, int* cnt){
  int e = blockIdx.x*256 + threadIdx.x;
  if(e < E) atomicAdd(&cnt[edst[e]], 1);
}
// one block per graph: exclusive scan -> row_ptr + cursor
__global__ void k_scan3(const int* c1, int n1, int* r1, int* u1,
                        const int* c2, int n2, int* r2, int* u2,
                        const int* c3, int n3, int* r3, int* u3){
  __shared__ int tsum[1024];
  const int* cnt; int n; int* row_ptr; int* cursor;
  if(blockIdx.x == 0){ cnt=c1; n=n1; row_ptr=r1; cursor=u1; }
  else if(blockIdx.x == 1){ cnt=c2; n=n2; row_ptr=r2; cursor=u2; }
  else { cnt=c3; n=n3; row_ptr=r3; cursor=u3; }
  int tid = threadIdx.x;
  int per = (n + 1023) / 1024;
  int start = tid*per; int end = min(start+per, n);
  int s = 0;
  for(int i=start;i<end;i++) s += cnt[i];
  tsum[tid] = s; __syncthreads();
  for(int off=1;off<1024;off<<=1){
    int v = (tid>=off) ? tsum[tid-off] : 0;
    __syncthreads();
    tsum[tid] += v;
    __syncthreads();
  }
  int run = (tid==0) ? 0 : tsum[tid-1];
  for(int i=start;i<end;i++){ row_ptr[i]=run; cursor[i]=run; run += cnt[i]; }
  if(end == n) row_ptr[n] = run;
}
// fill + permute merged: meta[pos] = {esrc, ew|ety<<16}
__global__ void k_fillperm(const int* edst, const int* esrc, const int* ew, const int* ety,
                           int E, int* cursor, int2* meta){
  int e = blockIdx.x*256 + threadIdx.x;
  if(e >= E) return;
  int pos = atomicAdd(&cursor[edst[e]], 1);
  meta[pos] = make_int2(esrc[e], ew[e] | (ety[e]<<16));
}

// single-pass attention on packed bf16 KV; 8-edge ILP, packed int2 edge meta,
// 0.25 scale folded into q.
__global__ void k_attn_fused8(const int* __restrict__ row_ptr, const int2* __restrict__ meta,
                              const unsigned* __restrict__ KVp, const float* __restrict__ Qbuf,
                              const float* __restrict__ EW2, const float* __restrict__ mu,
                              float* __restrict__ Abuf){
  int d = blockIdx.x; int o = threadIdx.x;
  int r0 = row_ptr[d], r1 = row_ptr[d+1];
  __shared__ float q[HH];
  q[o] = Qbuf[(size_t)d*HH+o]*0.25f;
  __syncthreads();
  int h = o >> 4;
  float qo = q[o];
  float dn0=0.f, dn1=0.f, dn2=0.f, dn3=0.f;
  float ac0=0.f, ac1=0.f, ac2=0.f, ac3=0.f;
  int r = r0;
  for(; r+7 < r1; r += 8){
    int2 m[8]; unsigned u[8]; float e[8]; float p[8];
    #pragma unroll
    for(int j=0;j<8;j++) m[j] = meta[r+j];
    #pragma unroll
    for(int j=0;j<8;j++) u[j] = KVp[(size_t)m[j].x*HH + o];
    #pragma unroll
    for(int j=0;j<8;j++) e[j] = EW2[(m[j].y & 0xffff)*HH + o];
    #pragma unroll
    for(int j=0;j<8;j++) p[j] = qo*(__uint_as_float(u[j]<<16) + e[j]);
    #pragma unroll
    for(int j=0;j<8;j++) p[j] += __shfl_xor(p[j], 1, 64);
    #pragma unroll
    for(int j=0;j<8;j++) p[j] += __shfl_xor(p[j], 2, 64);
    #pragma unroll
    for(int j=0;j<8;j++) p[j] += __shfl_xor(p[j], 4, 64);
    #pragma unroll
    for(int j=0;j<8;j++) p[j] += __shfl_xor(p[j], 8, 64);
    float ex[8];
    #pragma unroll
    for(int j=0;j<8;j++) ex[j] = __expf(p[j]*mu[(m[j].y>>16)*NH+h]);
    dn0 += ex[0]+ex[4]; dn1 += ex[1]+ex[5]; dn2 += ex[2]+ex[6]; dn3 += ex[3]+ex[7];
    ac0 += ex[0]*__uint_as_float(u[0]&0xffff0000u) + ex[4]*__uint_as_float(u[4]&0xffff0000u);
    ac1 += ex[1]*__uint_as_float(u[1]&0xffff0000u) + ex[5]*__uint_as_float(u[5]&0xffff0000u);
    ac2 += ex[2]*__uint_as_float(u[2]&0xffff0000u) + ex[6]*__uint_as_float(u[6]&0xffff0000u);
    ac3 += ex[3]*__uint_as_float(u[3]&0xffff0000u) + ex[7]*__uint_as_float(u[7]&0xffff0000u);
  }
  for(; r+3 < r1; r += 4){
    int2 m[4]; unsigned u[4]; float e[4]; float p[4];
    #pragma unroll
    for(int j=0;j<4;j++) m[j] = meta[r+j];
    #pragma unroll
    for(int j=0;j<4;j++) u[j] = KVp[(size_t)m[j].x*HH + o];
    #pragma unroll
    for(int j=0;j<4;j++) e[j] = EW2[(m[j].y & 0xffff)*HH + o];
    #pragma unroll
    for(int j=0;j<4;j++) p[j] = qo*(__uint_as_float(u[j]<<16) + e[j]);
    #pragma unroll
    for(int j=0;j<4;j++) p[j] += __shfl_xor(p[j], 1, 64);
    #pragma unroll
    for(int j=0;j<4;j++) p[j] += __shfl_xor(p[j], 2, 64);
    #pragma unroll
    for(int j=0;j<4;j++) p[j] += __shfl_xor(p[j], 4, 64);
    #pragma unroll
    for(int j=0;j<4;j++) p[j] += __shfl_xor(p[j], 8, 64);
    float ex[4];
    #pragma unroll
    for(int j=0;j<4;j++) ex[j] = __expf(p[j]*mu[(m[j].y>>16)*NH+h]);
    dn0 += ex[0]; dn1 += ex[1]; dn2 += ex[2]; dn3 += ex[3];
    ac0 += ex[0]*__uint_as_float(u[0]&0xffff0000u);
    ac1 += ex[1]*__uint_as_float(u[1]&0xffff0000u);
    ac2 += ex[2]*__uint_as_float(u[2]&0xffff0000u);
    ac3 += ex[3]*__uint_as_float(u[3]&0xffff0000u);
  }
  for(; r < r1; r++){
    int2 m = meta[r];
    unsigned u = KVp[(size_t)m.x*HH + o];
    float p = qo*(__uint_as_float(u<<16) + EW2[(m.y & 0xffff)*HH + o]);
    p += __shfl_xor(p, 1, 64);
    p += __shfl_xor(p, 2, 64);
    p += __shfl_xor(p, 4, 64);
    p += __shfl_xor(p, 8, 64);
    float ex = __expf(p*mu[(m.y>>16)*NH+h]);
    dn0 += ex; ac0 += ex*__uint_as_float(u&0xffff0000u);
  }
  float dd = (dn0+dn1)+(dn2+dn3), acc = (ac0+ac1)+(ac2+ac3);
  Abuf[(size_t)d*HH + o] = acc / fmaxf(dd, 1e-9f);
}

// ---------------- stage D: token pooling ----------------
__global__ void k_tokatt(const float* h2f, const int* toknt, const float* ipW, const float* iaW,
                         float* abuf, unsigned* amax, const int* tokid){
  int t = blockIdx.x; int o = threadIdx.x;
  __shared__ float es[HH];
  __shared__ float red[HH];
  int b = t % BB, l = t / BB;
  es[o] = h2f[(b*LL+l)*HH+o];
  __syncthreads();
  int nt = toknt[t];
  const float* w = ipW + (size_t)nt*HH*HH;
  float acc = 0.f;
  for(int j=0;j<HH;j++) acc += es[j]*w[j*HH+o];
  float u = tanhfast(acc);
  red[o] = u * iaW[nt*HH+o];
  __syncthreads();
  for(int s=64;s>0;s>>=1){ if(o<s) red[o]+=red[o+s]; __syncthreads(); }
  if(o==0){
    float a = red[0];
    abuf[t] = a;
    atomicMax(&amax[tokid[t]], fenc(a));
  }
}

__global__ void k_tokexp(const int* tokid, float* abuf, const unsigned* amax, float* aden, float* cnt){
  int t = blockIdx.x*blockDim.x + threadIdx.x;
  if(t >= TT) return;
  int c = tokid[t];
  float ex = __expf(abuf[t]-fdec(amax[c]));
  abuf[t] = ex;
  atomicAdd(&aden[c], ex);
  atomicAdd(&cnt[c], 1.f);
}

__global__ void k_tokagg(const int* tokid, const float* abuf, const float* aden,
                         const float* h2f, float* hist2){
  int t = blockIdx.x; int o = threadIdx.x;
  int c = tokid[t];
  float w = abuf[t]/fmaxf(aden[c],1e-9f);
  int b = t % BB, l = t / BB;
  atomicAdd(&hist2[c*HH+o], w*h2f[(b*LL+l)*HH+o]);
}

__global__ void k_histfix(const float* cnt, const float* hist_emb, float* hist2){
  int c = blockIdx.x; int o = threadIdx.x;
  if(cnt[c] == 0.f) hist2[c*HH+o] = hist_emb[c*HH+o];
}

// ---------------- parent pooling ----------------
__global__ void k_peagg(const int* pe_p, const int* pe_c, const float* cef, float* psum, float* pcnt){
  int i = blockIdx.x; int o = threadIdx.x;
  int p = pe_p[i], c = pe_c[i];
  atomicAdd(&psum[p*HH+o], cef[c*HH+o]);
  if(o==0) atomicAdd(&pcnt[p], 1.f);
}

__global__ void k_parent(const float* psum, const float* pcnt, float* out){
  int i = blockIdx.x; int o = threadIdx.x;
  out[i*HH+o] = psum[i*HH+o]/fmaxf(pcnt[i],1.f);
}

extern "C" void kernel_launch(void* const* d_in, const int* in_sizes, int n_in,
                              void* d_out, int out_size, void* d_ws, size_t ws_size,
                              hipStream_t stream){
  const int* seq     = (const int*)d_in[0];
  const int* seq_nt  = (const int*)d_in[1];
  const int* dur     = (const int*)d_in[2];
  const int* stime   = (const int*)d_in[3];
  const int* etime   = (const int*)d_in[4];
  const int* g1_nid  = (const int*)d_in[5];
  const int* g1_nt   = (const int*)d_in[6];
  const int* g1_esrc = (const int*)d_in[7];
  const int* g1_edst = (const int*)d_in[8];
  const int* g1_ety  = (const int*)d_in[9];
  const int* g1_ew   = (const int*)d_in[10];
  const int* g2_sel  = (const int*)d_in[11];
  const int* g2_esrc = (const int*)d_in[12];
  const int* g2_edst = (const int*)d_in[13];
  const int* g2_ety  = (const int*)d_in[14];
  const int* g2_ew   = (const int*)d_in[15];
  const int* tok_sel = (const int*)d_in[16];
  const int* g4_esrc = (const int*)d_in[17];
  const int* g4_edst = (const int*)d_in[18];
  const int* g4_ety  = (const int*)d_in[19];
  const int* g4_ew   = (const int*)d_in[20];
  const int* pe_p    = (const int*)d_in[21];
  const int* pe_c    = (const int*)d_in[22];
  const float* emb     = (const float*)d_in[23];
  const float* hist_emb= (const float*)d_in[24];
  const float* edge_emb= (const float*)d_in[25];
  const float* dia_w   = (const float*)d_in[26];
  const float* dia_b   = (const float*)d_in[27];
  const float* t2v_w   = (const float*)d_in[28];
  const float* t2v_b   = (const float*)d_in[29];
  const float* exp_W   = (const float*)d_in[30];
  const float* exp_b   = (const float*)d_in[31];
  const float* l1Wi    = (const float*)d_in[32];
  const float* l1Wh    = (const float*)d_in[33];
  const float* l1b     = (const float*)d_in[34];
  const float* l2Wi    = (const float*)d_in[35];
  const float* l2Wh    = (const float*)d_in[36];
  const float* l2b     = (const float*)d_in[37];
  const float* convK   = (const float*)d_in[38];
  const float* convQ   = (const float*)d_in[39];
  const float* convV   = (const float*)d_in[40];
  const float* convO   = (const float*)d_in[41];
  const float* convE   = (const float*)d_in[42];
  const float* convMu  = (const float*)d_in[43];
  const float* ipW     = (const float*)d_in[44];
  const float* iaW     = (const float*)d_in[45];
  const float* skip    = (const float*)d_in[46];
  float* outp = (float*)d_out;

  // workspace arena
  char* wsp = (char*)d_ws;
  size_t off = 0;
  auto A = [&](size_t nbytes)->char*{ char* p = wsp+off; off += (nbytes+255)&~(size_t)255; return p; };
  float*    srcbuf = (float*)   A((size_t)N1SN*HH*4);
  unsigned* KVp    = (unsigned*)A((size_t)N1SN*HH*4);    // packed bf16 [V|K]
  float*    Qbuf   = (float*)   A((size_t)N1DN*HH*4);
  float*    Abuf   = (float*)   A((size_t)N1DN*HH*4);
  float*    xbuf   = (float*)   A((size_t)TT*HH*4);
  float*    gpre   = (float*)   A((size_t)TT*512*4);
  float*    h1     = (float*)   A((size_t)TT*HH*4);
  float*    dst2   = (float*)   A((size_t)TT*HH*4);
  float*    xg     = (float*)   A((size_t)N1DN*HH*4);
  float*    x2     = (float*)   A((size_t)TT*HH*4);
  float*    h2f    = (float*)   A((size_t)TT*HH*4);
  float*    hist2  = (float*)   A((size_t)CHILDN*HH*4);
  float*    cnt    = (float*)   A((size_t)CHILDN*4);
  float*    abuf   = (float*)   A((size_t)TT*4);
  unsigned* amax   = (unsigned*)A((size_t)CHILDN*4);
  float*    aden   = (float*)   A((size_t)CHILDN*4);
  float*    x3     = (float*)   A((size_t)N1DN*HH*4);
  float*    cef    = (float*)   A((size_t)N4DN*HH*4);
  float*    psum   = (float*)   A((size_t)PARENTN*HH*4);
  float*    pcnt   = (float*)   A((size_t)PARENTN*4);
  float*    sdia   = (float*)   A((size_t)CHILDN*64*4);  // sin(dia_w+dia_b) cols 64..127
  int*      tokid  = (int*)     A((size_t)TT*4);
  int*      toknt  = (int*)     A((size_t)TT*4);
  int*      gnid2  = (int*)     A((size_t)N2N*4);
  int*      idxS1  = (int*)     A((size_t)NTY*N1SN*4);
  int*      idxS2  = (int*)     A((size_t)NTY*N1DN*4);
  int*      idxS3  = (int*)     A((size_t)NTY*N2N*4);
  int*      idxS4  = (int*)     A((size_t)NTY*TT*4);
  int*      idxS5  = (int*)     A((size_t)NTY*N4DN*4);
  int*      cntall = (int*)     A((size_t)5*NTY*4);
  int*      tdesc  = (int*)     A((size_t)3*TDSTRIDE*4);
  int*      tcnt   = (int*)     A((size_t)8*4);
  float*    EW2all = (float*)   A((size_t)4*50*HH*4);
  short*    Wsw    = (short*)   A((size_t)64*16384*2);   // bf16-swizzled weights
  int*      g1row  = (int*)     A((size_t)(N1DN+1)*4);
  int2*     g1meta = (int2*)    A((size_t)E1N*8);
  int*      g2row  = (int*)     A((size_t)(TT+1)*4);
  int2*     g2meta = (int2*)    A((size_t)E2N*8);
  int*      g4row  = (int*)     A((size_t)(N4DN+1)*4);
  int2*     g4meta = (int2*)    A((size_t)E4N*8);
  int*      icnt1  = (int*)     A((size_t)(N1DN+1)*4);
  int*      icur1  = (int*)     A((size_t)(N1DN+1)*4);
  int*      icnt2  = (int*)     A((size_t)(TT+1)*4);
  int*      icur2  = (int*)     A((size_t)(TT+1)*4);
  int*      icnt3  = (int*)     A((size_t)(N4DN+1)*4);
  int*      icur3  = (int*)     A((size_t)(N4DN+1)*4);
  if(off > ws_size) return;  // insufficient scratch: output stays zero

  auto run_conv = [&](int cfg, int gkvq, int gq,
                      const float* src_X, const int* src_nid, const int* srcmap,
                      const int* idx_src, int* cnt_src, int stride_src,
                      const float* q_X, const int* q_map,
                      const float* resid_X, const int* r_map, int ndst,
                      const int* idx_dst, int* cnt_dst, int stride_dst,
                      const int* rowp, const int2* meta,
                      int layer, float* outbuf, float* out2, int relu){
    const bfrag* WB = (const bfrag*)Wsw;
    const bfrag* WK = WB + (size_t)( 0 + layer*4)*2048;
    const bfrag* WV = WB + (size_t)(16 + layer*4)*2048;
    const bfrag* WQ = WB + (size_t)(32 + layer*4)*2048;
    const bfrag* WO = WB + (size_t)(48 + layer*4)*2048;
    const float* MU  = convMu + (size_t)layer*NRL*NH;
    const float* EW2 = EW2all + (size_t)layer*50*HH;
    const int* td = tdesc + (size_t)cfg*TDSTRIDE;
    const int* tc = tcnt + cfg*2;
    k_gemm_kvq<<<gkvq, 256, 0, stream>>>(td, tc, src_X, src_nid, srcmap, sdia,
                                         idx_src, cnt_src, stride_src, WK, WV, KVp,
                                         q_X, q_map, idx_dst, cnt_dst, stride_dst, WQ, Qbuf);
    k_attn_fused8<<<ndst, HH, 0, stream>>>(rowp, meta, KVp, Qbuf, EW2, MU, Abuf);
    k_gemm_t5<<<gq, 256, 0, stream>>>(td, tc, Abuf, idx_dst, cnt_dst, stride_dst, WO,
                                      resid_X, r_map, outbuf, out2, relu);
  };

  // ---- upfront: init, sin table, weight prepack, edge tables, scatters, tiles, CSR ----
  k_init<<<(CHILDN*HH+255)/256, 256, 0, stream>>>(hist2, cnt, amax, aden, psum, pcnt, cntall,
                                                  icnt1, icnt2, icnt3);
  k_sindia<<<(CHILDN*64+255)/256, 256, 0, stream>>>(dia_w, dia_b, sdia);
  k_prepack<<<64, 256, 0, stream>>>(convK, convV, convQ, convO, Wsw);
  k_edge_tab4<<<dim3(50,4), HH, 0, stream>>>(edge_emb, convE, EW2all);
  k_scatter3<<<(N1SN+255)/256, 256, 0, stream>>>(g1_nt, cntall+0*NTY, idxS1,
                                                 cntall+1*NTY, idxS2, cntall+4*NTY, idxS5);
  k_tokprep<<<(TT+255)/256, 256, 0, stream>>>(seq, seq_nt, tokid, toknt, cntall+3*NTY, idxS4);
  k_prep2scat<<<(N2N+255)/256, 256, 0, stream>>>(g2_sel, g1_nid, g1_nt, gnid2, cntall+2*NTY, idxS3);
  k_mktiles<<<1, 256, 0, stream>>>(cntall, tdesc, tcnt);
  k_hist_dst<<<(E1N+255)/256, 256, 0, stream>>>(g1_edst, E1N, icnt1);
  k_hist_dst<<<(E2N+255)/256, 256, 0, stream>>>(g2_edst, E2N, icnt2);
  k_hist_dst<<<(E4N+255)/256, 256, 0, stream>>>(g4_edst, E4N, icnt3);
  k_scan3<<<3, 1024, 0, stream>>>(icnt1, N1DN, g1row, icur1,
                                  icnt2, TT,   g2row, icur2,
                                  icnt3, N4DN, g4row, icur3);
  k_fillperm<<<(E1N+255)/256, 256, 0, stream>>>(g1_edst, g1_esrc, g1_ew, g1_ety, E1N, icur1, g1meta);
  k_fillperm<<<(E2N+255)/256, 256, 0, stream>>>(g2_edst, g2_esrc, g2_ew, g2_ety, E2N, icur2, g2meta);
  k_fillperm<<<(E4N+255)/256, 256, 0, stream>>>(g4_edst, g4_esrc, g4_ew, g4_ety, E4N, icur3, g4meta);

  // ---- stage A: features + LSTM1 (fused scan) ----
  k_featx2<<<TT/32, 512, 0, stream>>>(seq, dur, stime, etime, emb, dia_w, dia_b, t2v_w, t2v_b, exp_W, exp_b, xbuf);
  k_xwi2<<<(TT+15)/16, 256, 0, stream>>>(xbuf, l1Wi, l1b, gpre, TT, 0);
  k_lstm_fused<<<BB, 512, 0, stream>>>(gpre, l1Wh, h1, (float*)nullptr);

  // grid bounds (true tile counts are device-side; these are safe upper bounds)
  const int GKVQ_A = (N1SN+N1DN)/32 + 8;   // conv1 / conv3
  const int GKVQ_B = (N2N+TT)/32 + 8;      // conv2
  const int GKVQ_C = (N1DN+N4DN)/32 + 8;   // conv4
  const int GQ_A   = (N1DN+31)/32 + 4;
  const int GQ_B   = (TT+31)/32 + 4;
  const int GQ_C   = (N4DN+31)/32 + 4;

  // ---- conv1 on g1 (src/dst features gathered from emb via g1_nid in the gemms) ----
  run_conv(0, GKVQ_A, GQ_A,
           emb, g1_nid, g1_nid, idxS1, cntall+0*NTY, N1SN,
           emb, g1_nid,
           emb, g1_nid, N1DN, idxS2, cntall+1*NTY, N1DN,
           g1row, g1meta, 0, xg, (float*)nullptr, 1);

  // ---- conv2 on g2 (src features gathered from xg via g2_sel in the gemm) ----
  k_dst2<<<TT, HH, 0, stream>>>(tok_sel, xg, h1, dst2);
  run_conv(1, GKVQ_B, GQ_B,
           xg, gnid2, g2_sel, idxS3, cntall+2*NTY, N2N,
           dst2, (const int*)nullptr,
           dst2, (const int*)nullptr, TT, idxS4, cntall+3*NTY, TT,
           g2row, g2meta, 1, x2, (float*)nullptr, 1);

  // ---- LSTM2 (h2 is output 0); x2 read directly with permuted layout ----
  k_xwi2<<<(TT+15)/16, 256, 0, stream>>>(x2, l2Wi, l2b, gpre, TT, 1);
  k_lstm_fused<<<BB, 512, 0, stream>>>(gpre, l2Wh, h2f, outp);

  // ---- stage D: token attention pooling -> hist2 ----
  k_tokatt<<<TT, HH, 0, stream>>>(h2f, toknt, ipW, iaW, abuf, amax, tokid);
  k_tokexp<<<(TT+255)/256, 256, 0, stream>>>(tokid, abuf, amax, aden, cnt);
  k_tokagg<<<TT, HH, 0, stream>>>(tokid, abuf, aden, h2f, hist2);
  k_histfix<<<CHILDN, HH, 0, stream>>>(cnt, hist_emb, hist2);

  // ---- conv3 on g1 with skip-mixed input (g1 CSR + scatters + tiles reused) ----
  k_x0<<<N1SN, HH, 0, stream>>>(g1_nid, g1_nt, emb, hist2, skip, srcbuf);
  run_conv(0, GKVQ_A, GQ_A,
           srcbuf, g1_nid, (const int*)nullptr, idxS1, cntall+0*NTY, N1SN,
           srcbuf, (const int*)nullptr,
           srcbuf, (const int*)nullptr, N1DN, idxS2, cntall+1*NTY, N1DN,
           g1row, g1meta, 2, x3, (float*)nullptr, 1);

  // ---- conv4 on g4 (child_embed = output 1, no relu) ----
  run_conv(2, GKVQ_C, GQ_C,
           x3, g1_nid, (const int*)nullptr, idxS2, cntall+1*NTY, N1DN,
           x3, (const int*)nullptr,
           x3, (const int*)nullptr, N4DN, idxS5, cntall+4*NTY, N4DN,
           g4row, g4meta, 3, cef, outp + (size_t)TT*HH, 0);

  // ---- parent pooling (output 2) ----
  k_peagg<<<EC2PN, HH, 0, stream>>>(pe_p, pe_c, cef, psum, pcnt);
  k_parent<<<PARENTN, HH, 0, stream>>>(psum, pcnt, outp + (size_t)TT*HH + (size_t)N4DN*HH);
}

// Round 8
// 759.106 us; speedup vs baseline: 1.0515x; 1.0515x over previous
//
#include <hip/hip_runtime.h>
#include <math.h>

#define BB 256
#define LL 20
#define HH 128
#define NH 8
#define D2C 64
#define NTY 4
#define NRL 4
#define CHILDN 30001
#define PARENTN 500
#define N1SN 50000
#define N1DN 20000
#define E1N 300000
#define N2N 20000
#define E2N 200000
#define TT (BB*LL)
#define N4DN 5000
#define E4N 150000
#define EC2PN 8000
#define TDSTRIDE 2304

typedef __attribute__((ext_vector_type(8))) short bfrag;   // 8 bf16 in 4 VGPRs
typedef __attribute__((ext_vector_type(4))) float ffrag;   // MFMA accumulator

__device__ __forceinline__ unsigned fenc(float f){ unsigned u=__float_as_uint(f); return (u&0x80000000u)? ~u : (u|0x80000000u); }
__device__ __forceinline__ float fdec(unsigned u){ return (u&0x80000000u)? __uint_as_float(u^0x80000000u) : __uint_as_float(~u); }
__device__ __forceinline__ float sigfast(float x){ return 1.f/(1.f+__expf(-x)); }
__device__ __forceinline__ float tanhfast(float x){ float e = __expf(-2.f*x); return (1.f-e)/(1.f+e); }
__device__ __forceinline__ short f2bf(float f){
  unsigned u = __float_as_uint(f);
  unsigned r = u + 0x7FFFu + ((u>>16)&1u);   // round-to-nearest-even
  return (short)(r>>16);
}

// ---------------- upfront init: all zero/poison buffers in one launch ----------------
__global__ void k_init(float* hist2, float* cnt, unsigned* amax, float* aden,
                       float* psum, float* pcnt, int* cntall,
                       int* icnt1, int* icnt2, int* icnt3){
  int i = blockIdx.x*256 + threadIdx.x;
  if(i < CHILDN*HH) hist2[i] = 0.f;
  if(i < CHILDN){ cnt[i] = 0.f; aden[i] = 0.f; amax[i] = 0x007FFFFFu; }
  if(i < PARENTN*HH) psum[i] = 0.f;
  if(i < PARENTN) pcnt[i] = 0.f;
  if(i < 5*NTY) cntall[i] = 0;
  if(i < N1DN) icnt1[i] = 0;
  if(i < TT)   icnt2[i] = 0;
  if(i < N4DN) icnt3[i] = 0;
}

// sin(dia_w + dia_b) per child node, cols 64..127 — shared by all 4 convs
__global__ void k_sindia(const float* __restrict__ dia_w, const float* __restrict__ dia_b,
                         float* __restrict__ sdia){
  int i = blockIdx.x*256 + threadIdx.x;
  if(i >= CHILDN*64) return;
  int c = i >> 6, k = (i & 63) + 64;
  sdia[i] = __sinf(dia_w[(size_t)c*HH+k] + dia_b[(size_t)c*HH+k]);
}

// ---------------- Stage A: feature expansion (tiled: 32 tokens/block) ----------------
__global__ __launch_bounds__(512) void k_featx2(const int* __restrict__ seq, const int* __restrict__ dur,
                        const int* __restrict__ stime, const int* __restrict__ etime,
                        const float* __restrict__ emb, const float* __restrict__ dia_w, const float* __restrict__ dia_b,
                        const float* __restrict__ t2v_w, const float* __restrict__ t2v_b,
                        const float* __restrict__ exp_W, const float* __restrict__ exp_b, float* __restrict__ xout){
  __shared__ float feat[32*273];           // [st(128) | et(128) | tv(16)] per token, stride 273
  int base = blockIdx.x*32;
  int j = threadIdx.x >> 4;                // token 0..31
  int p = threadIdx.x & 15;                // 16 threads/token, 8 cols each
  int row = base + j;
  int node = seq[row];
  float ts = (float)stime[row], te = (float)etime[row];
  const float* ep = emb + (size_t)node*HH;
  float* fr = feat + j*273;
  int o0 = p*8;
  #pragma unroll
  for(int ii=0; ii<8; ii+=4){
    int o = o0 + ii;
    float4 e = *(const float4*)(ep + o);
    float4 st = e, et = e;
    if(o >= D2C){
      float4 w = *(const float4*)(dia_w + (size_t)node*HH + o);
      float4 b = *(const float4*)(dia_b + (size_t)node*HH + o);
      st.x = e.x*__sinf(w.x*ts+b.x); st.y = e.y*__sinf(w.y*ts+b.y);
      st.z = e.z*__sinf(w.z*ts+b.z); st.w = e.w*__sinf(w.w*ts+b.w);
      et.x = e.x*__sinf(w.x*te+b.x); et.y = e.y*__sinf(w.y*te+b.y);
      et.z = e.z*__sinf(w.z*te+b.z); et.w = e.w*__sinf(w.w*te+b.w);
    }
    fr[o] = st.x; fr[o+1] = st.y; fr[o+2] = st.z; fr[o+3] = st.w;
    fr[128+o] = et.x; fr[128+o+1] = et.y; fr[128+o+2] = et.z; fr[128+o+3] = et.w;
  }
  if(p == 0){
    float td = (float)dur[row];
    #pragma unroll
    for(int i=0;i<16;i++){
      float w = t2v_w[i], b = t2v_b[i];
      fr[256+i] = (i==0) ? (w*td + b) : __sinf(w*td + b);
    }
  }
  __syncthreads();
  // GEMM: 32x272 @ 272x128, each thread: 2 rows x 4 cols
  int oc = (threadIdx.x & 31)*4;
  int jg = threadIdx.x >> 5;               // 0..15
  const float* f0 = feat + (jg*2)*273;
  const float* f1 = feat + (jg*2+1)*273;
  float4 a0 = {0,0,0,0}, a1 = {0,0,0,0};
  for(int k=0;k<272;k++){
    float4 w = *(const float4*)(exp_W + (size_t)k*HH + oc);
    float x0 = f0[k], x1 = f1[k];
    a0.x += x0*w.x; a0.y += x0*w.y; a0.z += x0*w.z; a0.w += x0*w.w;
    a1.x += x1*w.x; a1.y += x1*w.y; a1.z += x1*w.z; a1.w += x1*w.w;
  }
  float4 bv = *(const float4*)(exp_b + oc);
  a0.x = fmaxf(a0.x+bv.x, 0.f); a0.y = fmaxf(a0.y+bv.y, 0.f);
  a0.z = fmaxf(a0.z+bv.z, 0.f); a0.w = fmaxf(a0.w+bv.w, 0.f);
  a1.x = fmaxf(a1.x+bv.x, 0.f); a1.y = fmaxf(a1.y+bv.y, 0.f);
  a1.z = fmaxf(a1.z+bv.z, 0.f); a1.w = fmaxf(a1.w+bv.w, 0.f);
  *(float4*)(xout + (size_t)(base + jg*2  )*HH + oc) = a0;
  *(float4*)(xout + (size_t)(base + jg*2+1)*HH + oc) = a1;
}

// tiled x @ Wi + b -> gpre: 16 rows x 512 cols per block; perm=1 reads x in (l*BB+b) layout
__global__ void k_xwi2(const float* x, const float* Wi, const float* bias, float* gpre, int rows, int perm){
  int base = blockIdx.x*16;
  __shared__ float xs[128*17];
  int tid = threadIdx.x;
  #pragma unroll
  for(int s=0;s<8;s++){
    int elem = tid + 256*s;
    int k = elem & 127, j = elem >> 7;
    int r = base + j;
    int src = r;
    if(perm) src = (r % LL)*BB + (r / LL);
    xs[k*17 + j] = (r < rows) ? x[(size_t)src*HH + k] : 0.f;
  }
  __syncthreads();
  int o4 = (tid & 127)*4;
  int ng = tid >> 7;
  float4 a[8];
  #pragma unroll
  for(int j=0;j<8;j++) a[j]=make_float4(0,0,0,0);
  for(int k=0;k<HH;k++){
    float4 w = *(const float4*)(Wi + (size_t)k*512 + o4);
    const float* xr = xs + k*17 + ng*8;
    #pragma unroll
    for(int j=0;j<8;j++){
      float xv = xr[j];
      a[j].x += xv*w.x; a[j].y += xv*w.y; a[j].z += xv*w.z; a[j].w += xv*w.w;
    }
  }
  float4 bv = *(const float4*)(bias + o4);
  #pragma unroll
  for(int j=0;j<8;j++){
    int r = base + ng*8 + j;
    if(r < rows){
      float4 v = a[j];
      v.x += bv.x; v.y += bv.y; v.z += bv.z; v.w += bv.w;
      *(float4*)(gpre + (size_t)r*512 + o4) = v;
    }
  }
}

// fused 20-step LSTM: one block per batch row, Wh column in registers, gpre
// prefetched into registers, activations spread across all 512 threads.
__global__ __launch_bounds__(512, 2) void k_lstm_fused(const float* __restrict__ gpre,
                                                       const float* __restrict__ Wh,
                                                       float* __restrict__ hout,
                                                       float* __restrict__ hout2){
  int b = blockIdx.x;
  int o = threadIdx.x;
  __shared__ float hs[HH];
  __shared__ float act[512];
  float wr[HH];
  #pragma unroll
  for(int h=0;h<HH;h++) wr[h] = Wh[(size_t)h*512 + o];
  float gv[LL];
  const float* gp = gpre + (size_t)b*LL*512 + o;
  #pragma unroll
  for(int l=0;l<LL;l++) gv[l] = gp[(size_t)l*512];
  if(o < HH) hs[o] = 0.f;
  float cc = 0.f;
  int quad = o >> 7;                        // 0=i, 1=f, 2=g, 3=o
  __syncthreads();
  for(int l=0;l<LL;l++){
    float a0=0.f,a1=0.f,a2=0.f,a3=0.f;
    #pragma unroll
    for(int h=0;h<HH;h+=4){
      float4 hv = *(const float4*)&hs[h];
      a0 += hv.x*wr[h];   a1 += hv.y*wr[h+1];
      a2 += hv.z*wr[h+2]; a3 += hv.w*wr[h+3];
    }
    float g = gv[l] + ((a0+a1)+(a2+a3));
    act[o] = (quad==2) ? tanhfast(g) : sigfast(g);
    __syncthreads();
    if(o < HH){
      cc = act[HH+o]*cc + act[o]*act[2*HH+o];
      float hh = act[3*HH+o]*tanhfast(cc);
      hs[o] = hh;
      size_t bi = ((size_t)b*LL + l)*HH + o;
      hout[bi] = hh;
      if(hout2) hout2[bi] = hh;
    }
    __syncthreads();
  }
}

// ---------------- token prep + type scatter (merged) ----------------
__global__ void k_tokprep(const int* __restrict__ seq, const int* __restrict__ seq_nt,
                          int* __restrict__ tokid, int* __restrict__ toknt,
                          int* __restrict__ cnts, int* __restrict__ idxb){
  __shared__ int h[NTY];
  __shared__ int bs[NTY];
  int i = blockIdx.x*256 + threadIdx.x;
  if(threadIdx.x < NTY) h[threadIdx.x] = 0;
  __syncthreads();
  int nt = 0, r = 0;
  bool act = (i < TT);
  if(act){
    int b = i % BB, l = i / BB;
    tokid[i] = seq[b*LL+l];
    nt = seq_nt[b*LL+l];
    toknt[i] = nt;
    r = atomicAdd(&h[nt], 1);
  }
  __syncthreads();
  if(threadIdx.x < NTY && h[threadIdx.x] > 0)
    bs[threadIdx.x] = atomicAdd(&cnts[threadIdx.x], h[threadIdx.x]);
  __syncthreads();
  if(act) idxb[nt*TT + bs[nt] + r] = i;
}

// conv2 src prep + type scatter (merged)
__global__ void k_prep2scat(const int* __restrict__ sel, const int* __restrict__ g1_nid,
                            const int* __restrict__ g1_nt, int* __restrict__ gnid2,
                            int* __restrict__ cnts, int* __restrict__ idxb){
  __shared__ int h[NTY];
  __shared__ int bs[NTY];
  int i = blockIdx.x*256 + threadIdx.x;
  if(threadIdx.x < NTY) h[threadIdx.x] = 0;
  __syncthreads();
  int nt = 0, r = 0;
  bool act = (i < N2N);
  if(act){
    int s = sel[i];
    gnid2[i] = g1_nid[s];
    nt = g1_nt[s];
    r = atomicAdd(&h[nt], 1);
  }
  __syncthreads();
  if(threadIdx.x < NTY && h[threadIdx.x] > 0)
    bs[threadIdx.x] = atomicAdd(&cnts[threadIdx.x], h[threadIdx.x]);
  __syncthreads();
  if(act) idxb[nt*N2N + bs[nt] + r] = i;
}

__global__ void k_dst2(const int* tok_sel, const float* xg, const float* h1, float* dst2){
  int t = blockIdx.x; int o = threadIdx.x;
  int b = t % BB, l = t / BB;
  dst2[t*HH+o] = xg[tok_sel[t]*HH+o] + h1[(b*LL+l)*HH+o];
}

__global__ void k_x0(const int* nid, const int* ntype, const float* emb, const float* hist2,
                     const float* skip, float* srcbuf){
  int i = blockIdx.x; int o = threadIdx.x;
  float a = sigfast(skip[ntype[i]]);
  int nd = nid[i];
  srcbuf[i*HH+o] = emb[nd*HH+o]*a + hist2[nd*HH+o]*(1.f-a);
}

// 3-way type scatter of g1_nt for prefixes N1SN / N1DN / N4DN in one pass
__global__ void k_scatter3(const int* __restrict__ types,
                           int* cnts1, int* idx1, int* cnts2, int* idx2, int* cnts3, int* idx3){
  __shared__ int h[3][NTY];
  __shared__ int bs[3][NTY];
  int i = blockIdx.x*256 + threadIdx.x;
  if(threadIdx.x < 3*NTY) (&h[0][0])[threadIdx.x] = 0;
  __syncthreads();
  int t = 0, r1 = 0, r2 = 0, r3 = 0;
  bool a1 = (i < N1SN), a2 = (i < N1DN), a3 = (i < N4DN);
  if(a1){
    t = types[i];
    r1 = atomicAdd(&h[0][t], 1);
    if(a2) r2 = atomicAdd(&h[1][t], 1);
    if(a3) r3 = atomicAdd(&h[2][t], 1);
  }
  __syncthreads();
  if(threadIdx.x < NTY){
    int ty = threadIdx.x;
    if(h[0][ty] > 0) bs[0][ty] = atomicAdd(&cnts1[ty], h[0][ty]);
    if(h[1][ty] > 0) bs[1][ty] = atomicAdd(&cnts2[ty], h[1][ty]);
    if(h[2][ty] > 0) bs[2][ty] = atomicAdd(&cnts3[ty], h[2][ty]);
  }
  __syncthreads();
  if(a1) idx1[t*N1SN + bs[0][t] + r1] = i;
  if(a2) idx2[t*N1DN + bs[1][t] + r2] = i;
  if(a3) idx3[t*N4DN + bs[2][t] + r3] = i;
}

// ---- tile-descriptor builder: compacted work lists for the 3 unique conv configs.
__global__ void k_mktiles(const int* __restrict__ cntall, int* __restrict__ tdesc, int* __restrict__ tcnt){
  __shared__ int start[3][2][NTY];
  if(threadIdx.x == 0){
    const int srcg[3] = {0,2,1};
    const int dstg[3] = {1,3,4};
    for(int c=0;c<3;c++){
      int acc = 0;
      for(int z=0;z<2;z++){
        int g = (z==0) ? srcg[c] : dstg[c];
        int zacc = 0;
        for(int t=0;t<NTY;t++){
          start[c][z][t] = acc;
          int tiles = (cntall[g*NTY+t]+31)>>5;
          acc += tiles; zacc += tiles;
        }
        tcnt[c*2+z] = zacc;
      }
    }
  }
  __syncthreads();
  const int srcg[3] = {0,2,1};
  const int dstg[3] = {1,3,4};
  for(int c=0;c<3;c++){
    for(int z=0;z<2;z++){
      int g = (z==0) ? srcg[c] : dstg[c];
      for(int t=0;t<NTY;t++){
        int tiles = (cntall[g*NTY+t]+31)>>5;
        for(int i=threadIdx.x; i<tiles; i+=blockDim.x)
          tdesc[c*TDSTRIDE + start[c][z][t] + i] = (int)(((unsigned)z<<31) | ((unsigned)t<<28) | (unsigned)(i<<5));
      }
    }
  }
}

// ---- weight prepack: fp32 -> bf16 + MFMA B-fragment swizzle.
__global__ void k_prepack(const float* convK, const float* convV, const float* convQ,
                          const float* convO, short* Wsw){
  int m = blockIdx.x;          // 0..63
  int fam = m >> 4;
  int lt = m & 15;             // layer*4 + type
  const float* src = (fam==0?convK:fam==1?convV:fam==2?convQ:convO) + (size_t)lt*HH*HH;
  short* dst = Wsw + (size_t)m*16384;
  for(int s=0;s<64;s++){
    int i = threadIdx.x + 256*s;
    int j = i & 7, lane = (i>>3)&63, kc = (i>>9)&3, nt = i>>11;
    int k = kc*32 + (lane>>4)*8 + j;
    int n = nt*16 + (lane&15);
    dst[i] = f2bf(src[k*HH+n]);
  }
}

// ---- fused KV (z=0) + Q (z=1) projection via MFMA; compacted 1-D tile list,
// float4 staging, warp-level LN reduce (float4 LDS reads), float4 normalize pass.
__global__ __launch_bounds__(256) void k_gemm_kvq(
    const int* __restrict__ tdesc, const int* __restrict__ tcnt,
    const float* __restrict__ Xs, const int* __restrict__ src_nid, const int* __restrict__ smap,
    const float* __restrict__ sdia,
    const int* __restrict__ idxs, const int* __restrict__ cnts_s, int stride_s,
    const bfrag* __restrict__ WK, const bfrag* __restrict__ WV, unsigned* __restrict__ KVp,
    const float* __restrict__ Xq, const int* __restrict__ qmap,
    const int* __restrict__ idxd, const int* __restrict__ cnts_d, int stride_d,
    const bfrag* __restrict__ WQ, float* __restrict__ Qbuf){
  __shared__ float xs[32*132];
  __shared__ float mean_s[32], inv_s[32];
  __shared__ int sid[32], nid[32], xrow[32];
  int ntk = tcnt[0], ntq = tcnt[1];
  int bid = blockIdx.x;
  if(bid >= ntk + ntq) return;
  unsigned ud = (unsigned)tdesc[bid];
  int isQ = ud >> 31;
  int t = (ud >> 28) & 7;
  int base = ud & 0x0FFFFFFF;
  int tid = threadIdx.x;
  int cnt = isQ ? cnts_d[t] : cnts_s[t];
  if(base >= cnt) return;
  int nn = min(32, cnt - base);
  const float* X = isQ ? Xq : Xs;
  const int* map = isQ ? qmap : smap;
  const int* ids = (isQ ? idxd + (size_t)t*stride_d : idxs + (size_t)t*stride_s) + base;
  if(tid < 32){
    int s_ = (tid < nn) ? ids[tid] : ids[0];
    sid[tid] = s_;
    if(!isQ) nid[tid] = src_nid[s_];
    xrow[tid] = map ? map[s_] : s_;
  }
  __syncthreads();
  // float4 staging: 1024 float4 = 32 rows x 128 cols
  #pragma unroll
  for(int s=0;s<4;s++){
    int e4 = tid + 256*s;
    int j = e4 >> 5, c4 = (e4 & 31)*4;
    *(float4*)&xs[j*132 + c4] = *(const float4*)&X[(size_t)xrow[j]*HH + c4];
  }
  __syncthreads();
  // warp-level LN reduce: 8 lanes per row, float4 LDS reads, shfl_xor over p
  {
    int wid = tid >> 6, lane = tid & 63;
    int row = wid*8 + (lane>>3), p = lane & 7;
    const float* xr = xs + row*132 + p*16;
    float sm=0.f, sq=0.f;
    #pragma unroll
    for(int i=0;i<4;i++){
      float4 v = *(const float4*)(xr + i*4);
      sm += (v.x+v.y)+(v.z+v.w);
      sq += (v.x*v.x+v.y*v.y)+(v.z*v.z+v.w*v.w);
    }
    sm += __shfl_xor(sm, 1, 64); sq += __shfl_xor(sq, 1, 64);
    sm += __shfl_xor(sm, 2, 64); sq += __shfl_xor(sq, 2, 64);
    sm += __shfl_xor(sm, 4, 64); sq += __shfl_xor(sq, 4, 64);
    if(p == 0){
      float mean = sm*(1.f/128.f);
      float var = sq*(1.f/128.f) - mean*mean;
      mean_s[row] = mean;
      inv_s[row] = 1.f/sqrtf(fmaxf(var,0.f)+1e-5f);
    }
  }
  __syncthreads();
  // float4 normalize pass (+ sdia time-mod on cols 64..127 for the KV path)
  #pragma unroll
  for(int s=0;s<4;s++){
    int e4 = tid + 256*s;
    int j = e4 >> 5, c4 = (e4 & 31)*4;
    float* px = &xs[j*132 + c4];
    float4 v = *(float4*)px;
    float mj = mean_s[j], ij = inv_s[j];
    v.x = (v.x-mj)*ij; v.y = (v.y-mj)*ij; v.z = (v.z-mj)*ij; v.w = (v.w-mj)*ij;
    if(!isQ && c4 >= D2C){
      float4 sd = *(const float4*)(sdia + (size_t)nid[j]*64 + (c4 - D2C));
      v.x *= sd.x; v.y *= sd.y; v.z *= sd.z; v.w *= sd.w;
    }
    *(float4*)px = v;
  }
  __syncthreads();
  int lane = tid & 63, w = tid >> 6;
  int mt = w & 1, ng0 = (w>>1)*4;
  int arow = mt*16 + (lane & 15);
  int koff = (lane >> 4)*8;
  int tb = t*2048;
  if(!isQ){
    ffrag aK[4], aV[4];
    #pragma unroll
    for(int i=0;i<4;i++){ aK[i] = (ffrag){0.f,0.f,0.f,0.f}; aV[i] = (ffrag){0.f,0.f,0.f,0.f}; }
    #pragma unroll
    for(int kc=0;kc<4;kc++){
      const float* ap = xs + arow*132 + kc*32 + koff;
      bfrag a;
      #pragma unroll
      for(int j=0;j<8;j++) a[j] = f2bf(ap[j]);
      #pragma unroll
      for(int nt=0;nt<4;nt++){
        int fi = tb + ((ng0+nt)*4 + kc)*64 + lane;
        bfrag bk = WK[fi];
        bfrag bv = WV[fi];
        aK[nt] = __builtin_amdgcn_mfma_f32_16x16x32_bf16(a, bk, aK[nt], 0, 0, 0);
        aV[nt] = __builtin_amdgcn_mfma_f32_16x16x32_bf16(a, bv, aV[nt], 0, 0, 0);
      }
    }
    int col0 = lane & 15;
    int rb = mt*16 + (lane>>4)*4;
    #pragma unroll
    for(int nt=0;nt<4;nt++){
      int col = (ng0+nt)*16 + col0;
      #pragma unroll
      for(int i=0;i<4;i++){
        int n = rb + i;
        if(n < nn){
          unsigned pk = (unsigned short)f2bf(aK[nt][i]);
          unsigned pv = (unsigned short)f2bf(aV[nt][i]);
          KVp[(size_t)sid[n]*HH + col] = (pv<<16) | pk;
        }
      }
    }
  } else {
    ffrag acc[4];
    #pragma unroll
    for(int i=0;i<4;i++) acc[i] = (ffrag){0.f,0.f,0.f,0.f};
    #pragma unroll
    for(int kc=0;kc<4;kc++){
      const float* ap = xs + arow*132 + kc*32 + koff;
      bfrag a;
      #pragma unroll
      for(int j=0;j<8;j++) a[j] = f2bf(ap[j]);
      #pragma unroll
      for(int nt=0;nt<4;nt++){
        bfrag b = WQ[tb + ((ng0+nt)*4 + kc)*64 + lane];
        acc[nt] = __builtin_amdgcn_mfma_f32_16x16x32_bf16(a, b, acc[nt], 0, 0, 0);
      }
    }
    int col0 = lane & 15;
    int rb = mt*16 + (lane>>4)*4;
    #pragma unroll
    for(int nt=0;nt<4;nt++){
      int col = (ng0+nt)*16 + col0;
      #pragma unroll
      for(int i=0;i<4;i++){
        int n = rb + i;
        if(n < nn) Qbuf[(size_t)sid[n]*HH + col] = acc[nt][i];
      }
    }
  }
}

// ---- O projection via MFMA (resid+relu, optional copy); compacted dst tile list.
__global__ __launch_bounds__(256) void k_gemm_t5(
    const int* __restrict__ tdesc, const int* __restrict__ tcnt,
    const float* X, const int* idxb, const int* cnts, int stride,
    const bfrag* W, const float* resid, const int* rmap, float* Y, float* Y2,
    int relu){
  __shared__ float xs[32*132];
  __shared__ int sid[32], rrow[32];
  int ntk = tcnt[0], ntq = tcnt[1];
  if(blockIdx.x >= ntq) return;
  unsigned ud = (unsigned)tdesc[ntk + blockIdx.x];
  int t = (ud >> 28) & 7;
  int base = ud & 0x0FFFFFFF;
  int cnt = cnts[t];
  if(base >= cnt) return;
  int nn = min(32, cnt - base);
  const int* ids = idxb + (size_t)t*stride + base;
  int tid = threadIdx.x;
  if(tid < 32){
    int s_ = (tid < nn) ? ids[tid] : ids[0];
    sid[tid] = s_;
    rrow[tid] = rmap ? rmap[s_] : s_;
  }
  __syncthreads();
  #pragma unroll
  for(int s=0;s<4;s++){
    int e4 = tid + 256*s;
    int j = e4 >> 5, c4 = (e4 & 31)*4;
    *(float4*)&xs[j*132 + c4] = *(const float4*)&X[(size_t)sid[j]*HH + c4];
  }
  __syncthreads();
  int lane = tid & 63, w = tid >> 6;
  int mt = w & 1, ng0 = (w>>1)*4;
  int arow = mt*16 + (lane & 15);
  int koff = (lane >> 4)*8;
  int tb = t*2048;
  ffrag acc[4];
  #pragma unroll
  for(int i=0;i<4;i++) acc[i] = (ffrag){0.f,0.f,0.f,0.f};
  #pragma unroll
  for(int kc=0;kc<4;kc++){
    const float* ap = xs + arow*132 + kc*32 + koff;
    bfrag a;
    #pragma unroll
    for(int j=0;j<8;j++) a[j] = f2bf(ap[j]);
    #pragma unroll
    for(int nt=0;nt<4;nt++){
      bfrag b = W[tb + ((ng0+nt)*4 + kc)*64 + lane];
      acc[nt] = __builtin_amdgcn_mfma_f32_16x16x32_bf16(a, b, acc[nt], 0, 0, 0);
    }
  }
  int col0 = lane & 15;
  int rb = mt*16 + (lane>>4)*4;
  #pragma unroll
  for(int nt=0;nt<4;nt++){
    int col = (ng0+nt)*16 + col0;
    #pragma unroll
    for(int i=0;i<4;i++){
      int n = rb + i;
      if(n < nn){
        size_t r = (size_t)sid[n]*HH + col;
        float v = acc[nt][i];
        if(resid){
          v += resid[(size_t)rrow[n]*HH + col];
          if(relu) v = fmaxf(v, 0.f);
        }
        Y[r] = v;
        if(Y2) Y2[r] = v;
      }
    }
  }
}

// EW2all[layer][50][128] = edge_emb @ convE[layer]
__global__ void k_edge_tab4(const float* edge_emb, const float* convE, float* EW2all){
  int r = blockIdx.x; int layer = blockIdx.y; int o = threadIdx.x;
  const float* EWp = convE + (size_t)layer*32*HH;
  float acc = 0.f;
  for(int j=0;j<32;j++) acc += edge_emb[r*32+j]*EWp[j*HH+o];
  EW2all[((size_t)layer*50 + r)*HH + o] = acc;
}

// ---------------- CSR build (batched over 3 graphs) ----------------
__global__ void k_hist_dst(const int* edst, int E, int* cnt){
  int e = blockIdx.x*256 + threadIdx.x;
  if(e < E) atomicAdd(&cnt[edst[e]], 1);
}
// one block per graph: exclusive scan -> row_ptr + cursor
__global__ void k_scan3(const int* c1, int n1, int* r1, int* u1,
                        const int* c2, int n2, int* r2, int* u2,
                        const int* c3, int n3, int* r3, int* u3){
  __shared__ int tsum[1024];
  const int* cnt; int n; int* row_ptr; int* cursor;
  if(blockIdx.x == 0){ cnt=c1; n=n1; row_ptr=r1; cursor=u1; }
  else if(blockIdx.x == 1){ cnt=c2; n=n2; row_ptr=r2; cursor=u2; }
  else { cnt=c3; n=n3; row_ptr=r3; cursor=u3; }
  int tid = threadIdx.x;
  int per = (n + 1023) / 1024;
  int start = tid*per; int end = min(start+per, n);
  int s = 0;
  for(int i=start;i<end;i++) s += cnt[i];
  tsum[tid] = s; __syncthreads();
  for(int off=1;off<1024;off<<=1){
    int v = (tid>=off) ? tsum[tid-off] : 0;
    __syncthreads();
    tsum[tid] += v;
    __syncthreads();
  }
  int run = (tid==0) ? 0 : tsum[tid-1];
  for(int i=start;i<end;i++){ row_ptr[i]=run; cursor[i]=run; run += cnt[i]; }
  if(end == n) row_ptr[n] = run;
}
// fill + permute merged: meta[pos] = {esrc, ew|ety<<16}
__global__ void k_fillperm(const int* edst, const int* esrc, const int* ew, const int* ety,
                           int E, int* cursor, int2* meta){
  int e = blockIdx.x*256 + threadIdx.x;
  if(e >= E) return;
  int pos = atomicAdd(&cursor[edst[e]], 1);
  meta[pos] = make_int2(esrc[e], ew[e] | (ety[e]<<16));
}

// single-pass attention on packed bf16 KV; 8-edge ILP, packed int2 edge meta,
// 0.25 scale folded into q.
__global__ void k_attn_fused8(const int* __restrict__ row_ptr, const int2* __restrict__ meta,
                              const unsigned* __restrict__ KVp, const float* __restrict__ Qbuf,
                              const float* __restrict__ EW2, const float* __restrict__ mu,
                              float* __restrict__ Abuf){
  int d = blockIdx.x; int o = threadIdx.x;
  int r0 = row_ptr[d], r1 = row_ptr[d+1];
  __shared__ float q[HH];
  q[o] = Qbuf[(size_t)d*HH+o]*0.25f;
  __syncthreads();
  int h = o >> 4;
  float qo = q[o];
  float dn0=0.f, dn1=0.f, dn2=0.f, dn3=0.f;
  float ac0=0.f, ac1=0.f, ac2=0.f, ac3=0.f;
  int r = r0;
  for(; r+7 < r1; r += 8){
    int2 m[8]; unsigned u[8]; float e[8]; float p[8];
    #pragma unroll
    for(int j=0;j<8;j++) m[j] = meta[r+j];
    #pragma unroll
    for(int j=0;j<8;j++) u[j] = KVp[(size_t)m[j].x*HH + o];
    #pragma unroll
    for(int j=0;j<8;j++) e[j] = EW2[(m[j].y & 0xffff)*HH + o];
    #pragma unroll
    for(int j=0;j<8;j++) p[j] = qo*(__uint_as_float(u[j]<<16) + e[j]);
    #pragma unroll
    for(int j=0;j<8;j++) p[j] += __shfl_xor(p[j], 1, 64);
    #pragma unroll
    for(int j=0;j<8;j++) p[j] += __shfl_xor(p[j], 2, 64);
    #pragma unroll
    for(int j=0;j<8;j++) p[j] += __shfl_xor(p[j], 4, 64);
    #pragma unroll
    for(int j=0;j<8;j++) p[j] += __shfl_xor(p[j], 8, 64);
    float ex[8];
    #pragma unroll
    for(int j=0;j<8;j++) ex[j] = __expf(p[j]*mu[(m[j].y>>16)*NH+h]);
    dn0 += ex[0]+ex[4]; dn1 += ex[1]+ex[5]; dn2 += ex[2]+ex[6]; dn3 += ex[3]+ex[7];
    ac0 += ex[0]*__uint_as_float(u[0]&0xffff0000u) + ex[4]*__uint_as_float(u[4]&0xffff0000u);
    ac1 += ex[1]*__uint_as_float(u[1]&0xffff0000u) + ex[5]*__uint_as_float(u[5]&0xffff0000u);
    ac2 += ex[2]*__uint_as_float(u[2]&0xffff0000u) + ex[6]*__uint_as_float(u[6]&0xffff0000u);
    ac3 += ex[3]*__uint_as_float(u[3]&0xffff0000u) + ex[7]*__uint_as_float(u[7]&0xffff0000u);
  }
  for(; r+3 < r1; r += 4){
    int2 m[4]; unsigned u[4]; float e[4]; float p[4];
    #pragma unroll
    for(int j=0;j<4;j++) m[j] = meta[r+j];
    #pragma unroll
    for(int j=0;j<4;j++) u[j] = KVp[(size_t)m[j].x*HH + o];
    #pragma unroll
    for(int j=0;j<4;j++) e[j] = EW2[(m[j].y & 0xffff)*HH + o];
    #pragma unroll
    for(int j=0;j<4;j++) p[j] = qo*(__uint_as_float(u[j]<<16) + e[j]);
    #pragma unroll
    for(int j=0;j<4;j++) p[j] += __shfl_xor(p[j], 1, 64);
    #pragma unroll
    for(int j=0;j<4;j++) p[j] += __shfl_xor(p[j], 2, 64);
    #pragma unroll
    for(int j=0;j<4;j++) p[j] += __shfl_xor(p[j], 4, 64);
    #pragma unroll
    for(int j=0;j<4;j++) p[j] += __shfl_xor(p[j], 8, 64);
    float ex[4];
    #pragma unroll
    for(int j=0;j<4;j++) ex[j] = __expf(p[j]*mu[(m[j].y>>16)*NH+h]);
    dn0 += ex[0]; dn1 += ex[1]; dn2 += ex[2]; dn3 += ex[3];
    ac0 += ex[0]*__uint_as_float(u[0]&0xffff0000u);
    ac1 += ex[1]*__uint_as_float(u[1]&0xffff0000u);
    ac2 += ex[2]*__uint_as_float(u[2]&0xffff0000u);
    ac3 += ex[3]*__uint_as_float(u[3]&0xffff0000u);
  }
  for(; r < r1; r++){
    int2 m = meta[r];
    unsigned u = KVp[(size_t)m.x*HH + o];
    float p = qo*(__uint_as_float(u<<16) + EW2[(m.y & 0xffff)*HH + o]);
    p += __shfl_xor(p, 1, 64);
    p += __shfl_xor(p, 2, 64);
    p += __shfl_xor(p, 4, 64);
    p += __shfl_xor(p, 8, 64);
    float ex = __expf(p*mu[(m.y>>16)*NH+h]);
    dn0 += ex; ac0 += ex*__uint_as_float(u&0xffff0000u);
  }
  float dd = (dn0+dn1)+(dn2+dn3), acc = (ac0+ac1)+(ac2+ac3);
  Abuf[(size_t)d*HH + o] = acc / fmaxf(dd, 1e-9f);
}

// ---------------- stage D: token pooling ----------------
__global__ void k_tokatt(const float* h2f, const int* toknt, const float* ipW, const float* iaW,
                         float* abuf, unsigned* amax, const int* tokid){
  int t = blockIdx.x; int o = threadIdx.x;
  __shared__ float es[HH];
  __shared__ float red[HH];
  int b = t % BB, l = t / BB;
  es[o] = h2f[(b*LL+l)*HH+o];
  __syncthreads();
  int nt = toknt[t];
  const float* w = ipW + (size_t)nt*HH*HH;
  float acc = 0.f;
  for(int j=0;j<HH;j++) acc += es[j]*w[j*HH+o];
  float u = tanhfast(acc);
  red[o] = u * iaW[nt*HH+o];
  __syncthreads();
  for(int s=64;s>0;s>>=1){ if(o<s) red[o]+=red[o+s]; __syncthreads(); }
  if(o==0){
    float a = red[0];
    abuf[t] = a;
    atomicMax(&amax[tokid[t]], fenc(a));
  }
}

__global__ void k_tokexp(const int* tokid, float* abuf, const unsigned* amax, float* aden, float* cnt){
  int t = blockIdx.x*blockDim.x + threadIdx.x;
  if(t >= TT) return;
  int c = tokid[t];
  float ex = __expf(abuf[t]-fdec(amax[c]));
  abuf[t] = ex;
  atomicAdd(&aden[c], ex);
  atomicAdd(&cnt[c], 1.f);
}

__global__ void k_tokagg(const int* tokid, const float* abuf, const float* aden,
                         const float* h2f, float* hist2){
  int t = blockIdx.x; int o = threadIdx.x;
  int c = tokid[t];
  float w = abuf[t]/fmaxf(aden[c],1e-9f);
  int b = t % BB, l = t / BB;
  atomicAdd(&hist2[c*HH+o], w*h2f[(b*LL+l)*HH+o]);
}

__global__ void k_histfix(const float* cnt, const float* hist_emb, float* hist2){
  int c = blockIdx.x; int o = threadIdx.x;
  if(cnt[c] == 0.f) hist2[c*HH+o] = hist_emb[c*HH+o];
}

// ---------------- parent pooling ----------------
__global__ void k_peagg(const int* pe_p, const int* pe_c, const float* cef, float* psum, float* pcnt){
  int i = blockIdx.x; int o = threadIdx.x;
  int p = pe_p[i], c = pe_c[i];
  atomicAdd(&psum[p*HH+o], cef[c*HH+o]);
  if(o==0) atomicAdd(&pcnt[p], 1.f);
}

__global__ void k_parent(const float* psum, const float* pcnt, float* out){
  int i = blockIdx.x; int o = threadIdx.x;
  out[i*HH+o] = psum[i*HH+o]/fmaxf(pcnt[i],1.f);
}

extern "C" void kernel_launch(void* const* d_in, const int* in_sizes, int n_in,
                              void* d_out, int out_size, void* d_ws, size_t ws_size,
                              hipStream_t stream){
  const int* seq     = (const int*)d_in[0];
  const int* seq_nt  = (const int*)d_in[1];
  const int* dur     = (const int*)d_in[2];
  const int* stime   = (const int*)d_in[3];
  const int* etime   = (const int*)d_in[4];
  const int* g1_nid  = (const int*)d_in[5];
  const int* g1_nt   = (const int*)d_in[6];
  const int* g1_esrc = (const int*)d_in[7];
  const int* g1_edst = (const int*)d_in[8];
  const int* g1_ety  = (const int*)d_in[9];
  const int* g1_ew   = (const int*)d_in[10];
  const int* g2_sel  = (const int*)d_in[11];
  const int* g2_esrc = (const int*)d_in[12];
  const int* g2_edst = (const int*)d_in[13];
  const int* g2_ety  = (const int*)d_in[14];
  const int* g2_ew   = (const int*)d_in[15];
  const int* tok_sel = (const int*)d_in[16];
  const int* g4_esrc = (const int*)d_in[17];
  const int* g4_edst = (const int*)d_in[18];
  const int* g4_ety  = (const int*)d_in[19];
  const int* g4_ew   = (const int*)d_in[20];
  const int* pe_p    = (const int*)d_in[21];
  const int* pe_c    = (const int*)d_in[22];
  const float* emb     = (const float*)d_in[23];
  const float* hist_emb= (const float*)d_in[24];
  const float* edge_emb= (const float*)d_in[25];
  const float* dia_w   = (const float*)d_in[26];
  const float* dia_b   = (const float*)d_in[27];
  const float* t2v_w   = (const float*)d_in[28];
  const float* t2v_b   = (const float*)d_in[29];
  const float* exp_W   = (const float*)d_in[30];
  const float* exp_b   = (const float*)d_in[31];
  const float* l1Wi    = (const float*)d_in[32];
  const float* l1Wh    = (const float*)d_in[33];
  const float* l1b     = (const float*)d_in[34];
  const float* l2Wi    = (const float*)d_in[35];
  const float* l2Wh    = (const float*)d_in[36];
  const float* l2b     = (const float*)d_in[37];
  const float* convK   = (const float*)d_in[38];
  const float* convQ   = (const float*)d_in[39];
  const float* convV   = (const float*)d_in[40];
  const float* convO   = (const float*)d_in[41];
  const float* convE   = (const float*)d_in[42];
  const float* convMu  = (const float*)d_in[43];
  const float* ipW     = (const float*)d_in[44];
  const float* iaW     = (const float*)d_in[45];
  const float* skip    = (const float*)d_in[46];
  float* outp = (float*)d_out;

  // workspace arena
  char* wsp = (char*)d_ws;
  size_t off = 0;
  auto A = [&](size_t nbytes)->char*{ char* p = wsp+off; off += (nbytes+255)&~(size_t)255; return p; };
  float*    srcbuf = (float*)   A((size_t)N1SN*HH*4);
  unsigned* KVp    = (unsigned*)A((size_t)N1SN*HH*4);    // packed bf16 [V|K]
  float*    Qbuf   = (float*)   A((size_t)N1DN*HH*4);
  float*    Abuf   = (float*)   A((size_t)N1DN*HH*4);
  float*    xbuf   = (float*)   A((size_t)TT*HH*4);
  float*    gpre   = (float*)   A((size_t)TT*512*4);
  float*    h1     = (float*)   A((size_t)TT*HH*4);
  float*    dst2   = (float*)   A((size_t)TT*HH*4);
  float*    xg     = (float*)   A((size_t)N1DN*HH*4);
  float*    x2     = (float*)   A((size_t)TT*HH*4);
  float*    h2f    = (float*)   A((size_t)TT*HH*4);
  float*    hist2  = (float*)   A((size_t)CHILDN*HH*4);
  float*    cnt    = (float*)   A((size_t)CHILDN*4);
  float*    abuf   = (float*)   A((size_t)TT*4);
  unsigned* amax   = (unsigned*)A((size_t)CHILDN*4);
  float*    aden   = (float*)   A((size_t)CHILDN*4);
  float*    x3     = (float*)   A((size_t)N1DN*HH*4);
  float*    cef    = (float*)   A((size_t)N4DN*HH*4);
  float*    psum   = (float*)   A((size_t)PARENTN*HH*4);
  float*    pcnt   = (float*)   A((size_t)PARENTN*4);
  float*    sdia   = (float*)   A((size_t)CHILDN*64*4);  // sin(dia_w+dia_b) cols 64..127
  int*      tokid  = (int*)     A((size_t)TT*4);
  int*      toknt  = (int*)     A((size_t)TT*4);
  int*      gnid2  = (int*)     A((size_t)N2N*4);
  int*      idxS1  = (int*)     A((size_t)NTY*N1SN*4);
  int*      idxS2  = (int*)     A((size_t)NTY*N1DN*4);
  int*      idxS3  = (int*)     A((size_t)NTY*N2N*4);
  int*      idxS4  = (int*)     A((size_t)NTY*TT*4);
  int*      idxS5  = (int*)     A((size_t)NTY*N4DN*4);
  int*      cntall = (int*)     A((size_t)5*NTY*4);
  int*      tdesc  = (int*)     A((size_t)3*TDSTRIDE*4);
  int*      tcnt   = (int*)     A((size_t)8*4);
  float*    EW2all = (float*)   A((size_t)4*50*HH*4);
  short*    Wsw    = (short*)   A((size_t)64*16384*2);   // bf16-swizzled weights
  int*      g1row  = (int*)     A((size_t)(N1DN+1)*4);
  int2*     g1meta = (int2*)    A((size_t)E1N*8);
  int*      g2row  = (int*)     A((size_t)(TT+1)*4);
  int2*     g2meta = (int2*)    A((size_t)E2N*8);
  int*      g4row  = (int*)     A((size_t)(N4DN+1)*4);
  int2*     g4meta = (int2*)    A((size_t)E4N*8);
  int*      icnt1  = (int*)     A((size_t)(N1DN+1)*4);
  int*      icur1  = (int*)     A((size_t)(N1DN+1)*4);
  int*      icnt2  = (int*)     A((size_t)(TT+1)*4);
  int*      icur2  = (int*)     A((size_t)(TT+1)*4);
  int*      icnt3  = (int*)     A((size_t)(N4DN+1)*4);
  int*      icur3  = (int*)     A((size_t)(N4DN+1)*4);
  if(off > ws_size) return;  // insufficient scratch: output stays zero

  auto run_conv = [&](int cfg, int gkvq, int gq,
                      const float* src_X, const int* src_nid, const int* srcmap,
                      const int* idx_src, int* cnt_src, int stride_src,
                      const float* q_X, const int* q_map,
                      const float* resid_X, const int* r_map, int ndst,
                      const int* idx_dst, int* cnt_dst, int stride_dst,
                      const int* rowp, const int2* meta,
                      int layer, float* outbuf, float* out2, int relu){
    const bfrag* WB = (const bfrag*)Wsw;
    const bfrag* WK = WB + (size_t)( 0 + layer*4)*2048;
    const bfrag* WV = WB + (size_t)(16 + layer*4)*2048;
    const bfrag* WQ = WB + (size_t)(32 + layer*4)*2048;
    const bfrag* WO = WB + (size_t)(48 + layer*4)*2048;
    const float* MU  = convMu + (size_t)layer*NRL*NH;
    const float* EW2 = EW2all + (size_t)layer*50*HH;
    const int* td = tdesc + (size_t)cfg*TDSTRIDE;
    const int* tc = tcnt + cfg*2;
    k_gemm_kvq<<<gkvq, 256, 0, stream>>>(td, tc, src_X, src_nid, srcmap, sdia,
                                         idx_src, cnt_src, stride_src, WK, WV, KVp,
                                         q_X, q_map, idx_dst, cnt_dst, stride_dst, WQ, Qbuf);
    k_attn_fused8<<<ndst, HH, 0, stream>>>(rowp, meta, KVp, Qbuf, EW2, MU, Abuf);
    k_gemm_t5<<<gq, 256, 0, stream>>>(td, tc, Abuf, idx_dst, cnt_dst, stride_dst, WO,
                                      resid_X, r_map, outbuf, out2, relu);
  };

  // ---- upfront: init, sin table, weight prepack, edge tables, scatters, tiles, CSR ----
  k_init<<<(CHILDN*HH+255)/256, 256, 0, stream>>>(hist2, cnt, amax, aden, psum, pcnt, cntall,
                                                  icnt1, icnt2, icnt3);
  k_sindia<<<(CHILDN*64+255)/256, 256, 0, stream>>>(dia_w, dia_b, sdia);
  k_prepack<<<64, 256, 0, stream>>>(convK, convV, convQ, convO, Wsw);
  k_edge_tab4<<<dim3(50,4), HH, 0, stream>>>(edge_emb, convE, EW2all);
  k_scatter3<<<(N1SN+255)/256, 256, 0, stream>>>(g1_nt, cntall+0*NTY, idxS1,
                                                 cntall+1*NTY, idxS2, cntall+4*NTY, idxS5);
  k_tokprep<<<(TT+255)/256, 256, 0, stream>>>(seq, seq_nt, tokid, toknt, cntall+3*NTY, idxS4);
  k_prep2scat<<<(N2N+255)/256, 256, 0, stream>>>(g2_sel, g1_nid, g1_nt, gnid2, cntall+2*NTY, idxS3);
  k_mktiles<<<1, 256, 0, stream>>>(cntall, tdesc, tcnt);
  k_hist_dst<<<(E1N+255)/256, 256, 0, stream>>>(g1_edst, E1N, icnt1);
  k_hist_dst<<<(E2N+255)/256, 256, 0, stream>>>(g2_edst, E2N, icnt2);
  k_hist_dst<<<(E4N+255)/256, 256, 0, stream>>>(g4_edst, E4N, icnt3);
  k_scan3<<<3, 1024, 0, stream>>>(icnt1, N1DN, g1row, icur1,
                                  icnt2, TT,   g2row, icur2,
                                  icnt3, N4DN, g4row, icur3);
  k_fillperm<<<(E1N+255)/256, 256, 0, stream>>>(g1_edst, g1_esrc, g1_ew, g1_ety, E1N, icur1, g1meta);
  k_fillperm<<<(E2N+255)/256, 256, 0, stream>>>(g2_edst, g2_esrc, g2_ew, g2_ety, E2N, icur2, g2meta);
  k_fillperm<<<(E4N+255)/256, 256, 0, stream>>>(g4_edst, g4_esrc, g4_ew, g4_ety, E4N, icur3, g4meta);

  // ---- stage A: features + LSTM1 (fused scan) ----
  k_featx2<<<TT/32, 512, 0, stream>>>(seq, dur, stime, etime, emb, dia_w, dia_b, t2v_w, t2v_b, exp_W, exp_b, xbuf);
  k_xwi2<<<(TT+15)/16, 256, 0, stream>>>(xbuf, l1Wi, l1b, gpre, TT, 0);
  k_lstm_fused<<<BB, 512, 0, stream>>>(gpre, l1Wh, h1, (float*)nullptr);

  // grid bounds (true tile counts are device-side; these are safe upper bounds)
  const int GKVQ_A = (N1SN+N1DN)/32 + 8;   // conv1 / conv3
  const int GKVQ_B = (N2N+TT)/32 + 8;      // conv2
  const int GKVQ_C = (N1DN+N4DN)/32 + 8;   // conv4
  const int GQ_A   = (N1DN+31)/32 + 4;
  const int GQ_B   = (TT+31)/32 + 4;
  const int GQ_C   = (N4DN+31)/32 + 4;

  // ---- conv1 on g1 (src/dst features gathered from emb via g1_nid in the gemms) ----
  run_conv(0, GKVQ_A, GQ_A,
           emb, g1_nid, g1_nid, idxS1, cntall+0*NTY, N1SN,
           emb, g1_nid,
           emb, g1_nid, N1DN, idxS2, cntall+1*NTY, N1DN,
           g1row, g1meta, 0, xg, (float*)nullptr, 1);

  // ---- conv2 on g2 (src features gathered from xg via g2_sel in the gemm) ----
  k_dst2<<<TT, HH, 0, stream>>>(tok_sel, xg, h1, dst2);
  run_conv(1, GKVQ_B, GQ_B,
           xg, gnid2, g2_sel, idxS3, cntall+2*NTY, N2N,
           dst2, (const int*)nullptr,
           dst2, (const int*)nullptr, TT, idxS4, cntall+3*NTY, TT,
           g2row, g2meta, 1, x2, (float*)nullptr, 1);

  // ---- LSTM2 (h2 is output 0); x2 read directly with permuted layout ----
  k_xwi2<<<(TT+15)/16, 256, 0, stream>>>(x2, l2Wi, l2b, gpre, TT, 1);
  k_lstm_fused<<<BB, 512, 0, stream>>>(gpre, l2Wh, h2f, outp);

  // ---- stage D: token attention pooling -> hist2 ----
  k_tokatt<<<TT, HH, 0, stream>>>(h2f, toknt, ipW, iaW, abuf, amax, tokid);
  k_tokexp<<<(TT+255)/256, 256, 0, stream>>>(tokid, abuf, amax, aden, cnt);
  k_tokagg<<<TT, HH, 0, stream>>>(tokid, abuf, aden, h2f, hist2);
  k_histfix<<<CHILDN, HH, 0, stream>>>(cnt, hist_emb, hist2);

  // ---- conv3 on g1 with skip-mixed input (g1 CSR + scatters + tiles reused) ----
  k_x0<<<N1SN, HH, 0, stream>>>(g1_nid, g1_nt, emb, hist2, skip, srcbuf);
  run_conv(0, GKVQ_A, GQ_A,
           srcbuf, g1_nid, (const int*)nullptr, idxS1, cntall+0*NTY, N1SN,
           srcbuf, (const int*)nullptr,
           srcbuf, (const int*)nullptr, N1DN, idxS2, cntall+1*NTY, N1DN,
           g1row, g1meta, 2, x3, (float*)nullptr, 1);

  // ---- conv4 on g4 (child_embed = output 1, no relu) ----
  run_conv(2, GKVQ_C, GQ_C,
           x3, g1_nid, (const int*)nullptr, idxS2, cntall+1*NTY, N1DN,
           x3, (const int*)nullptr,
           x3, (const int*)nullptr, N4DN, idxS5, cntall+4*NTY, N4DN,
           g4row, g4meta, 3, cef, outp + (size_t)TT*HH, 0);

  // ---- parent pooling (output 2) ----
  k_peagg<<<EC2PN, HH, 0, stream>>>(pe_p, pe_c, cef, psum, pcnt);
  k_parent<<<PARENTN, HH, 0, stream>>>(psum, pcnt, outp + (size_t)TT*HH + (size_t)N4DN*HH);
}

// Round 9
// 723.839 us; speedup vs baseline: 1.1028x; 1.0487x over previous
//
#include <hip/hip_runtime.h>
#include <math.h>

#define BB 256
#define LL 20
#define HH 128
#define NH 8
#define D2C 64
#define NTY 4
#define NRL 4
#define CHILDN 30001
#define PARENTN 500
#define N1SN 50000
#define N1DN 20000
#define E1N 300000
#define N2N 20000
#define E2N 200000
#define TT (BB*LL)
#define N4DN 5000
#define E4N 150000
#define EC2PN 8000
#define TDSTRIDE 2304

typedef __attribute__((ext_vector_type(8))) short bfrag;   // 8 bf16 in 4 VGPRs
typedef __attribute__((ext_vector_type(4))) float ffrag;   // MFMA accumulator

__device__ __forceinline__ unsigned fenc(float f){ unsigned u=__float_as_uint(f); return (u&0x80000000u)? ~u : (u|0x80000000u); }
__device__ __forceinline__ float fdec(unsigned u){ return (u&0x80000000u)? __uint_as_float(u^0x80000000u) : __uint_as_float(~u); }
__device__ __forceinline__ float sigfast(float x){ return 1.f/(1.f+__expf(-x)); }
__device__ __forceinline__ float tanhfast(float x){ float e = __expf(-2.f*x); return (1.f-e)/(1.f+e); }
__device__ __forceinline__ short f2bf(float f){
  unsigned u = __float_as_uint(f);
  unsigned r = u + 0x7FFFu + ((u>>16)&1u);   // round-to-nearest-even
  return (short)(r>>16);
}

// ---------------- upfront init: zero/poison buffers + sin table + weight prepack
// + edge tables, all folded into one grid (index-range dispatch) ----------------
__global__ void k_init(float* hist2, float* cnt, unsigned* amax, float* aden,
                       float* psum, float* pcnt, int* cntall,
                       int* icnt1, int* icnt2, int* icnt3,
                       const float* __restrict__ dia_w, const float* __restrict__ dia_b,
                       float* __restrict__ sdia,
                       const float* convK, const float* convV, const float* convQ,
                       const float* convO, short* Wsw,
                       const float* edge_emb, const float* convE, float* EW2all){
  int i = blockIdx.x*256 + threadIdx.x;
  if(i < CHILDN*HH) hist2[i] = 0.f;
  if(i < CHILDN){ cnt[i] = 0.f; aden[i] = 0.f; amax[i] = 0x007FFFFFu; }
  if(i < PARENTN*HH) psum[i] = 0.f;
  if(i < PARENTN) pcnt[i] = 0.f;
  if(i < 5*NTY) cntall[i] = 0;
  if(i < N1DN) icnt1[i] = 0;
  if(i < TT)   icnt2[i] = 0;
  if(i < N4DN) icnt3[i] = 0;
  if(i < CHILDN*64){
    int c = i >> 6, k = (i & 63) + 64;
    sdia[i] = __sinf(dia_w[(size_t)c*HH+k] + dia_b[(size_t)c*HH+k]);
  }
  if(i < 64*16384){
    int m = i >> 14, im = i & 16383;
    int fam = m >> 4, lt = m & 15;
    const float* src = (fam==0?convK:fam==1?convV:fam==2?convQ:convO) + (size_t)lt*HH*HH;
    int j = im & 7, lane = (im>>3)&63, kc = (im>>9)&3, nt = im>>11;
    int k = kc*32 + (lane>>4)*8 + j;
    int n = nt*16 + (lane&15);
    Wsw[(size_t)m*16384 + im] = f2bf(src[k*HH+n]);
  }
  if(i < 4*50*HH){
    int layer = i/(50*HH), rr = (i/HH)%50, o = i%HH;
    const float* EWp = convE + (size_t)layer*32*HH;
    float acc = 0.f;
    for(int j=0;j<32;j++) acc += edge_emb[rr*32+j]*EWp[j*HH+o];
    EW2all[i] = acc;
  }
}

// ---------------- Stage A: feature expansion (tiled: 32 tokens/block) ----------------
__global__ __launch_bounds__(512) void k_featx2(const int* __restrict__ seq, const int* __restrict__ dur,
                        const int* __restrict__ stime, const int* __restrict__ etime,
                        const float* __restrict__ emb, const float* __restrict__ dia_w, const float* __restrict__ dia_b,
                        const float* __restrict__ t2v_w, const float* __restrict__ t2v_b,
                        const float* __restrict__ exp_W, const float* __restrict__ exp_b, float* __restrict__ xout){
  __shared__ float feat[32*273];           // [st(128) | et(128) | tv(16)] per token, stride 273
  int base = blockIdx.x*32;
  int j = threadIdx.x >> 4;                // token 0..31
  int p = threadIdx.x & 15;                // 16 threads/token, 8 cols each
  int row = base + j;
  int node = seq[row];
  float ts = (float)stime[row], te = (float)etime[row];
  const float* ep = emb + (size_t)node*HH;
  float* fr = feat + j*273;
  int o0 = p*8;
  #pragma unroll
  for(int ii=0; ii<8; ii+=4){
    int o = o0 + ii;
    float4 e = *(const float4*)(ep + o);
    float4 st = e, et = e;
    if(o >= D2C){
      float4 w = *(const float4*)(dia_w + (size_t)node*HH + o);
      float4 b = *(const float4*)(dia_b + (size_t)node*HH + o);
      st.x = e.x*__sinf(w.x*ts+b.x); st.y = e.y*__sinf(w.y*ts+b.y);
      st.z = e.z*__sinf(w.z*ts+b.z); st.w = e.w*__sinf(w.w*ts+b.w);
      et.x = e.x*__sinf(w.x*te+b.x); et.y = e.y*__sinf(w.y*te+b.y);
      et.z = e.z*__sinf(w.z*te+b.z); et.w = e.w*__sinf(w.w*te+b.w);
    }
    fr[o] = st.x; fr[o+1] = st.y; fr[o+2] = st.z; fr[o+3] = st.w;
    fr[128+o] = et.x; fr[128+o+1] = et.y; fr[128+o+2] = et.z; fr[128+o+3] = et.w;
  }
  if(p == 0){
    float td = (float)dur[row];
    #pragma unroll
    for(int i=0;i<16;i++){
      float w = t2v_w[i], b = t2v_b[i];
      fr[256+i] = (i==0) ? (w*td + b) : __sinf(w*td + b);
    }
  }
  __syncthreads();
  // GEMM: 32x272 @ 272x128, each thread: 2 rows x 4 cols
  int oc = (threadIdx.x & 31)*4;
  int jg = threadIdx.x >> 5;               // 0..15
  const float* f0 = feat + (jg*2)*273;
  const float* f1 = feat + (jg*2+1)*273;
  float4 a0 = {0,0,0,0}, a1 = {0,0,0,0};
  for(int k=0;k<272;k++){
    float4 w = *(const float4*)(exp_W + (size_t)k*HH + oc);
    float x0 = f0[k], x1 = f1[k];
    a0.x += x0*w.x; a0.y += x0*w.y; a0.z += x0*w.z; a0.w += x0*w.w;
    a1.x += x1*w.x; a1.y += x1*w.y; a1.z += x1*w.z; a1.w += x1*w.w;
  }
  float4 bv = *(const float4*)(exp_b + oc);
  a0.x = fmaxf(a0.x+bv.x, 0.f); a0.y = fmaxf(a0.y+bv.y, 0.f);
  a0.z = fmaxf(a0.z+bv.z, 0.f); a0.w = fmaxf(a0.w+bv.w, 0.f);
  a1.x = fmaxf(a1.x+bv.x, 0.f); a1.y = fmaxf(a1.y+bv.y, 0.f);
  a1.z = fmaxf(a1.z+bv.z, 0.f); a1.w = fmaxf(a1.w+bv.w, 0.f);
  *(float4*)(xout + (size_t)(base + jg*2  )*HH + oc) = a0;
  *(float4*)(xout + (size_t)(base + jg*2+1)*HH + oc) = a1;
}

// tiled x @ Wi + b -> gpre: 16 rows x 512 cols per block; perm=1 reads x in (l*BB+b) layout
__global__ void k_xwi2(const float* x, const float* Wi, const float* bias, float* gpre, int rows, int perm){
  int base = blockIdx.x*16;
  __shared__ float xs[128*17];
  int tid = threadIdx.x;
  #pragma unroll
  for(int s=0;s<8;s++){
    int elem = tid + 256*s;
    int k = elem & 127, j = elem >> 7;
    int r = base + j;
    int src = r;
    if(perm) src = (r % LL)*BB + (r / LL);
    xs[k*17 + j] = (r < rows) ? x[(size_t)src*HH + k] : 0.f;
  }
  __syncthreads();
  int o4 = (tid & 127)*4;
  int ng = tid >> 7;
  float4 a[8];
  #pragma unroll
  for(int j=0;j<8;j++) a[j]=make_float4(0,0,0,0);
  for(int k=0;k<HH;k++){
    float4 w = *(const float4*)(Wi + (size_t)k*512 + o4);
    const float* xr = xs + k*17 + ng*8;
    #pragma unroll
    for(int j=0;j<8;j++){
      float xv = xr[j];
      a[j].x += xv*w.x; a[j].y += xv*w.y; a[j].z += xv*w.z; a[j].w += xv*w.w;
    }
  }
  float4 bv = *(const float4*)(bias + o4);
  #pragma unroll
  for(int j=0;j<8;j++){
    int r = base + ng*8 + j;
    if(r < rows){
      float4 v = a[j];
      v.x += bv.x; v.y += bv.y; v.z += bv.z; v.w += bv.w;
      *(float4*)(gpre + (size_t)r*512 + o4) = v;
    }
  }
}

// fused 20-step LSTM: one block per batch row, Wh column in registers, gpre
// prefetched into registers, activations spread across all 512 threads.
__global__ __launch_bounds__(512, 2) void k_lstm_fused(const float* __restrict__ gpre,
                                                       const float* __restrict__ Wh,
                                                       float* __restrict__ hout,
                                                       float* __restrict__ hout2){
  int b = blockIdx.x;
  int o = threadIdx.x;
  __shared__ float hs[HH];
  __shared__ float act[512];
  float wr[HH];
  #pragma unroll
  for(int h=0;h<HH;h++) wr[h] = Wh[(size_t)h*512 + o];
  float gv[LL];
  const float* gp = gpre + (size_t)b*LL*512 + o;
  #pragma unroll
  for(int l=0;l<LL;l++) gv[l] = gp[(size_t)l*512];
  if(o < HH) hs[o] = 0.f;
  float cc = 0.f;
  int quad = o >> 7;                        // 0=i, 1=f, 2=g, 3=o
  __syncthreads();
  for(int l=0;l<LL;l++){
    float a0=0.f,a1=0.f,a2=0.f,a3=0.f;
    #pragma unroll
    for(int h=0;h<HH;h+=4){
      float4 hv = *(const float4*)&hs[h];
      a0 += hv.x*wr[h];   a1 += hv.y*wr[h+1];
      a2 += hv.z*wr[h+2]; a3 += hv.w*wr[h+3];
    }
    float g = gv[l] + ((a0+a1)+(a2+a3));
    act[o] = (quad==2) ? tanhfast(g) : sigfast(g);
    __syncthreads();
    if(o < HH){
      cc = act[HH+o]*cc + act[o]*act[2*HH+o];
      float hh = act[3*HH+o]*tanhfast(cc);
      hs[o] = hh;
      size_t bi = ((size_t)b*LL + l)*HH + o;
      hout[bi] = hh;
      if(hout2) hout2[bi] = hh;
    }
    __syncthreads();
  }
}

// ---------------- merged scatters: scatter3 | tokprep | prep2scat (block ranges) ----------------
__global__ void k_scatall(const int* __restrict__ g1_nt, const int* __restrict__ seq,
                          const int* __restrict__ seq_nt, const int* __restrict__ g2_sel,
                          const int* __restrict__ g1_nid,
                          int* __restrict__ tokid, int* __restrict__ toknt, int* __restrict__ gnid2,
                          int* __restrict__ cntall,
                          int* __restrict__ idxS1, int* __restrict__ idxS2, int* __restrict__ idxS5,
                          int* __restrict__ idxS4, int* __restrict__ idxS3){
  const int B1 = (N1SN+255)/256;
  const int B2 = (TT+255)/256;
  __shared__ int h[3][NTY];
  __shared__ int bs[3][NTY];
  int bx = blockIdx.x;
  if(bx < B1){
    // 3-way type scatter of g1_nt prefixes
    int i = bx*256 + threadIdx.x;
    if(threadIdx.x < 3*NTY) (&h[0][0])[threadIdx.x] = 0;
    __syncthreads();
    int t = 0, r1 = 0, r2 = 0, r3 = 0;
    bool a1 = (i < N1SN), a2 = (i < N1DN), a3 = (i < N4DN);
    if(a1){
      t = g1_nt[i];
      r1 = atomicAdd(&h[0][t], 1);
      if(a2) r2 = atomicAdd(&h[1][t], 1);
      if(a3) r3 = atomicAdd(&h[2][t], 1);
    }
    __syncthreads();
    if(threadIdx.x < NTY){
      int ty = threadIdx.x;
      if(h[0][ty] > 0) bs[0][ty] = atomicAdd(&cntall[0*NTY+ty], h[0][ty]);
      if(h[1][ty] > 0) bs[1][ty] = atomicAdd(&cntall[1*NTY+ty], h[1][ty]);
      if(h[2][ty] > 0) bs[2][ty] = atomicAdd(&cntall[4*NTY+ty], h[2][ty]);
    }
    __syncthreads();
    if(a1) idxS1[t*N1SN + bs[0][t] + r1] = i;
    if(a2) idxS2[t*N1DN + bs[1][t] + r2] = i;
    if(a3) idxS5[t*N4DN + bs[2][t] + r3] = i;
  } else if(bx < B1 + B2){
    // token prep + scatter
    int i = (bx - B1)*256 + threadIdx.x;
    if(threadIdx.x < NTY) h[0][threadIdx.x] = 0;
    __syncthreads();
    int nt = 0, r = 0;
    bool act = (i < TT);
    if(act){
      int b = i % BB, l = i / BB;
      tokid[i] = seq[b*LL+l];
      nt = seq_nt[b*LL+l];
      toknt[i] = nt;
      r = atomicAdd(&h[0][nt], 1);
    }
    __syncthreads();
    if(threadIdx.x < NTY && h[0][threadIdx.x] > 0)
      bs[0][threadIdx.x] = atomicAdd(&cntall[3*NTY+threadIdx.x], h[0][threadIdx.x]);
    __syncthreads();
    if(act) idxS4[nt*TT + bs[0][nt] + r] = i;
  } else {
    // conv2 src prep + scatter
    int i = (bx - B1 - B2)*256 + threadIdx.x;
    if(threadIdx.x < NTY) h[0][threadIdx.x] = 0;
    __syncthreads();
    int nt = 0, r = 0;
    bool act = (i < N2N);
    if(act){
      int s = g2_sel[i];
      gnid2[i] = g1_nid[s];
      nt = g1_nt[s];
      r = atomicAdd(&h[0][nt], 1);
    }
    __syncthreads();
    if(threadIdx.x < NTY && h[0][threadIdx.x] > 0)
      bs[0][threadIdx.x] = atomicAdd(&cntall[2*NTY+threadIdx.x], h[0][threadIdx.x]);
    __syncthreads();
    if(act) idxS3[nt*N2N + bs[0][nt] + r] = i;
  }
}

__global__ void k_dst2(const int* tok_sel, const float* xg, const float* h1, float* dst2){
  int t = blockIdx.x; int o = threadIdx.x;
  int b = t % BB, l = t / BB;
  dst2[t*HH+o] = xg[tok_sel[t]*HH+o] + h1[(b*LL+l)*HH+o];
}

// skip-mixed input with histfix fused (cnt==0 -> hist_emb fallback)
__global__ void k_x0(const int* nid, const int* ntype, const float* emb, const float* hist2,
                     const float* cnt, const float* hist_emb, const float* skip, float* srcbuf){
  int i = blockIdx.x; int o = threadIdx.x;
  float a = sigfast(skip[ntype[i]]);
  int nd = nid[i];
  float hv = (cnt[nd] > 0.f) ? hist2[(size_t)nd*HH+o] : hist_emb[(size_t)nd*HH+o];
  srcbuf[i*HH+o] = emb[(size_t)nd*HH+o]*a + hv*(1.f-a);
}

// ---- tile-descriptor builder: compacted work lists for the 3 unique conv configs.
__global__ void k_mktiles(const int* __restrict__ cntall, int* __restrict__ tdesc, int* __restrict__ tcnt){
  __shared__ int start[3][2][NTY];
  if(threadIdx.x == 0){
    const int srcg[3] = {0,2,1};
    const int dstg[3] = {1,3,4};
    for(int c=0;c<3;c++){
      int acc = 0;
      for(int z=0;z<2;z++){
        int g = (z==0) ? srcg[c] : dstg[c];
        int zacc = 0;
        for(int t=0;t<NTY;t++){
          start[c][z][t] = acc;
          int tiles = (cntall[g*NTY+t]+31)>>5;
          acc += tiles; zacc += tiles;
        }
        tcnt[c*2+z] = zacc;
      }
    }
  }
  __syncthreads();
  const int srcg[3] = {0,2,1};
  const int dstg[3] = {1,3,4};
  for(int c=0;c<3;c++){
    for(int z=0;z<2;z++){
      int g = (z==0) ? srcg[c] : dstg[c];
      for(int t=0;t<NTY;t++){
        int tiles = (cntall[g*NTY+t]+31)>>5;
        for(int i=threadIdx.x; i<tiles; i+=blockDim.x)
          tdesc[c*TDSTRIDE + start[c][z][t] + i] = (int)(((unsigned)z<<31) | ((unsigned)t<<28) | (unsigned)(i<<5));
      }
    }
  }
}

// ---- fused KV (z=0) + Q (z=1) projection via MFMA; compacted 1-D tile list,
// float4 staging, warp-level LN reduce (float4 LDS reads), float4 normalize pass.
__global__ __launch_bounds__(256) void k_gemm_kvq(
    const int* __restrict__ tdesc, const int* __restrict__ tcnt,
    const float* __restrict__ Xs, const int* __restrict__ src_nid, const int* __restrict__ smap,
    const float* __restrict__ sdia,
    const int* __restrict__ idxs, const int* __restrict__ cnts_s, int stride_s,
    const bfrag* __restrict__ WK, const bfrag* __restrict__ WV, unsigned* __restrict__ KVp,
    const float* __restrict__ Xq, const int* __restrict__ qmap,
    const int* __restrict__ idxd, const int* __restrict__ cnts_d, int stride_d,
    const bfrag* __restrict__ WQ, float* __restrict__ Qbuf){
  __shared__ float xs[32*132];
  __shared__ float mean_s[32], inv_s[32];
  __shared__ int sid[32], nid[32], xrow[32];
  int ntk = tcnt[0], ntq = tcnt[1];
  int bid = blockIdx.x;
  if(bid >= ntk + ntq) return;
  unsigned ud = (unsigned)tdesc[bid];
  int isQ = ud >> 31;
  int t = (ud >> 28) & 7;
  int base = ud & 0x0FFFFFFF;
  int tid = threadIdx.x;
  int cnt = isQ ? cnts_d[t] : cnts_s[t];
  if(base >= cnt) return;
  int nn = min(32, cnt - base);
  const float* X = isQ ? Xq : Xs;
  const int* map = isQ ? qmap : smap;
  const int* ids = (isQ ? idxd + (size_t)t*stride_d : idxs + (size_t)t*stride_s) + base;
  if(tid < 32){
    int s_ = (tid < nn) ? ids[tid] : ids[0];
    sid[tid] = s_;
    if(!isQ) nid[tid] = src_nid[s_];
    xrow[tid] = map ? map[s_] : s_;
  }
  __syncthreads();
  // float4 staging: 1024 float4 = 32 rows x 128 cols
  #pragma unroll
  for(int s=0;s<4;s++){
    int e4 = tid + 256*s;
    int j = e4 >> 5, c4 = (e4 & 31)*4;
    *(float4*)&xs[j*132 + c4] = *(const float4*)&X[(size_t)xrow[j]*HH + c4];
  }
  __syncthreads();
  // warp-level LN reduce: 8 lanes per row, float4 LDS reads, shfl_xor over p
  {
    int wid = tid >> 6, lane = tid & 63;
    int row = wid*8 + (lane>>3), p = lane & 7;
    const float* xr = xs + row*132 + p*16;
    float sm=0.f, sq=0.f;
    #pragma unroll
    for(int i=0;i<4;i++){
      float4 v = *(const float4*)(xr + i*4);
      sm += (v.x+v.y)+(v.z+v.w);
      sq += (v.x*v.x+v.y*v.y)+(v.z*v.z+v.w*v.w);
    }
    sm += __shfl_xor(sm, 1, 64); sq += __shfl_xor(sq, 1, 64);
    sm += __shfl_xor(sm, 2, 64); sq += __shfl_xor(sq, 2, 64);
    sm += __shfl_xor(sm, 4, 64); sq += __shfl_xor(sq, 4, 64);
    if(p == 0){
      float mean = sm*(1.f/128.f);
      float var = sq*(1.f/128.f) - mean*mean;
      mean_s[row] = mean;
      inv_s[row] = 1.f/sqrtf(fmaxf(var,0.f)+1e-5f);
    }
  }
  __syncthreads();
  // float4 normalize pass (+ sdia time-mod on cols 64..127 for the KV path)
  #pragma unroll
  for(int s=0;s<4;s++){
    int e4 = tid + 256*s;
    int j = e4 >> 5, c4 = (e4 & 31)*4;
    float* px = &xs[j*132 + c4];
    float4 v = *(float4*)px;
    float mj = mean_s[j], ij = inv_s[j];
    v.x = (v.x-mj)*ij; v.y = (v.y-mj)*ij; v.z = (v.z-mj)*ij; v.w = (v.w-mj)*ij;
    if(!isQ && c4 >= D2C){
      float4 sd = *(const float4*)(sdia + (size_t)nid[j]*64 + (c4 - D2C));
      v.x *= sd.x; v.y *= sd.y; v.z *= sd.z; v.w *= sd.w;
    }
    *(float4*)px = v;
  }
  __syncthreads();
  int lane = tid & 63, w = tid >> 6;
  int mt = w & 1, ng0 = (w>>1)*4;
  int arow = mt*16 + (lane & 15);
  int koff = (lane >> 4)*8;
  int tb = t*2048;
  if(!isQ){
    ffrag aK[4], aV[4];
    #pragma unroll
    for(int i=0;i<4;i++){ aK[i] = (ffrag){0.f,0.f,0.f,0.f}; aV[i] = (ffrag){0.f,0.f,0.f,0.f}; }
    #pragma unroll
    for(int kc=0;kc<4;kc++){
      const float* ap = xs + arow*132 + kc*32 + koff;
      bfrag a;
      #pragma unroll
      for(int j=0;j<8;j++) a[j] = f2bf(ap[j]);
      #pragma unroll
      for(int nt=0;nt<4;nt++){
        int fi = tb + ((ng0+nt)*4 + kc)*64 + lane;
        bfrag bk = WK[fi];
        bfrag bv = WV[fi];
        aK[nt] = __builtin_amdgcn_mfma_f32_16x16x32_bf16(a, bk, aK[nt], 0, 0, 0);
        aV[nt] = __builtin_amdgcn_mfma_f32_16x16x32_bf16(a, bv, aV[nt], 0, 0, 0);
      }
    }
    int col0 = lane & 15;
    int rb = mt*16 + (lane>>4)*4;
    #pragma unroll
    for(int nt=0;nt<4;nt++){
      int col = (ng0+nt)*16 + col0;
      #pragma unroll
      for(int i=0;i<4;i++){
        int n = rb + i;
        if(n < nn){
          unsigned pk = (unsigned short)f2bf(aK[nt][i]);
          unsigned pv = (unsigned short)f2bf(aV[nt][i]);
          KVp[(size_t)sid[n]*HH + col] = (pv<<16) | pk;
        }
      }
    }
  } else {
    ffrag acc[4];
    #pragma unroll
    for(int i=0;i<4;i++) acc[i] = (ffrag){0.f,0.f,0.f,0.f};
    #pragma unroll
    for(int kc=0;kc<4;kc++){
      const float* ap = xs + arow*132 + kc*32 + koff;
      bfrag a;
      #pragma unroll
      for(int j=0;j<8;j++) a[j] = f2bf(ap[j]);
      #pragma unroll
      for(int nt=0;nt<4;nt++){
        bfrag b = WQ[tb + ((ng0+nt)*4 + kc)*64 + lane];
        acc[nt] = __builtin_amdgcn_mfma_f32_16x16x32_bf16(a, b, acc[nt], 0, 0, 0);
      }
    }
    int col0 = lane & 15;
    int rb = mt*16 + (lane>>4)*4;
    #pragma unroll
    for(int nt=0;nt<4;nt++){
      int col = (ng0+nt)*16 + col0;
      #pragma unroll
      for(int i=0;i<4;i++){
        int n = rb + i;
        if(n < nn) Qbuf[(size_t)sid[n]*HH + col] = acc[nt][i];
      }
    }
  }
}

// ---- O projection via MFMA (resid+relu, optional copy); compacted dst tile list.
__global__ __launch_bounds__(256) void k_gemm_t5(
    const int* __restrict__ tdesc, const int* __restrict__ tcnt,
    const float* X, const int* idxb, const int* cnts, int stride,
    const bfrag* W, const float* resid, const int* rmap, float* Y, float* Y2,
    int relu){
  __shared__ float xs[32*132];
  __shared__ int sid[32], rrow[32];
  int ntk = tcnt[0], ntq = tcnt[1];
  if(blockIdx.x >= ntq) return;
  unsigned ud = (unsigned)tdesc[ntk + blockIdx.x];
  int t = (ud >> 28) & 7;
  int base = ud & 0x0FFFFFFF;
  int cnt = cnts[t];
  if(base >= cnt) return;
  int nn = min(32, cnt - base);
  const int* ids = idxb + (size_t)t*stride + base;
  int tid = threadIdx.x;
  if(tid < 32){
    int s_ = (tid < nn) ? ids[tid] : ids[0];
    sid[tid] = s_;
    rrow[tid] = rmap ? rmap[s_] : s_;
  }
  __syncthreads();
  #pragma unroll
  for(int s=0;s<4;s++){
    int e4 = tid + 256*s;
    int j = e4 >> 5, c4 = (e4 & 31)*4;
    *(float4*)&xs[j*132 + c4] = *(const float4*)&X[(size_t)sid[j]*HH + c4];
  }
  __syncthreads();
  int lane = tid & 63, w = tid >> 6;
  int mt = w & 1, ng0 = (w>>1)*4;
  int arow = mt*16 + (lane & 15);
  int koff = (lane >> 4)*8;
  int tb = t*2048;
  ffrag acc[4];
  #pragma unroll
  for(int i=0;i<4;i++) acc[i] = (ffrag){0.f,0.f,0.f,0.f};
  #pragma unroll
  for(int kc=0;kc<4;kc++){
    const float* ap = xs + arow*132 + kc*32 + koff;
    bfrag a;
    #pragma unroll
    for(int j=0;j<8;j++) a[j] = f2bf(ap[j]);
    #pragma unroll
    for(int nt=0;nt<4;nt++){
      bfrag b = W[tb + ((ng0+nt)*4 + kc)*64 + lane];
      acc[nt] = __builtin_amdgcn_mfma_f32_16x16x32_bf16(a, b, acc[nt], 0, 0, 0);
    }
  }
  int col0 = lane & 15;
  int rb = mt*16 + (lane>>4)*4;
  #pragma unroll
  for(int nt=0;nt<4;nt++){
    int col = (ng0+nt)*16 + col0;
    #pragma unroll
    for(int i=0;i<4;i++){
      int n = rb + i;
      if(n < nn){
        size_t r = (size_t)sid[n]*HH + col;
        float v = acc[nt][i];
        if(resid){
          v += resid[(size_t)rrow[n]*HH + col];
          if(relu) v = fmaxf(v, 0.f);
        }
        Y[r] = v;
        if(Y2) Y2[r] = v;
      }
    }
  }
}

// ---------------- CSR build (merged over 3 graphs) ----------------
__global__ void k_hist3(const int* __restrict__ e1, const int* __restrict__ e2,
                        const int* __restrict__ e3, int* c1, int* c2, int* c3){
  const int B1 = (E1N+255)/256, B2 = (E2N+255)/256;
  int bx = blockIdx.x;
  if(bx < B1){ int e = bx*256 + threadIdx.x; if(e < E1N) atomicAdd(&c1[e1[e]], 1); }
  else if(bx < B1+B2){ int e = (bx-B1)*256 + threadIdx.x; if(e < E2N) atomicAdd(&c2[e2[e]], 1); }
  else { int e = (bx-B1-B2)*256 + threadIdx.x; if(e < E4N) atomicAdd(&c3[e3[e]], 1); }
}
// one block per graph: exclusive scan -> row_ptr + cursor
__global__ void k_scan3(const int* c1, int n1, int* r1, int* u1,
                        const int* c2, int n2, int* r2, int* u2,
                        const int* c3, int n3, int* r3, int* u3){
  __shared__ int tsum[1024];
  const int* cnt; int n; int* row_ptr; int* cursor;
  if(blockIdx.x == 0){ cnt=c1; n=n1; row_ptr=r1; cursor=u1; }
  else if(blockIdx.x == 1){ cnt=c2; n=n2; row_ptr=r2; cursor=u2; }
  else { cnt=c3; n=n3; row_ptr=r3; cursor=u3; }
  int tid = threadIdx.x;
  int per = (n + 1023) / 1024;
  int start = tid*per; int end = min(start+per, n);
  int s = 0;
  for(int i=start;i<end;i++) s += cnt[i];
  tsum[tid] = s; __syncthreads();
  for(int off=1;off<1024;off<<=1){
    int v = (tid>=off) ? tsum[tid-off] : 0;
    __syncthreads();
    tsum[tid] += v;
    __syncthreads();
  }
  int run = (tid==0) ? 0 : tsum[tid-1];
  for(int i=start;i<end;i++){ row_ptr[i]=run; cursor[i]=run; run += cnt[i]; }
  if(end == n) row_ptr[n] = run;
}
// merged fill+permute over 3 graphs: meta[pos] = {esrc, ew|ety<<16}
__global__ void k_fillperm3(const int* d1, const int* s1, const int* w1, const int* t1, int* u1, int2* m1,
                            const int* d2, const int* s2, const int* w2, const int* t2, int* u2, int2* m2,
                            const int* d3, const int* s3, const int* w3, const int* t3, int* u3, int2* m3){
  const int B1 = (E1N+255)/256, B2 = (E2N+255)/256;
  int bx = blockIdx.x;
  if(bx < B1){
    int e = bx*256 + threadIdx.x;
    if(e < E1N){ int pos = atomicAdd(&u1[d1[e]], 1); m1[pos] = make_int2(s1[e], w1[e] | (t1[e]<<16)); }
  } else if(bx < B1+B2){
    int e = (bx-B1)*256 + threadIdx.x;
    if(e < E2N){ int pos = atomicAdd(&u2[d2[e]], 1); m2[pos] = make_int2(s2[e], w2[e] | (t2[e]<<16)); }
  } else {
    int e = (bx-B1-B2)*256 + threadIdx.x;
    if(e < E4N){ int pos = atomicAdd(&u3[d3[e]], 1); m3[pos] = make_int2(s3[e], w3[e] | (t3[e]<<16)); }
  }
}

// single-pass attention on packed bf16 KV; 8-edge ILP, packed int2 edge meta,
// 0.25 scale folded into q.
__global__ void k_attn_fused8(const int* __restrict__ row_ptr, const int2* __restrict__ meta,
                              const unsigned* __restrict__ KVp, const float* __restrict__ Qbuf,
                              const float* __restrict__ EW2, const float* __restrict__ mu,
                              float* __restrict__ Abuf){
  int d = blockIdx.x; int o = threadIdx.x;
  int r0 = row_ptr[d], r1 = row_ptr[d+1];
  __shared__ float q[HH];
  q[o] = Qbuf[(size_t)d*HH+o]*0.25f;
  __syncthreads();
  int h = o >> 4;
  float qo = q[o];
  float dn0=0.f, dn1=0.f, dn2=0.f, dn3=0.f;
  float ac0=0.f, ac1=0.f, ac2=0.f, ac3=0.f;
  int r = r0;
  for(; r+7 < r1; r += 8){
    int2 m[8]; unsigned u[8]; float e[8]; float p[8];
    #pragma unroll
    for(int j=0;j<8;j++) m[j] = meta[r+j];
    #pragma unroll
    for(int j=0;j<8;j++) u[j] = KVp[(size_t)m[j].x*HH + o];
    #pragma unroll
    for(int j=0;j<8;j++) e[j] = EW2[(m[j].y & 0xffff)*HH + o];
    #pragma unroll
    for(int j=0;j<8;j++) p[j] = qo*(__uint_as_float(u[j]<<16) + e[j]);
    #pragma unroll
    for(int j=0;j<8;j++) p[j] += __shfl_xor(p[j], 1, 64);
    #pragma unroll
    for(int j=0;j<8;j++) p[j] += __shfl_xor(p[j], 2, 64);
    #pragma unroll
    for(int j=0;j<8;j++) p[j] += __shfl_xor(p[j], 4, 64);
    #pragma unroll
    for(int j=0;j<8;j++) p[j] += __shfl_xor(p[j], 8, 64);
    float ex[8];
    #pragma unroll
    for(int j=0;j<8;j++) ex[j] = __expf(p[j]*mu[(m[j].y>>16)*NH+h]);
    dn0 += ex[0]+ex[4]; dn1 += ex[1]+ex[5]; dn2 += ex[2]+ex[6]; dn3 += ex[3]+ex[7];
    ac0 += ex[0]*__uint_as_float(u[0]&0xffff0000u) + ex[4]*__uint_as_float(u[4]&0xffff0000u);
    ac1 += ex[1]*__uint_as_float(u[1]&0xffff0000u) + ex[5]*__uint_as_float(u[5]&0xffff0000u);
    ac2 += ex[2]*__uint_as_float(u[2]&0xffff0000u) + ex[6]*__uint_as_float(u[6]&0xffff0000u);
    ac3 += ex[3]*__uint_as_float(u[3]&0xffff0000u) + ex[7]*__uint_as_float(u[7]&0xffff0000u);
  }
  for(; r+3 < r1; r += 4){
    int2 m[4]; unsigned u[4]; float e[4]; float p[4];
    #pragma unroll
    for(int j=0;j<4;j++) m[j] = meta[r+j];
    #pragma unroll
    for(int j=0;j<4;j++) u[j] = KVp[(size_t)m[j].x*HH + o];
    #pragma unroll
    for(int j=0;j<4;j++) e[j] = EW2[(m[j].y & 0xffff)*HH + o];
    #pragma unroll
    for(int j=0;j<4;j++) p[j] = qo*(__uint_as_float(u[j]<<16) + e[j]);
    #pragma unroll
    for(int j=0;j<4;j++) p[j] += __shfl_xor(p[j], 1, 64);
    #pragma unroll
    for(int j=0;j<4;j++) p[j] += __shfl_xor(p[j], 2, 64);
    #pragma unroll
    for(int j=0;j<4;j++) p[j] += __shfl_xor(p[j], 4, 64);
    #pragma unroll
    for(int j=0;j<4;j++) p[j] += __shfl_xor(p[j], 8, 64);
    float ex[4];
    #pragma unroll
    for(int j=0;j<4;j++) ex[j] = __expf(p[j]*mu[(m[j].y>>16)*NH+h]);
    dn0 += ex[0]; dn1 += ex[1]; dn2 += ex[2]; dn3 += ex[3];
    ac0 += ex[0]*__uint_as_float(u[0]&0xffff0000u);
    ac1 += ex[1]*__uint_as_float(u[1]&0xffff0000u);
    ac2 += ex[2]*__uint_as_float(u[2]&0xffff0000u);
    ac3 += ex[3]*__uint_as_float(u[3]&0xffff0000u);
  }
  for(; r < r1; r++){
    int2 m = meta[r];
    unsigned u = KVp[(size_t)m.x*HH + o];
    float p = qo*(__uint_as_float(u<<16) + EW2[(m.y & 0xffff)*HH + o]);
    p += __shfl_xor(p, 1, 64);
    p += __shfl_xor(p, 2, 64);
    p += __shfl_xor(p, 4, 64);
    p += __shfl_xor(p, 8, 64);
    float ex = __expf(p*mu[(m.y>>16)*NH+h]);
    dn0 += ex; ac0 += ex*__uint_as_float(u&0xffff0000u);
  }
  float dd = (dn0+dn1)+(dn2+dn3), acc = (ac0+ac1)+(ac2+ac3);
  Abuf[(size_t)d*HH + o] = acc / fmaxf(dd, 1e-9f);
}

// ---------------- stage D: token pooling ----------------
__global__ void k_tokatt(const float* h2f, const int* toknt, const float* ipW, const float* iaW,
                         float* abuf, unsigned* amax, const int* tokid){
  int t = blockIdx.x; int o = threadIdx.x;
  __shared__ float es[HH];
  __shared__ float red[HH];
  int b = t % BB, l = t / BB;
  es[o] = h2f[(b*LL+l)*HH+o];
  __syncthreads();
  int nt = toknt[t];
  const float* w = ipW + (size_t)nt*HH*HH;
  float acc = 0.f;
  for(int j=0;j<HH;j++) acc += es[j]*w[j*HH+o];
  float u = tanhfast(acc);
  red[o] = u * iaW[nt*HH+o];
  __syncthreads();
  for(int s=64;s>0;s>>=1){ if(o<s) red[o]+=red[o+s]; __syncthreads(); }
  if(o==0){
    float a = red[0];
    abuf[t] = a;
    atomicMax(&amax[tokid[t]], fenc(a));
  }
}

__global__ void k_tokexp(const int* tokid, float* abuf, const unsigned* amax, float* aden, float* cnt){
  int t = blockIdx.x*blockDim.x + threadIdx.x;
  if(t >= TT) return;
  int c = tokid[t];
  float ex = __expf(abuf[t]-fdec(amax[c]));
  abuf[t] = ex;
  atomicAdd(&aden[c], ex);
  atomicAdd(&cnt[c], 1.f);
}

__global__ void k_tokagg(const int* tokid, const float* abuf, const float* aden,
                         const float* h2f, float* hist2){
  int t = blockIdx.x; int o = threadIdx.x;
  int c = tokid[t];
  float w = abuf[t]/fmaxf(aden[c],1e-9f);
  int b = t % BB, l = t / BB;
  atomicAdd(&hist2[c*HH+o], w*h2f[(b*LL+l)*HH+o]);
}

// ---------------- parent pooling ----------------
__global__ void k_peagg(const int* pe_p, const int* pe_c, const float* cef, float* psum, float* pcnt){
  int i = blockIdx.x; int o = threadIdx.x;
  int p = pe_p[i], c = pe_c[i];
  atomicAdd(&psum[p*HH+o], cef[c*HH+o]);
  if(o==0) atomicAdd(&pcnt[p], 1.f);
}

__global__ void k_parent(const float* psum, const float* pcnt, float* out){
  int i = blockIdx.x; int o = threadIdx.x;
  out[i*HH+o] = psum[i*HH+o]/fmaxf(pcnt[i],1.f);
}

extern "C" void kernel_launch(void* const* d_in, const int* in_sizes, int n_in,
                              void* d_out, int out_size, void* d_ws, size_t ws_size,
                              hipStream_t stream){
  const int* seq     = (const int*)d_in[0];
  const int* seq_nt  = (const int*)d_in[1];
  const int* dur     = (const int*)d_in[2];
  const int* stime   = (const int*)d_in[3];
  const int* etime   = (const int*)d_in[4];
  const int* g1_nid  = (const int*)d_in[5];
  const int* g1_nt   = (const int*)d_in[6];
  const int* g1_esrc = (const int*)d_in[7];
  const int* g1_edst = (const int*)d_in[8];
  const int* g1_ety  = (const int*)d_in[9];
  const int* g1_ew   = (const int*)d_in[10];
  const int* g2_sel  = (const int*)d_in[11];
  const int* g2_esrc = (const int*)d_in[12];
  const int* g2_edst = (const int*)d_in[13];
  const int* g2_ety  = (const int*)d_in[14];
  const int* g2_ew   = (const int*)d_in[15];
  const int* tok_sel = (const int*)d_in[16];
  const int* g4_esrc = (const int*)d_in[17];
  const int* g4_edst = (const int*)d_in[18];
  const int* g4_ety  = (const int*)d_in[19];
  const int* g4_ew   = (const int*)d_in[20];
  const int* pe_p    = (const int*)d_in[21];
  const int* pe_c    = (const int*)d_in[22];
  const float* emb     = (const float*)d_in[23];
  const float* hist_emb= (const float*)d_in[24];
  const float* edge_emb= (const float*)d_in[25];
  const float* dia_w   = (const float*)d_in[26];
  const float* dia_b   = (const float*)d_in[27];
  const float* t2v_w   = (const float*)d_in[28];
  const float* t2v_b   = (const float*)d_in[29];
  const float* exp_W   = (const float*)d_in[30];
  const float* exp_b   = (const float*)d_in[31];
  const float* l1Wi    = (const float*)d_in[32];
  const float* l1Wh    = (const float*)d_in[33];
  const float* l1b     = (const float*)d_in[34];
  const float* l2Wi    = (const float*)d_in[35];
  const float* l2Wh    = (const float*)d_in[36];
  const float* l2b     = (const float*)d_in[37];
  const float* convK   = (const float*)d_in[38];
  const float* convQ   = (const float*)d_in[39];
  const float* convV   = (const float*)d_in[40];
  const float* convO   = (const float*)d_in[41];
  const float* convE   = (const float*)d_in[42];
  const float* convMu  = (const float*)d_in[43];
  const float* ipW     = (const float*)d_in[44];
  const float* iaW     = (const float*)d_in[45];
  const float* skip    = (const float*)d_in[46];
  float* outp = (float*)d_out;

  // workspace arena
  char* wsp = (char*)d_ws;
  size_t off = 0;
  auto A = [&](size_t nbytes)->char*{ char* p = wsp+off; off += (nbytes+255)&~(size_t)255; return p; };
  float*    srcbuf = (float*)   A((size_t)N1SN*HH*4);
  unsigned* KVp    = (unsigned*)A((size_t)N1SN*HH*4);    // packed bf16 [V|K]
  float*    Qbuf   = (float*)   A((size_t)N1DN*HH*4);
  float*    Abuf   = (float*)   A((size_t)N1DN*HH*4);
  float*    xbuf   = (float*)   A((size_t)TT*HH*4);
  float*    gpre   = (float*)   A((size_t)TT*512*4);
  float*    h1     = (float*)   A((size_t)TT*HH*4);
  float*    dst2   = (float*)   A((size_t)TT*HH*4);
  float*    xg     = (float*)   A((size_t)N1DN*HH*4);
  float*    x2     = (float*)   A((size_t)TT*HH*4);
  float*    h2f    = (float*)   A((size_t)TT*HH*4);
  float*    hist2  = (float*)   A((size_t)CHILDN*HH*4);
  float*    cnt    = (float*)   A((size_t)CHILDN*4);
  float*    abuf   = (float*)   A((size_t)TT*4);
  unsigned* amax   = (unsigned*)A((size_t)CHILDN*4);
  float*    aden   = (float*)   A((size_t)CHILDN*4);
  float*    x3     = (float*)   A((size_t)N1DN*HH*4);
  float*    cef    = (float*)   A((size_t)N4DN*HH*4);
  float*    psum   = (float*)   A((size_t)PARENTN*HH*4);
  float*    pcnt   = (float*)   A((size_t)PARENTN*4);
  float*    sdia   = (float*)   A((size_t)CHILDN*64*4);  // sin(dia_w+dia_b) cols 64..127
  int*      tokid  = (int*)     A((size_t)TT*4);
  int*      toknt  = (int*)     A((size_t)TT*4);
  int*      gnid2  = (int*)     A((size_t)N2N*4);
  int*      idxS1  = (int*)     A((size_t)NTY*N1SN*4);
  int*      idxS2  = (int*)     A((size_t)NTY*N1DN*4);
  int*      idxS3  = (int*)     A((size_t)NTY*N2N*4);
  int*      idxS4  = (int*)     A((size_t)NTY*TT*4);
  int*      idxS5  = (int*)     A((size_t)NTY*N4DN*4);
  int*      cntall = (int*)     A((size_t)5*NTY*4);
  int*      tdesc  = (int*)     A((size_t)3*TDSTRIDE*4);
  int*      tcnt   = (int*)     A((size_t)8*4);
  float*    EW2all = (float*)   A((size_t)4*50*HH*4);
  short*    Wsw    = (short*)   A((size_t)64*16384*2);   // bf16-swizzled weights
  int*      g1row  = (int*)     A((size_t)(N1DN+1)*4);
  int2*     g1meta = (int2*)    A((size_t)E1N*8);
  int*      g2row  = (int*)     A((size_t)(TT+1)*4);
  int2*     g2meta = (int2*)    A((size_t)E2N*8);
  int*      g4row  = (int*)     A((size_t)(N4DN+1)*4);
  int2*     g4meta = (int2*)    A((size_t)E4N*8);
  int*      icnt1  = (int*)     A((size_t)(N1DN+1)*4);
  int*      icur1  = (int*)     A((size_t)(N1DN+1)*4);
  int*      icnt2  = (int*)     A((size_t)(TT+1)*4);
  int*      icur2  = (int*)     A((size_t)(TT+1)*4);
  int*      icnt3  = (int*)     A((size_t)(N4DN+1)*4);
  int*      icur3  = (int*)     A((size_t)(N4DN+1)*4);
  if(off > ws_size) return;  // insufficient scratch: output stays zero

  auto run_conv = [&](int cfg, int gkvq, int gq,
                      const float* src_X, const int* src_nid, const int* srcmap,
                      const int* idx_src, int* cnt_src, int stride_src,
                      const float* q_X, const int* q_map,
                      const float* resid_X, const int* r_map, int ndst,
                      const int* idx_dst, int* cnt_dst, int stride_dst,
                      const int* rowp, const int2* meta,
                      int layer, float* outbuf, float* out2, int relu){
    const bfrag* WB = (const bfrag*)Wsw;
    const bfrag* WK = WB + (size_t)( 0 + layer*4)*2048;
    const bfrag* WV = WB + (size_t)(16 + layer*4)*2048;
    const bfrag* WQ = WB + (size_t)(32 + layer*4)*2048;
    const bfrag* WO = WB + (size_t)(48 + layer*4)*2048;
    const float* MU  = convMu + (size_t)layer*NRL*NH;
    const float* EW2 = EW2all + (size_t)layer*50*HH;
    const int* td = tdesc + (size_t)cfg*TDSTRIDE;
    const int* tc = tcnt + cfg*2;
    k_gemm_kvq<<<gkvq, 256, 0, stream>>>(td, tc, src_X, src_nid, srcmap, sdia,
                                         idx_src, cnt_src, stride_src, WK, WV, KVp,
                                         q_X, q_map, idx_dst, cnt_dst, stride_dst, WQ, Qbuf);
    k_attn_fused8<<<ndst, HH, 0, stream>>>(rowp, meta, KVp, Qbuf, EW2, MU, Abuf);
    k_gemm_t5<<<gq, 256, 0, stream>>>(td, tc, Abuf, idx_dst, cnt_dst, stride_dst, WO,
                                      resid_X, r_map, outbuf, out2, relu);
  };

  // ---- upfront: merged init (zeros + sin table + prepack + edge tables), scatters, tiles, CSR ----
  k_init<<<(CHILDN*HH+255)/256, 256, 0, stream>>>(hist2, cnt, amax, aden, psum, pcnt, cntall,
                                                  icnt1, icnt2, icnt3,
                                                  dia_w, dia_b, sdia,
                                                  convK, convV, convQ, convO, Wsw,
                                                  edge_emb, convE, EW2all);
  {
    const int B1 = (N1SN+255)/256, B2 = (TT+255)/256, B3 = (N2N+255)/256;
    k_scatall<<<B1+B2+B3, 256, 0, stream>>>(g1_nt, seq, seq_nt, g2_sel, g1_nid,
                                            tokid, toknt, gnid2, cntall,
                                            idxS1, idxS2, idxS5, idxS4, idxS3);
  }
  k_mktiles<<<1, 256, 0, stream>>>(cntall, tdesc, tcnt);
  {
    const int B1 = (E1N+255)/256, B2 = (E2N+255)/256, B3 = (E4N+255)/256;
    k_hist3<<<B1+B2+B3, 256, 0, stream>>>(g1_edst, g2_edst, g4_edst, icnt1, icnt2, icnt3);
    k_scan3<<<3, 1024, 0, stream>>>(icnt1, N1DN, g1row, icur1,
                                    icnt2, TT,   g2row, icur2,
                                    icnt3, N4DN, g4row, icur3);
    k_fillperm3<<<B1+B2+B3, 256, 0, stream>>>(g1_edst, g1_esrc, g1_ew, g1_ety, icur1, g1meta,
                                              g2_edst, g2_esrc, g2_ew, g2_ety, icur2, g2meta,
                                              g4_edst, g4_esrc, g4_ew, g4_ety, icur3, g4meta);
  }

  // ---- stage A: features + LSTM1 (fused scan) ----
  k_featx2<<<TT/32, 512, 0, stream>>>(seq, dur, stime, etime, emb, dia_w, dia_b, t2v_w, t2v_b, exp_W, exp_b, xbuf);
  k_xwi2<<<(TT+15)/16, 256, 0, stream>>>(xbuf, l1Wi, l1b, gpre, TT, 0);
  k_lstm_fused<<<BB, 512, 0, stream>>>(gpre, l1Wh, h1, (float*)nullptr);

  // grid bounds (true tile counts are device-side; these are safe upper bounds)
  const int GKVQ_A = (N1SN+N1DN)/32 + 8;   // conv1 / conv3
  const int GKVQ_B = (N2N+TT)/32 + 8;      // conv2
  const int GKVQ_C = (N1DN+N4DN)/32 + 8;   // conv4
  const int GQ_A   = (N1DN+31)/32 + 4;
  const int GQ_B   = (TT+31)/32 + 4;
  const int GQ_C   = (N4DN+31)/32 + 4;

  // ---- conv1 on g1 (src/dst features gathered from emb via g1_nid in the gemms) ----
  run_conv(0, GKVQ_A, GQ_A,
           emb, g1_nid, g1_nid, idxS1, cntall+0*NTY, N1SN,
           emb, g1_nid,
           emb, g1_nid, N1DN, idxS2, cntall+1*NTY, N1DN,
           g1row, g1meta, 0, xg, (float*)nullptr, 1);

  // ---- conv2 on g2 (src features gathered from xg via g2_sel in the gemm) ----
  k_dst2<<<TT, HH, 0, stream>>>(tok_sel, xg, h1, dst2);
  run_conv(1, GKVQ_B, GQ_B,
           xg, gnid2, g2_sel, idxS3, cntall+2*NTY, N2N,
           dst2, (const int*)nullptr,
           dst2, (const int*)nullptr, TT, idxS4, cntall+3*NTY, TT,
           g2row, g2meta, 1, x2, (float*)nullptr, 1);

  // ---- LSTM2 (h2 is output 0); x2 read directly with permuted layout ----
  k_xwi2<<<(TT+15)/16, 256, 0, stream>>>(x2, l2Wi, l2b, gpre, TT, 1);
  k_lstm_fused<<<BB, 512, 0, stream>>>(gpre, l2Wh, h2f, outp);

  // ---- stage D: token attention pooling -> hist2 (histfix fused into k_x0) ----
  k_tokatt<<<TT, HH, 0, stream>>>(h2f, toknt, ipW, iaW, abuf, amax, tokid);
  k_tokexp<<<(TT+255)/256, 256, 0, stream>>>(tokid, abuf, amax, aden, cnt);
  k_tokagg<<<TT, HH, 0, stream>>>(tokid, abuf, aden, h2f, hist2);

  // ---- conv3 on g1 with skip-mixed input (g1 CSR + scatters + tiles reused) ----
  k_x0<<<N1SN, HH, 0, stream>>>(g1_nid, g1_nt, emb, hist2, cnt, hist_emb, skip, srcbuf);
  run_conv(0, GKVQ_A, GQ_A,
           srcbuf, g1_nid, (const int*)nullptr, idxS1, cntall+0*NTY, N1SN,
           srcbuf, (const int*)nullptr,
           srcbuf, (const int*)nullptr, N1DN, idxS2, cntall+1*NTY, N1DN,
           g1row, g1meta, 2, x3, (float*)nullptr, 1);

  // ---- conv4 on g4 (child_embed = output 1, no relu) ----
  run_conv(2, GKVQ_C, GQ_C,
           x3, g1_nid, (const int*)nullptr, idxS2, cntall+1*NTY, N1DN,
           x3, (const int*)nullptr,
           x3, (const int*)nullptr, N4DN, idxS5, cntall+4*NTY, N4DN,
           g4row, g4meta, 3, cef, outp + (size_t)TT*HH, 0);

  // ---- parent pooling (output 2) ----
  k_peagg<<<EC2PN, HH, 0, stream>>>(pe_p, pe_c, cef, psum, pcnt);
  k_parent<<<PARENTN, HH, 0, stream>>>(psum, pcnt, outp + (size_t)TT*HH + (size_t)N4DN*HH);
}

// Round 10
// 696.337 us; speedup vs baseline: 1.1463x; 1.0395x over previous
//
#include <hip/hip_runtime.h>
#include <math.h>

#define BB 256
#define LL 20
#define HH 128
#define NH 8
#define D2C 64
#define NTY 4
#define NRL 4
#define CHILDN 30001
#define PARENTN 500
#define N1SN 50000
#define N1DN 20000
#define E1N 300000
#define N2N 20000
#define E2N 200000
#define TT (BB*LL)
#define N4DN 5000
#define E4N 150000
#define EC2PN 8000
#define TDSTRIDE 2304

typedef __attribute__((ext_vector_type(8))) short bfrag;   // 8 bf16 in 4 VGPRs
typedef __attribute__((ext_vector_type(4))) float ffrag;   // MFMA accumulator

__device__ __forceinline__ unsigned fenc(float f){ unsigned u=__float_as_uint(f); return (u&0x80000000u)? ~u : (u|0x80000000u); }
__device__ __forceinline__ float fdec(unsigned u){ return (u&0x80000000u)? __uint_as_float(u^0x80000000u) : __uint_as_float(~u); }
__device__ __forceinline__ float sigfast(float x){ return 1.f/(1.f+__expf(-x)); }
__device__ __forceinline__ float tanhfast(float x){ float e = __expf(-2.f*x); return (1.f-e)/(1.f+e); }
__device__ __forceinline__ short f2bf(float f){
  unsigned u = __float_as_uint(f);
  unsigned r = u + 0x7FFFu + ((u>>16)&1u);   // round-to-nearest-even
  return (short)(r>>16);
}

// ---------------- upfront init: zero/poison buffers + sin table + weight prepack
// + edge tables, all folded into one grid (index-range dispatch) ----------------
__global__ void k_init(float* hist2, float* cnt, unsigned* amax, float* aden,
                       float* psum, float* pcnt, int* cntall,
                       int* icnt1, int* icnt2, int* icnt3,
                       const float* __restrict__ dia_w, const float* __restrict__ dia_b,
                       float* __restrict__ sdia,
                       const float* convK, const float* convV, const float* convQ,
                       const float* convO, short* Wsw,
                       const float* edge_emb, const float* convE, float* EW2all){
  int i = blockIdx.x*256 + threadIdx.x;
  if(i < CHILDN*HH) hist2[i] = 0.f;
  if(i < CHILDN){ cnt[i] = 0.f; aden[i] = 0.f; amax[i] = 0x007FFFFFu; }
  if(i < PARENTN*HH) psum[i] = 0.f;
  if(i < PARENTN) pcnt[i] = 0.f;
  if(i < 5*NTY) cntall[i] = 0;
  if(i < N1DN) icnt1[i] = 0;
  if(i < TT)   icnt2[i] = 0;
  if(i < N4DN) icnt3[i] = 0;
  if(i < CHILDN*64){
    int c = i >> 6, k = (i & 63) + 64;
    sdia[i] = __sinf(dia_w[(size_t)c*HH+k] + dia_b[(size_t)c*HH+k]);
  }
  if(i < 64*16384){
    int m = i >> 14, im = i & 16383;
    int fam = m >> 4, lt = m & 15;
    const float* src = (fam==0?convK:fam==1?convV:fam==2?convQ:convO) + (size_t)lt*HH*HH;
    int j = im & 7, lane = (im>>3)&63, kc = (im>>9)&3, nt = im>>11;
    int k = kc*32 + (lane>>4)*8 + j;
    int n = nt*16 + (lane&15);
    Wsw[(size_t)m*16384 + im] = f2bf(src[k*HH+n]);
  }
  if(i < 4*50*HH){
    int layer = i/(50*HH), rr = (i/HH)%50, o = i%HH;
    const float* EWp = convE + (size_t)layer*32*HH;
    float acc = 0.f;
    for(int j=0;j<32;j++) acc += edge_emb[rr*32+j]*EWp[j*HH+o];
    EW2all[i] = acc;
  }
}

// ---------------- Stage A: feature expansion (tiled: 32 tokens/block) ----------------
__global__ __launch_bounds__(512) void k_featx2(const int* __restrict__ seq, const int* __restrict__ dur,
                        const int* __restrict__ stime, const int* __restrict__ etime,
                        const float* __restrict__ emb, const float* __restrict__ dia_w, const float* __restrict__ dia_b,
                        const float* __restrict__ t2v_w, const float* __restrict__ t2v_b,
                        const float* __restrict__ exp_W, const float* __restrict__ exp_b, float* __restrict__ xout){
  __shared__ float feat[32*273];           // [st(128) | et(128) | tv(16)] per token, stride 273
  int base = blockIdx.x*32;
  int j = threadIdx.x >> 4;                // token 0..31
  int p = threadIdx.x & 15;                // 16 threads/token, 8 cols each
  int row = base + j;
  int node = seq[row];
  float ts = (float)stime[row], te = (float)etime[row];
  const float* ep = emb + (size_t)node*HH;
  float* fr = feat + j*273;
  int o0 = p*8;
  #pragma unroll
  for(int ii=0; ii<8; ii+=4){
    int o = o0 + ii;
    float4 e = *(const float4*)(ep + o);
    float4 st = e, et = e;
    if(o >= D2C){
      float4 w = *(const float4*)(dia_w + (size_t)node*HH + o);
      float4 b = *(const float4*)(dia_b + (size_t)node*HH + o);
      st.x = e.x*__sinf(w.x*ts+b.x); st.y = e.y*__sinf(w.y*ts+b.y);
      st.z = e.z*__sinf(w.z*ts+b.z); st.w = e.w*__sinf(w.w*ts+b.w);
      et.x = e.x*__sinf(w.x*te+b.x); et.y = e.y*__sinf(w.y*te+b.y);
      et.z = e.z*__sinf(w.z*te+b.z); et.w = e.w*__sinf(w.w*te+b.w);
    }
    fr[o] = st.x; fr[o+1] = st.y; fr[o+2] = st.z; fr[o+3] = st.w;
    fr[128+o] = et.x; fr[128+o+1] = et.y; fr[128+o+2] = et.z; fr[128+o+3] = et.w;
  }
  if(p == 0){
    float td = (float)dur[row];
    #pragma unroll
    for(int i=0;i<16;i++){
      float w = t2v_w[i], b = t2v_b[i];
      fr[256+i] = (i==0) ? (w*td + b) : __sinf(w*td + b);
    }
  }
  __syncthreads();
  // GEMM: 32x272 @ 272x128, each thread: 2 rows x 4 cols
  int oc = (threadIdx.x & 31)*4;
  int jg = threadIdx.x >> 5;               // 0..15
  const float* f0 = feat + (jg*2)*273;
  const float* f1 = feat + (jg*2+1)*273;
  float4 a0 = {0,0,0,0}, a1 = {0,0,0,0};
  for(int k=0;k<272;k++){
    float4 w = *(const float4*)(exp_W + (size_t)k*HH + oc);
    float x0 = f0[k], x1 = f1[k];
    a0.x += x0*w.x; a0.y += x0*w.y; a0.z += x0*w.z; a0.w += x0*w.w;
    a1.x += x1*w.x; a1.y += x1*w.y; a1.z += x1*w.z; a1.w += x1*w.w;
  }
  float4 bv = *(const float4*)(exp_b + oc);
  a0.x = fmaxf(a0.x+bv.x, 0.f); a0.y = fmaxf(a0.y+bv.y, 0.f);
  a0.z = fmaxf(a0.z+bv.z, 0.f); a0.w = fmaxf(a0.w+bv.w, 0.f);
  a1.x = fmaxf(a1.x+bv.x, 0.f); a1.y = fmaxf(a1.y+bv.y, 0.f);
  a1.z = fmaxf(a1.z+bv.z, 0.f); a1.w = fmaxf(a1.w+bv.w, 0.f);
  *(float4*)(xout + (size_t)(base + jg*2  )*HH + oc) = a0;
  *(float4*)(xout + (size_t)(base + jg*2+1)*HH + oc) = a1;
}

// tiled x @ Wi + b -> gpre: 16 rows x 512 cols per block; perm=1 reads x in (l*BB+b) layout
__global__ void k_xwi2(const float* x, const float* Wi, const float* bias, float* gpre, int rows, int perm){
  int base = blockIdx.x*16;
  __shared__ float xs[128*17];
  int tid = threadIdx.x;
  #pragma unroll
  for(int s=0;s<8;s++){
    int elem = tid + 256*s;
    int k = elem & 127, j = elem >> 7;
    int r = base + j;
    int src = r;
    if(perm) src = (r % LL)*BB + (r / LL);
    xs[k*17 + j] = (r < rows) ? x[(size_t)src*HH + k] : 0.f;
  }
  __syncthreads();
  int o4 = (tid & 127)*4;
  int ng = tid >> 7;
  float4 a[8];
  #pragma unroll
  for(int j=0;j<8;j++) a[j]=make_float4(0,0,0,0);
  for(int k=0;k<HH;k++){
    float4 w = *(const float4*)(Wi + (size_t)k*512 + o4);
    const float* xr = xs + k*17 + ng*8;
    #pragma unroll
    for(int j=0;j<8;j++){
      float xv = xr[j];
      a[j].x += xv*w.x; a[j].y += xv*w.y; a[j].z += xv*w.z; a[j].w += xv*w.w;
    }
  }
  float4 bv = *(const float4*)(bias + o4);
  #pragma unroll
  for(int j=0;j<8;j++){
    int r = base + ng*8 + j;
    if(r < rows){
      float4 v = a[j];
      v.x += bv.x; v.y += bv.y; v.z += bv.z; v.w += bv.w;
      *(float4*)(gpre + (size_t)r*512 + o4) = v;
    }
  }
}

// fused 20-step LSTM: one block per batch row, Wh column in registers, gpre
// prefetched into registers, activations spread across all 512 threads.
__global__ __launch_bounds__(512, 2) void k_lstm_fused(const float* __restrict__ gpre,
                                                       const float* __restrict__ Wh,
                                                       float* __restrict__ hout,
                                                       float* __restrict__ hout2){
  int b = blockIdx.x;
  int o = threadIdx.x;
  __shared__ float hs[HH];
  __shared__ float act[512];
  float wr[HH];
  #pragma unroll
  for(int h=0;h<HH;h++) wr[h] = Wh[(size_t)h*512 + o];
  float gv[LL];
  const float* gp = gpre + (size_t)b*LL*512 + o;
  #pragma unroll
  for(int l=0;l<LL;l++) gv[l] = gp[(size_t)l*512];
  if(o < HH) hs[o] = 0.f;
  float cc = 0.f;
  int quad = o >> 7;                        // 0=i, 1=f, 2=g, 3=o
  __syncthreads();
  for(int l=0;l<LL;l++){
    float a0=0.f,a1=0.f,a2=0.f,a3=0.f;
    #pragma unroll
    for(int h=0;h<HH;h+=4){
      float4 hv = *(const float4*)&hs[h];
      a0 += hv.x*wr[h];   a1 += hv.y*wr[h+1];
      a2 += hv.z*wr[h+2]; a3 += hv.w*wr[h+3];
    }
    float g = gv[l] + ((a0+a1)+(a2+a3));
    act[o] = (quad==2) ? tanhfast(g) : sigfast(g);
    __syncthreads();
    if(o < HH){
      cc = act[HH+o]*cc + act[o]*act[2*HH+o];
      float hh = act[3*HH+o]*tanhfast(cc);
      hs[o] = hh;
      size_t bi = ((size_t)b*LL + l)*HH + o;
      hout[bi] = hh;
      if(hout2) hout2[bi] = hh;
    }
    __syncthreads();
  }
}

// ---------------- merged scatters + edge histograms (block ranges) ----------------
// scatter3 | tokprep | prep2scat | hist(g1)+rank | hist(g2)+rank | hist(g4)+rank
__global__ void k_scatall(const int* __restrict__ g1_nt, const int* __restrict__ seq,
                          const int* __restrict__ seq_nt, const int* __restrict__ g2_sel,
                          const int* __restrict__ g1_nid,
                          int* __restrict__ tokid, int* __restrict__ toknt, int* __restrict__ gnid2,
                          int* __restrict__ cntall,
                          int* __restrict__ idxS1, int* __restrict__ idxS2, int* __restrict__ idxS5,
                          int* __restrict__ idxS4, int* __restrict__ idxS3,
                          const int* __restrict__ e1d, int* __restrict__ icnt1, int* __restrict__ rank1,
                          const int* __restrict__ e2d, int* __restrict__ icnt2, int* __restrict__ rank2,
                          const int* __restrict__ e3d, int* __restrict__ icnt3, int* __restrict__ rank3){
  const int B1 = (N1SN+255)/256;
  const int B2 = (TT+255)/256;
  const int B3 = (N2N+255)/256;
  const int BE1 = (E1N+255)/256;
  const int BE2 = (E2N+255)/256;
  __shared__ int h[3][NTY];
  __shared__ int bs[3][NTY];
  int bx = blockIdx.x;
  if(bx < B1){
    // 3-way type scatter of g1_nt prefixes
    int i = bx*256 + threadIdx.x;
    if(threadIdx.x < 3*NTY) (&h[0][0])[threadIdx.x] = 0;
    __syncthreads();
    int t = 0, r1 = 0, r2 = 0, r3 = 0;
    bool a1 = (i < N1SN), a2 = (i < N1DN), a3 = (i < N4DN);
    if(a1){
      t = g1_nt[i];
      r1 = atomicAdd(&h[0][t], 1);
      if(a2) r2 = atomicAdd(&h[1][t], 1);
      if(a3) r3 = atomicAdd(&h[2][t], 1);
    }
    __syncthreads();
    if(threadIdx.x < NTY){
      int ty = threadIdx.x;
      if(h[0][ty] > 0) bs[0][ty] = atomicAdd(&cntall[0*NTY+ty], h[0][ty]);
      if(h[1][ty] > 0) bs[1][ty] = atomicAdd(&cntall[1*NTY+ty], h[1][ty]);
      if(h[2][ty] > 0) bs[2][ty] = atomicAdd(&cntall[4*NTY+ty], h[2][ty]);
    }
    __syncthreads();
    if(a1) idxS1[t*N1SN + bs[0][t] + r1] = i;
    if(a2) idxS2[t*N1DN + bs[1][t] + r2] = i;
    if(a3) idxS5[t*N4DN + bs[2][t] + r3] = i;
  } else if(bx < B1 + B2){
    // token prep + scatter
    int i = (bx - B1)*256 + threadIdx.x;
    if(threadIdx.x < NTY) h[0][threadIdx.x] = 0;
    __syncthreads();
    int nt = 0, r = 0;
    bool act = (i < TT);
    if(act){
      int b = i % BB, l = i / BB;
      tokid[i] = seq[b*LL+l];
      nt = seq_nt[b*LL+l];
      toknt[i] = nt;
      r = atomicAdd(&h[0][nt], 1);
    }
    __syncthreads();
    if(threadIdx.x < NTY && h[0][threadIdx.x] > 0)
      bs[0][threadIdx.x] = atomicAdd(&cntall[3*NTY+threadIdx.x], h[0][threadIdx.x]);
    __syncthreads();
    if(act) idxS4[nt*TT + bs[0][nt] + r] = i;
  } else if(bx < B1 + B2 + B3){
    // conv2 src prep + scatter
    int i = (bx - B1 - B2)*256 + threadIdx.x;
    if(threadIdx.x < NTY) h[0][threadIdx.x] = 0;
    __syncthreads();
    int nt = 0, r = 0;
    bool act = (i < N2N);
    if(act){
      int s = g2_sel[i];
      gnid2[i] = g1_nid[s];
      nt = g1_nt[s];
      r = atomicAdd(&h[0][nt], 1);
    }
    __syncthreads();
    if(threadIdx.x < NTY && h[0][threadIdx.x] > 0)
      bs[0][threadIdx.x] = atomicAdd(&cntall[2*NTY+threadIdx.x], h[0][threadIdx.x]);
    __syncthreads();
    if(act) idxS3[nt*N2N + bs[0][nt] + r] = i;
  } else if(bx < B1 + B2 + B3 + BE1){
    int e = (bx - B1 - B2 - B3)*256 + threadIdx.x;
    if(e < E1N) rank1[e] = atomicAdd(&icnt1[e1d[e]], 1);
  } else if(bx < B1 + B2 + B3 + BE1 + BE2){
    int e = (bx - B1 - B2 - B3 - BE1)*256 + threadIdx.x;
    if(e < E2N) rank2[e] = atomicAdd(&icnt2[e2d[e]], 1);
  } else {
    int e = (bx - B1 - B2 - B3 - BE1 - BE2)*256 + threadIdx.x;
    if(e < E4N) rank3[e] = atomicAdd(&icnt3[e3d[e]], 1);
  }
}

__global__ void k_dst2(const int* tok_sel, const float* xg, const float* h1, float* dst2){
  int t = blockIdx.x; int o = threadIdx.x;
  int b = t % BB, l = t / BB;
  dst2[t*HH+o] = xg[tok_sel[t]*HH+o] + h1[(b*LL+l)*HH+o];
}

// skip-mixed input with histfix fused (cnt==0 -> hist_emb fallback)
__global__ void k_x0(const int* nid, const int* ntype, const float* emb, const float* hist2,
                     const float* cnt, const float* hist_emb, const float* skip, float* srcbuf){
  int i = blockIdx.x; int o = threadIdx.x;
  float a = sigfast(skip[ntype[i]]);
  int nd = nid[i];
  float hv = (cnt[nd] > 0.f) ? hist2[(size_t)nd*HH+o] : hist_emb[(size_t)nd*HH+o];
  srcbuf[i*HH+o] = emb[(size_t)nd*HH+o]*a + hv*(1.f-a);
}

// ---- tile-descriptor builder: compacted work lists for the 3 unique conv configs.
__global__ void k_mktiles(const int* __restrict__ cntall, int* __restrict__ tdesc, int* __restrict__ tcnt){
  __shared__ int start[3][2][NTY];
  if(threadIdx.x == 0){
    const int srcg[3] = {0,2,1};
    const int dstg[3] = {1,3,4};
    for(int c=0;c<3;c++){
      int acc = 0;
      for(int z=0;z<2;z++){
        int g = (z==0) ? srcg[c] : dstg[c];
        int zacc = 0;
        for(int t=0;t<NTY;t++){
          start[c][z][t] = acc;
          int tiles = (cntall[g*NTY+t]+31)>>5;
          acc += tiles; zacc += tiles;
        }
        tcnt[c*2+z] = zacc;
      }
    }
  }
  __syncthreads();
  const int srcg[3] = {0,2,1};
  const int dstg[3] = {1,3,4};
  for(int c=0;c<3;c++){
    for(int z=0;z<2;z++){
      int g = (z==0) ? srcg[c] : dstg[c];
      for(int t=0;t<NTY;t++){
        int tiles = (cntall[g*NTY+t]+31)>>5;
        for(int i=threadIdx.x; i<tiles; i+=blockDim.x)
          tdesc[c*TDSTRIDE + start[c][z][t] + i] = (int)(((unsigned)z<<31) | ((unsigned)t<<28) | (unsigned)(i<<5));
      }
    }
  }
}

// ---- fused KV (z=0) + Q (z=1) projection via MFMA; compacted 1-D tile list,
// float4 staging, warp-level LN reduce (float4 LDS reads), float4 normalize pass.
__global__ __launch_bounds__(256) void k_gemm_kvq(
    const int* __restrict__ tdesc, const int* __restrict__ tcnt,
    const float* __restrict__ Xs, const int* __restrict__ src_nid, const int* __restrict__ smap,
    const float* __restrict__ sdia,
    const int* __restrict__ idxs, const int* __restrict__ cnts_s, int stride_s,
    const bfrag* __restrict__ WK, const bfrag* __restrict__ WV, unsigned* __restrict__ KVp,
    const float* __restrict__ Xq, const int* __restrict__ qmap,
    const int* __restrict__ idxd, const int* __restrict__ cnts_d, int stride_d,
    const bfrag* __restrict__ WQ, float* __restrict__ Qbuf){
  __shared__ float xs[32*132];
  __shared__ float mean_s[32], inv_s[32];
  __shared__ int sid[32], nid[32], xrow[32];
  int ntk = tcnt[0], ntq = tcnt[1];
  int bid = blockIdx.x;
  if(bid >= ntk + ntq) return;
  unsigned ud = (unsigned)tdesc[bid];
  int isQ = ud >> 31;
  int t = (ud >> 28) & 7;
  int base = ud & 0x0FFFFFFF;
  int tid = threadIdx.x;
  int cnt = isQ ? cnts_d[t] : cnts_s[t];
  if(base >= cnt) return;
  int nn = min(32, cnt - base);
  const float* X = isQ ? Xq : Xs;
  const int* map = isQ ? qmap : smap;
  const int* ids = (isQ ? idxd + (size_t)t*stride_d : idxs + (size_t)t*stride_s) + base;
  if(tid < 32){
    int s_ = (tid < nn) ? ids[tid] : ids[0];
    sid[tid] = s_;
    if(!isQ) nid[tid] = src_nid[s_];
    xrow[tid] = map ? map[s_] : s_;
  }
  __syncthreads();
  // float4 staging: 1024 float4 = 32 rows x 128 cols
  #pragma unroll
  for(int s=0;s<4;s++){
    int e4 = tid + 256*s;
    int j = e4 >> 5, c4 = (e4 & 31)*4;
    *(float4*)&xs[j*132 + c4] = *(const float4*)&X[(size_t)xrow[j]*HH + c4];
  }
  __syncthreads();
  // warp-level LN reduce: 8 lanes per row, float4 LDS reads, shfl_xor over p
  {
    int wid = tid >> 6, lane = tid & 63;
    int row = wid*8 + (lane>>3), p = lane & 7;
    const float* xr = xs + row*132 + p*16;
    float sm=0.f, sq=0.f;
    #pragma unroll
    for(int i=0;i<4;i++){
      float4 v = *(const float4*)(xr + i*4);
      sm += (v.x+v.y)+(v.z+v.w);
      sq += (v.x*v.x+v.y*v.y)+(v.z*v.z+v.w*v.w);
    }
    sm += __shfl_xor(sm, 1, 64); sq += __shfl_xor(sq, 1, 64);
    sm += __shfl_xor(sm, 2, 64); sq += __shfl_xor(sq, 2, 64);
    sm += __shfl_xor(sm, 4, 64); sq += __shfl_xor(sq, 4, 64);
    if(p == 0){
      float mean = sm*(1.f/128.f);
      float var = sq*(1.f/128.f) - mean*mean;
      mean_s[row] = mean;
      inv_s[row] = 1.f/sqrtf(fmaxf(var,0.f)+1e-5f);
    }
  }
  __syncthreads();
  // float4 normalize pass (+ sdia time-mod on cols 64..127 for the KV path)
  #pragma unroll
  for(int s=0;s<4;s++){
    int e4 = tid + 256*s;
    int j = e4 >> 5, c4 = (e4 & 31)*4;
    float* px = &xs[j*132 + c4];
    float4 v = *(float4*)px;
    float mj = mean_s[j], ij = inv_s[j];
    v.x = (v.x-mj)*ij; v.y = (v.y-mj)*ij; v.z = (v.z-mj)*ij; v.w = (v.w-mj)*ij;
    if(!isQ && c4 >= D2C){
      float4 sd = *(const float4*)(sdia + (size_t)nid[j]*64 + (c4 - D2C));
      v.x *= sd.x; v.y *= sd.y; v.z *= sd.z; v.w *= sd.w;
    }
    *(float4*)px = v;
  }
  __syncthreads();
  int lane = tid & 63, w = tid >> 6;
  int mt = w & 1, ng0 = (w>>1)*4;
  int arow = mt*16 + (lane & 15);
  int koff = (lane >> 4)*8;
  int tb = t*2048;
  if(!isQ){
    ffrag aK[4], aV[4];
    #pragma unroll
    for(int i=0;i<4;i++){ aK[i] = (ffrag){0.f,0.f,0.f,0.f}; aV[i] = (ffrag){0.f,0.f,0.f,0.f}; }
    #pragma unroll
    for(int kc=0;kc<4;kc++){
      const float* ap = xs + arow*132 + kc*32 + koff;
      bfrag a;
      #pragma unroll
      for(int j=0;j<8;j++) a[j] = f2bf(ap[j]);
      #pragma unroll
      for(int nt=0;nt<4;nt++){
        int fi = tb + ((ng0+nt)*4 + kc)*64 + lane;
        bfrag bk = WK[fi];
        bfrag bv = WV[fi];
        aK[nt] = __builtin_amdgcn_mfma_f32_16x16x32_bf16(a, bk, aK[nt], 0, 0, 0);
        aV[nt] = __builtin_amdgcn_mfma_f32_16x16x32_bf16(a, bv, aV[nt], 0, 0, 0);
      }
    }
    int col0 = lane & 15;
    int rb = mt*16 + (lane>>4)*4;
    #pragma unroll
    for(int nt=0;nt<4;nt++){
      int col = (ng0+nt)*16 + col0;
      #pragma unroll
      for(int i=0;i<4;i++){
        int n = rb + i;
        if(n < nn){
          unsigned pk = (unsigned short)f2bf(aK[nt][i]);
          unsigned pv = (unsigned short)f2bf(aV[nt][i]);
          KVp[(size_t)sid[n]*HH + col] = (pv<<16) | pk;
        }
      }
    }
  } else {
    ffrag acc[4];
    #pragma unroll
    for(int i=0;i<4;i++) acc[i] = (ffrag){0.f,0.f,0.f,0.f};
    #pragma unroll
    for(int kc=0;kc<4;kc++){
      const float* ap = xs + arow*132 + kc*32 + koff;
      bfrag a;
      #pragma unroll
      for(int j=0;j<8;j++) a[j] = f2bf(ap[j]);
      #pragma unroll
      for(int nt=0;nt<4;nt++){
        bfrag b = WQ[tb + ((ng0+nt)*4 + kc)*64 + lane];
        acc[nt] = __builtin_amdgcn_mfma_f32_16x16x32_bf16(a, b, acc[nt], 0, 0, 0);
      }
    }
    int col0 = lane & 15;
    int rb = mt*16 + (lane>>4)*4;
    #pragma unroll
    for(int nt=0;nt<4;nt++){
      int col = (ng0+nt)*16 + col0;
      #pragma unroll
      for(int i=0;i<4;i++){
        int n = rb + i;
        if(n < nn) Qbuf[(size_t)sid[n]*HH + col] = acc[nt][i];
      }
    }
  }
}

// ---- O projection via MFMA (resid+relu, optional copy); compacted dst tile list.
__global__ __launch_bounds__(256) void k_gemm_t5(
    const int* __restrict__ tdesc, const int* __restrict__ tcnt,
    const float* X, const int* idxb, const int* cnts, int stride,
    const bfrag* W, const float* resid, const int* rmap, float* Y, float* Y2,
    int relu){
  __shared__ float xs[32*132];
  __shared__ int sid[32], rrow[32];
  int ntk = tcnt[0], ntq = tcnt[1];
  if(blockIdx.x >= ntq) return;
  unsigned ud = (unsigned)tdesc[ntk + blockIdx.x];
  int t = (ud >> 28) & 7;
  int base = ud & 0x0FFFFFFF;
  int cnt = cnts[t];
  if(base >= cnt) return;
  int nn = min(32, cnt - base);
  const int* ids = idxb + (size_t)t*stride + base;
  int tid = threadIdx.x;
  if(tid < 32){
    int s_ = (tid < nn) ? ids[tid] : ids[0];
    sid[tid] = s_;
    rrow[tid] = rmap ? rmap[s_] : s_;
  }
  __syncthreads();
  #pragma unroll
  for(int s=0;s<4;s++){
    int e4 = tid + 256*s;
    int j = e4 >> 5, c4 = (e4 & 31)*4;
    *(float4*)&xs[j*132 + c4] = *(const float4*)&X[(size_t)sid[j]*HH + c4];
  }
  __syncthreads();
  int lane = tid & 63, w = tid >> 6;
  int mt = w & 1, ng0 = (w>>1)*4;
  int arow = mt*16 + (lane & 15);
  int koff = (lane >> 4)*8;
  int tb = t*2048;
  ffrag acc[4];
  #pragma unroll
  for(int i=0;i<4;i++) acc[i] = (ffrag){0.f,0.f,0.f,0.f};
  #pragma unroll
  for(int kc=0;kc<4;kc++){
    const float* ap = xs + arow*132 + kc*32 + koff;
    bfrag a;
    #pragma unroll
    for(int j=0;j<8;j++) a[j] = f2bf(ap[j]);
    #pragma unroll
    for(int nt=0;nt<4;nt++){
      bfrag b = W[tb + ((ng0+nt)*4 + kc)*64 + lane];
      acc[nt] = __builtin_amdgcn_mfma_f32_16x16x32_bf16(a, b, acc[nt], 0, 0, 0);
    }
  }
  int col0 = lane & 15;
  int rb = mt*16 + (lane>>4)*4;
  #pragma unroll
  for(int nt=0;nt<4;nt++){
    int col = (ng0+nt)*16 + col0;
    #pragma unroll
    for(int i=0;i<4;i++){
      int n = rb + i;
      if(n < nn){
        size_t r = (size_t)sid[n]*HH + col;
        float v = acc[nt][i];
        if(resid){
          v += resid[(size_t)rrow[n]*HH + col];
          if(relu) v = fmaxf(v, 0.f);
        }
        Y[r] = v;
        if(Y2) Y2[r] = v;
      }
    }
  }
}

// one block per graph: exclusive scan of counts -> row_ptr
__global__ void k_scan3(const int* c1, int n1, int* r1,
                        const int* c2, int n2, int* r2,
                        const int* c3, int n3, int* r3){
  __shared__ int tsum[1024];
  const int* cnt; int n; int* row_ptr;
  if(blockIdx.x == 0){ cnt=c1; n=n1; row_ptr=r1; }
  else if(blockIdx.x == 1){ cnt=c2; n=n2; row_ptr=r2; }
  else { cnt=c3; n=n3; row_ptr=r3; }
  int tid = threadIdx.x;
  int per = (n + 1023) / 1024;
  int start = tid*per; int end = min(start+per, n);
  int s = 0;
  for(int i=start;i<end;i++) s += cnt[i];
  tsum[tid] = s; __syncthreads();
  for(int off=1;off<1024;off<<=1){
    int v = (tid>=off) ? tsum[tid-off] : 0;
    __syncthreads();
    tsum[tid] += v;
    __syncthreads();
  }
  int run = (tid==0) ? 0 : tsum[tid-1];
  for(int i=start;i<end;i++){ row_ptr[i]=run; run += cnt[i]; }
  if(end == n) row_ptr[n] = run;
}
// merged fill over 3 graphs using precomputed ranks: pos = row_ptr[dst] + rank
__global__ void k_fillperm3(const int* d1, const int* s1, const int* w1, const int* t1,
                            const int* rp1, const int* rk1, int2* m1,
                            const int* d2, const int* s2, const int* w2, const int* t2,
                            const int* rp2, const int* rk2, int2* m2,
                            const int* d3, const int* s3, const int* w3, const int* t3,
                            const int* rp3, const int* rk3, int2* m3){
  const int B1 = (E1N+255)/256, B2 = (E2N+255)/256;
  int bx = blockIdx.x;
  if(bx < B1){
    int e = bx*256 + threadIdx.x;
    if(e < E1N){ int pos = rp1[d1[e]] + rk1[e]; m1[pos] = make_int2(s1[e], w1[e] | (t1[e]<<16)); }
  } else if(bx < B1+B2){
    int e = (bx-B1)*256 + threadIdx.x;
    if(e < E2N){ int pos = rp2[d2[e]] + rk2[e]; m2[pos] = make_int2(s2[e], w2[e] | (t2[e]<<16)); }
  } else {
    int e = (bx-B1-B2)*256 + threadIdx.x;
    if(e < E4N){ int pos = rp3[d3[e]] + rk3[e]; m3[pos] = make_int2(s3[e], w3[e] | (t3[e]<<16)); }
  }
}

// single-pass attention on packed bf16 KV; 8-edge ILP, packed int2 edge meta,
// 0.25 scale folded into q.
__global__ void k_attn_fused8(const int* __restrict__ row_ptr, const int2* __restrict__ meta,
                              const unsigned* __restrict__ KVp, const float* __restrict__ Qbuf,
                              const float* __restrict__ EW2, const float* __restrict__ mu,
                              float* __restrict__ Abuf){
  int d = blockIdx.x; int o = threadIdx.x;
  int r0 = row_ptr[d], r1 = row_ptr[d+1];
  __shared__ float q[HH];
  q[o] = Qbuf[(size_t)d*HH+o]*0.25f;
  __syncthreads();
  int h = o >> 4;
  float qo = q[o];
  float dn0=0.f, dn1=0.f, dn2=0.f, dn3=0.f;
  float ac0=0.f, ac1=0.f, ac2=0.f, ac3=0.f;
  int r = r0;
  for(; r+7 < r1; r += 8){
    int2 m[8]; unsigned u[8]; float e[8]; float p[8];
    #pragma unroll
    for(int j=0;j<8;j++) m[j] = meta[r+j];
    #pragma unroll
    for(int j=0;j<8;j++) u[j] = KVp[(size_t)m[j].x*HH + o];
    #pragma unroll
    for(int j=0;j<8;j++) e[j] = EW2[(m[j].y & 0xffff)*HH + o];
    #pragma unroll
    for(int j=0;j<8;j++) p[j] = qo*(__uint_as_float(u[j]<<16) + e[j]);
    #pragma unroll
    for(int j=0;j<8;j++) p[j] += __shfl_xor(p[j], 1, 64);
    #pragma unroll
    for(int j=0;j<8;j++) p[j] += __shfl_xor(p[j], 2, 64);
    #pragma unroll
    for(int j=0;j<8;j++) p[j] += __shfl_xor(p[j], 4, 64);
    #pragma unroll
    for(int j=0;j<8;j++) p[j] += __shfl_xor(p[j], 8, 64);
    float ex[8];
    #pragma unroll
    for(int j=0;j<8;j++) ex[j] = __expf(p[j]*mu[(m[j].y>>16)*NH+h]);
    dn0 += ex[0]+ex[4]; dn1 += ex[1]+ex[5]; dn2 += ex[2]+ex[6]; dn3 += ex[3]+ex[7];
    ac0 += ex[0]*__uint_as_float(u[0]&0xffff0000u) + ex[4]*__uint_as_float(u[4]&0xffff0000u);
    ac1 += ex[1]*__uint_as_float(u[1]&0xffff0000u) + ex[5]*__uint_as_float(u[5]&0xffff0000u);
    ac2 += ex[2]*__uint_as_float(u[2]&0xffff0000u) + ex[6]*__uint_as_float(u[6]&0xffff0000u);
    ac3 += ex[3]*__uint_as_float(u[3]&0xffff0000u) + ex[7]*__uint_as_float(u[7]&0xffff0000u);
  }
  for(; r+3 < r1; r += 4){
    int2 m[4]; unsigned u[4]; float e[4]; float p[4];
    #pragma unroll
    for(int j=0;j<4;j++) m[j] = meta[r+j];
    #pragma unroll
    for(int j=0;j<4;j++) u[j] = KVp[(size_t)m[j].x*HH + o];
    #pragma unroll
    for(int j=0;j<4;j++) e[j] = EW2[(m[j].y & 0xffff)*HH + o];
    #pragma unroll
    for(int j=0;j<4;j++) p[j] = qo*(__uint_as_float(u[j]<<16) + e[j]);
    #pragma unroll
    for(int j=0;j<4;j++) p[j] += __shfl_xor(p[j], 1, 64);
    #pragma unroll
    for(int j=0;j<4;j++) p[j] += __shfl_xor(p[j], 2, 64);
    #pragma unroll
    for(int j=0;j<4;j++) p[j] += __shfl_xor(p[j], 4, 64);
    #pragma unroll
    for(int j=0;j<4;j++) p[j] += __shfl_xor(p[j], 8, 64);
    float ex[4];
    #pragma unroll
    for(int j=0;j<4;j++) ex[j] = __expf(p[j]*mu[(m[j].y>>16)*NH+h]);
    dn0 += ex[0]; dn1 += ex[1]; dn2 += ex[2]; dn3 += ex[3];
    ac0 += ex[0]*__uint_as_float(u[0]&0xffff0000u);
    ac1 += ex[1]*__uint_as_float(u[1]&0xffff0000u);
    ac2 += ex[2]*__uint_as_float(u[2]&0xffff0000u);
    ac3 += ex[3]*__uint_as_float(u[3]&0xffff0000u);
  }
  for(; r < r1; r++){
    int2 m = meta[r];
    unsigned u = KVp[(size_t)m.x*HH + o];
    float p = qo*(__uint_as_float(u<<16) + EW2[(m.y & 0xffff)*HH + o]);
    p += __shfl_xor(p, 1, 64);
    p += __shfl_xor(p, 2, 64);
    p += __shfl_xor(p, 4, 64);
    p += __shfl_xor(p, 8, 64);
    float ex = __expf(p*mu[(m.y>>16)*NH+h]);
    dn0 += ex; ac0 += ex*__uint_as_float(u&0xffff0000u);
  }
  float dd = (dn0+dn1)+(dn2+dn3), acc = (ac0+ac1)+(ac2+ac3);
  Abuf[(size_t)d*HH + o] = acc / fmaxf(dd, 1e-9f);
}

// ---------------- stage D: token pooling ----------------
__global__ void k_tokatt(const float* h2f, const int* toknt, const float* ipW, const float* iaW,
                         float* abuf, unsigned* amax, const int* tokid){
  int t = blockIdx.x; int o = threadIdx.x;
  __shared__ float es[HH];
  __shared__ float red[HH];
  int b = t % BB, l = t / BB;
  es[o] = h2f[(b*LL+l)*HH+o];
  __syncthreads();
  int nt = toknt[t];
  const float* w = ipW + (size_t)nt*HH*HH;
  float acc = 0.f;
  for(int j=0;j<HH;j++) acc += es[j]*w[j*HH+o];
  float u = tanhfast(acc);
  red[o] = u * iaW[nt*HH+o];
  __syncthreads();
  for(int s=64;s>0;s>>=1){ if(o<s) red[o]+=red[o+s]; __syncthreads(); }
  if(o==0){
    float a = red[0];
    abuf[t] = a;
    atomicMax(&amax[tokid[t]], fenc(a));
  }
}

__global__ void k_tokexp(const int* tokid, float* abuf, const unsigned* amax, float* aden, float* cnt){
  int t = blockIdx.x*blockDim.x + threadIdx.x;
  if(t >= TT) return;
  int c = tokid[t];
  float ex = __expf(abuf[t]-fdec(amax[c]));
  abuf[t] = ex;
  atomicAdd(&aden[c], ex);
  atomicAdd(&cnt[c], 1.f);
}

__global__ void k_tokagg(const int* tokid, const float* abuf, const float* aden,
                         const float* h2f, float* hist2){
  int t = blockIdx.x; int o = threadIdx.x;
  int c = tokid[t];
  float w = abuf[t]/fmaxf(aden[c],1e-9f);
  int b = t % BB, l = t / BB;
  atomicAdd(&hist2[c*HH+o], w*h2f[(b*LL+l)*HH+o]);
}

// ---------------- parent pooling ----------------
__global__ void k_peagg(const int* pe_p, const int* pe_c, const float* cef, float* psum, float* pcnt){
  int i = blockIdx.x; int o = threadIdx.x;
  int p = pe_p[i], c = pe_c[i];
  atomicAdd(&psum[p*HH+o], cef[c*HH+o]);
  if(o==0) atomicAdd(&pcnt[p], 1.f);
}

__global__ void k_parent(const float* psum, const float* pcnt, float* out){
  int i = blockIdx.x; int o = threadIdx.x;
  out[i*HH+o] = psum[i*HH+o]/fmaxf(pcnt[i],1.f);
}

extern "C" void kernel_launch(void* const* d_in, const int* in_sizes, int n_in,
                              void* d_out, int out_size, void* d_ws, size_t ws_size,
                              hipStream_t stream){
  const int* seq     = (const int*)d_in[0];
  const int* seq_nt  = (const int*)d_in[1];
  const int* dur     = (const int*)d_in[2];
  const int* stime   = (const int*)d_in[3];
  const int* etime   = (const int*)d_in[4];
  const int* g1_nid  = (const int*)d_in[5];
  const int* g1_nt   = (const int*)d_in[6];
  const int* g1_esrc = (const int*)d_in[7];
  const int* g1_edst = (const int*)d_in[8];
  const int* g1_ety  = (const int*)d_in[9];
  const int* g1_ew   = (const int*)d_in[10];
  const int* g2_sel  = (const int*)d_in[11];
  const int* g2_esrc = (const int*)d_in[12];
  const int* g2_edst = (const int*)d_in[13];
  const int* g2_ety  = (const int*)d_in[14];
  const int* g2_ew   = (const int*)d_in[15];
  const int* tok_sel = (const int*)d_in[16];
  const int* g4_esrc = (const int*)d_in[17];
  const int* g4_edst = (const int*)d_in[18];
  const int* g4_ety  = (const int*)d_in[19];
  const int* g4_ew   = (const int*)d_in[20];
  const int* pe_p    = (const int*)d_in[21];
  const int* pe_c    = (const int*)d_in[22];
  const float* emb     = (const float*)d_in[23];
  const float* hist_emb= (const float*)d_in[24];
  const float* edge_emb= (const float*)d_in[25];
  const float* dia_w   = (const float*)d_in[26];
  const float* dia_b   = (const float*)d_in[27];
  const float* t2v_w   = (const float*)d_in[28];
  const float* t2v_b   = (const float*)d_in[29];
  const float* exp_W   = (const float*)d_in[30];
  const float* exp_b   = (const float*)d_in[31];
  const float* l1Wi    = (const float*)d_in[32];
  const float* l1Wh    = (const float*)d_in[33];
  const float* l1b     = (const float*)d_in[34];
  const float* l2Wi    = (const float*)d_in[35];
  const float* l2Wh    = (const float*)d_in[36];
  const float* l2b     = (const float*)d_in[37];
  const float* convK   = (const float*)d_in[38];
  const float* convQ   = (const float*)d_in[39];
  const float* convV   = (const float*)d_in[40];
  const float* convO   = (const float*)d_in[41];
  const float* convE   = (const float*)d_in[42];
  const float* convMu  = (const float*)d_in[43];
  const float* ipW     = (const float*)d_in[44];
  const float* iaW     = (const float*)d_in[45];
  const float* skip    = (const float*)d_in[46];
  float* outp = (float*)d_out;

  // workspace arena
  char* wsp = (char*)d_ws;
  size_t off = 0;
  auto A = [&](size_t nbytes)->char*{ char* p = wsp+off; off += (nbytes+255)&~(size_t)255; return p; };
  float*    srcbuf = (float*)   A((size_t)N1SN*HH*4);
  unsigned* KVp    = (unsigned*)A((size_t)N1SN*HH*4);    // packed bf16 [V|K]
  float*    Qbuf   = (float*)   A((size_t)N1DN*HH*4);
  float*    Abuf   = (float*)   A((size_t)N1DN*HH*4);
  float*    xbuf   = (float*)   A((size_t)TT*HH*4);
  float*    gpre   = (float*)   A((size_t)TT*512*4);
  float*    h1     = (float*)   A((size_t)TT*HH*4);
  float*    dst2   = (float*)   A((size_t)TT*HH*4);
  float*    xg     = (float*)   A((size_t)N1DN*HH*4);
  float*    x2     = (float*)   A((size_t)TT*HH*4);
  float*    h2f    = (float*)   A((size_t)TT*HH*4);
  float*    hist2  = (float*)   A((size_t)CHILDN*HH*4);
  float*    cnt    = (float*)   A((size_t)CHILDN*4);
  float*    abuf   = (float*)   A((size_t)TT*4);
  unsigned* amax   = (unsigned*)A((size_t)CHILDN*4);
  float*    aden   = (float*)   A((size_t)CHILDN*4);
  float*    x3     = (float*)   A((size_t)N1DN*HH*4);
  float*    cef    = (float*)   A((size_t)N4DN*HH*4);
  float*    psum   = (float*)   A((size_t)PARENTN*HH*4);
  float*    pcnt   = (float*)   A((size_t)PARENTN*4);
  float*    sdia   = (float*)   A((size_t)CHILDN*64*4);  // sin(dia_w+dia_b) cols 64..127
  int*      tokid  = (int*)     A((size_t)TT*4);
  int*      toknt  = (int*)     A((size_t)TT*4);
  int*      gnid2  = (int*)     A((size_t)N2N*4);
  int*      idxS1  = (int*)     A((size_t)NTY*N1SN*4);
  int*      idxS2  = (int*)     A((size_t)NTY*N1DN*4);
  int*      idxS3  = (int*)     A((size_t)NTY*N2N*4);
  int*      idxS4  = (int*)     A((size_t)NTY*TT*4);
  int*      idxS5  = (int*)     A((size_t)NTY*N4DN*4);
  int*      cntall = (int*)     A((size_t)5*NTY*4);
  int*      tdesc  = (int*)     A((size_t)3*TDSTRIDE*4);
  int*      tcnt   = (int*)     A((size_t)8*4);
  float*    EW2all = (float*)   A((size_t)4*50*HH*4);
  short*    Wsw    = (short*)   A((size_t)64*16384*2);   // bf16-swizzled weights
  int*      g1row  = (int*)     A((size_t)(N1DN+1)*4);
  int2*     g1meta = (int2*)    A((size_t)E1N*8);
  int*      g1rank = (int*)     A((size_t)E1N*4);
  int*      g2row  = (int*)     A((size_t)(TT+1)*4);
  int2*     g2meta = (int2*)    A((size_t)E2N*8);
  int*      g2rank = (int*)     A((size_t)E2N*4);
  int*      g4row  = (int*)     A((size_t)(N4DN+1)*4);
  int2*     g4meta = (int2*)    A((size_t)E4N*8);
  int*      g4rank = (int*)     A((size_t)E4N*4);
  int*      icnt1  = (int*)     A((size_t)(N1DN+1)*4);
  int*      icnt2  = (int*)     A((size_t)(TT+1)*4);
  int*      icnt3  = (int*)     A((size_t)(N4DN+1)*4);
  if(off > ws_size) return;  // insufficient scratch: output stays zero

  auto run_conv = [&](int cfg, int gkvq, int gq,
                      const float* src_X, const int* src_nid, const int* srcmap,
                      const int* idx_src, int* cnt_src, int stride_src,
                      const float* q_X, const int* q_map,
                      const float* resid_X, const int* r_map, int ndst,
                      const int* idx_dst, int* cnt_dst, int stride_dst,
                      const int* rowp, const int2* meta,
                      int layer, float* outbuf, float* out2, int relu){
    const bfrag* WB = (const bfrag*)Wsw;
    const bfrag* WK = WB + (size_t)( 0 + layer*4)*2048;
    const bfrag* WV = WB + (size_t)(16 + layer*4)*2048;
    const bfrag* WQ = WB + (size_t)(32 + layer*4)*2048;
    const bfrag* WO = WB + (size_t)(48 + layer*4)*2048;
    const float* MU  = convMu + (size_t)layer*NRL*NH;
    const float* EW2 = EW2all + (size_t)layer*50*HH;
    const int* td = tdesc + (size_t)cfg*TDSTRIDE;
    const int* tc = tcnt + cfg*2;
    k_gemm_kvq<<<gkvq, 256, 0, stream>>>(td, tc, src_X, src_nid, srcmap, sdia,
                                         idx_src, cnt_src, stride_src, WK, WV, KVp,
                                         q_X, q_map, idx_dst, cnt_dst, stride_dst, WQ, Qbuf);
    k_attn_fused8<<<ndst, HH, 0, stream>>>(rowp, meta, KVp, Qbuf, EW2, MU, Abuf);
    k_gemm_t5<<<gq, 256, 0, stream>>>(td, tc, Abuf, idx_dst, cnt_dst, stride_dst, WO,
                                      resid_X, r_map, outbuf, out2, relu);
  };

  // ---- upfront: merged init, merged scatters+hists, tiles, scan, fill ----
  k_init<<<(CHILDN*HH+255)/256, 256, 0, stream>>>(hist2, cnt, amax, aden, psum, pcnt, cntall,
                                                  icnt1, icnt2, icnt3,
                                                  dia_w, dia_b, sdia,
                                                  convK, convV, convQ, convO, Wsw,
                                                  edge_emb, convE, EW2all);
  {
    const int B1 = (N1SN+255)/256, B2 = (TT+255)/256, B3 = (N2N+255)/256;
    const int BE1 = (E1N+255)/256, BE2 = (E2N+255)/256, BE3 = (E4N+255)/256;
    k_scatall<<<B1+B2+B3+BE1+BE2+BE3, 256, 0, stream>>>(g1_nt, seq, seq_nt, g2_sel, g1_nid,
                                            tokid, toknt, gnid2, cntall,
                                            idxS1, idxS2, idxS5, idxS4, idxS3,
                                            g1_edst, icnt1, g1rank,
                                            g2_edst, icnt2, g2rank,
                                            g4_edst, icnt3, g4rank);
  }
  k_mktiles<<<1, 256, 0, stream>>>(cntall, tdesc, tcnt);
  k_scan3<<<3, 1024, 0, stream>>>(icnt1, N1DN, g1row,
                                  icnt2, TT,   g2row,
                                  icnt3, N4DN, g4row);
  {
    const int BE1 = (E1N+255)/256, BE2 = (E2N+255)/256, BE3 = (E4N+255)/256;
    k_fillperm3<<<BE1+BE2+BE3, 256, 0, stream>>>(g1_edst, g1_esrc, g1_ew, g1_ety, g1row, g1rank, g1meta,
                                                 g2_edst, g2_esrc, g2_ew, g2_ety, g2row, g2rank, g2meta,
                                                 g4_edst, g4_esrc, g4_ew, g4_ety, g4row, g4rank, g4meta);
  }

  // ---- stage A: features + LSTM1 (fused scan) ----
  k_featx2<<<TT/32, 512, 0, stream>>>(seq, dur, stime, etime, emb, dia_w, dia_b, t2v_w, t2v_b, exp_W, exp_b, xbuf);
  k_xwi2<<<(TT+15)/16, 256, 0, stream>>>(xbuf, l1Wi, l1b, gpre, TT, 0);
  k_lstm_fused<<<BB, 512, 0, stream>>>(gpre, l1Wh, h1, (float*)nullptr);

  // grid bounds (true tile counts are device-side; these are safe upper bounds)
  const int GKVQ_A = (N1SN+N1DN)/32 + 8;   // conv1 / conv3
  const int GKVQ_B = (N2N+TT)/32 + 8;      // conv2
  const int GKVQ_C = (N1DN+N4DN)/32 + 8;   // conv4
  const int GQ_A   = (N1DN+31)/32 + 4;
  const int GQ_B   = (TT+31)/32 + 4;
  const int GQ_C   = (N4DN+31)/32 + 4;

  // ---- conv1 on g1 (src/dst features gathered from emb via g1_nid in the gemms) ----
  run_conv(0, GKVQ_A, GQ_A,
           emb, g1_nid, g1_nid, idxS1, cntall+0*NTY, N1SN,
           emb, g1_nid,
           emb, g1_nid, N1DN, idxS2, cntall+1*NTY, N1DN,
           g1row, g1meta, 0, xg, (float*)nullptr, 1);

  // ---- conv2 on g2 (src features gathered from xg via g2_sel in the gemm) ----
  k_dst2<<<TT, HH, 0, stream>>>(tok_sel, xg, h1, dst2);
  run_conv(1, GKVQ_B, GQ_B,
           xg, gnid2, g2_sel, idxS3, cntall+2*NTY, N2N,
           dst2, (const int*)nullptr,
           dst2, (const int*)nullptr, TT, idxS4, cntall+3*NTY, TT,
           g2row, g2meta, 1, x2, (float*)nullptr, 1);

  // ---- LSTM2 (h2 is output 0); x2 read directly with permuted layout ----
  k_xwi2<<<(TT+15)/16, 256, 0, stream>>>(x2, l2Wi, l2b, gpre, TT, 1);
  k_lstm_fused<<<BB, 512, 0, stream>>>(gpre, l2Wh, h2f, outp);

  // ---- stage D: token attention pooling -> hist2 (histfix fused into k_x0) ----
  k_tokatt<<<TT, HH, 0, stream>>>(h2f, toknt, ipW, iaW, abuf, amax, tokid);
  k_tokexp<<<(TT+255)/256, 256, 0, stream>>>(tokid, abuf, amax, aden, cnt);
  k_tokagg<<<TT, HH, 0, stream>>>(tokid, abuf, aden, h2f, hist2);

  // ---- conv3 on g1 with skip-mixed input (g1 CSR + scatters + tiles reused) ----
  k_x0<<<N1SN, HH, 0, stream>>>(g1_nid, g1_nt, emb, hist2, cnt, hist_emb, skip, srcbuf);
  run_conv(0, GKVQ_A, GQ_A,
           srcbuf, g1_nid, (const int*)nullptr, idxS1, cntall+0*NTY, N1SN,
           srcbuf, (const int*)nullptr,
           srcbuf, (const int*)nullptr, N1DN, idxS2, cntall+1*NTY, N1DN,
           g1row, g1meta, 2, x3, (float*)nullptr, 1);

  // ---- conv4 on g4 (child_embed = output 1, no relu) ----
  run_conv(2, GKVQ_C, GQ_C,
           x3, g1_nid, (const int*)nullptr, idxS2, cntall+1*NTY, N1DN,
           x3, (const int*)nullptr,
           x3, (const int*)nullptr, N4DN, idxS5, cntall+4*NTY, N4DN,
           g4row, g4meta, 3, cef, outp + (size_t)TT*HH, 0);

  // ---- parent pooling (output 2) ----
  k_peagg<<<EC2PN, HH, 0, stream>>>(pe_p, pe_c, cef, psum, pcnt);
  k_parent<<<PARENTN, HH, 0, stream>>>(psum, pcnt, outp + (size_t)TT*HH + (size_t)N4DN*HH);
}

// Round 11
// 678.862 us; speedup vs baseline: 1.1758x; 1.0257x over previous
//
#include <hip/hip_runtime.h>
#include <math.h>

#define BB 256
#define LL 20
#define HH 128
#define NH 8
#define D2C 64
#define NTY 4
#define NRL 4
#define CHILDN 30001
#define PARENTN 500
#define N1SN 50000
#define N1DN 20000
#define E1N 300000
#define N2N 20000
#define E2N 200000
#define TT (BB*LL)
#define N4DN 5000
#define E4N 150000
#define EC2PN 8000
#define TDSTRIDE 2304

typedef __attribute__((ext_vector_type(8))) short bfrag;   // 8 bf16 in 4 VGPRs
typedef __attribute__((ext_vector_type(4))) float ffrag;   // MFMA accumulator

__device__ __forceinline__ unsigned fenc(float f){ unsigned u=__float_as_uint(f); return (u&0x80000000u)? ~u : (u|0x80000000u); }
__device__ __forceinline__ float fdec(unsigned u){ return (u&0x80000000u)? __uint_as_float(u^0x80000000u) : __uint_as_float(~u); }
__device__ __forceinline__ float sigfast(float x){ return 1.f/(1.f+__expf(-x)); }
__device__ __forceinline__ float tanhfast(float x){ float e = __expf(-2.f*x); return (1.f-e)/(1.f+e); }
__device__ __forceinline__ short f2bf(float f){
  unsigned u = __float_as_uint(f);
  unsigned r = u + 0x7FFFu + ((u>>16)&1u);   // round-to-nearest-even
  return (short)(r>>16);
}

// ---------------- upfront init: zero/poison buffers + sin table + weight prepack
// (conv K/V/Q/O + ipW) + edge tables, all folded into one grid ----------------
__global__ void k_init(float* hist2, float* cnt, unsigned* amax, float* aden,
                       float* psum, float* pcnt, int* cntall,
                       int* icnt1, int* icnt2, int* icnt3,
                       const float* __restrict__ dia_w, const float* __restrict__ dia_b,
                       float* __restrict__ sdia,
                       const float* convK, const float* convV, const float* convQ,
                       const float* convO, short* Wsw,
                       const float* ipW, short* WswI,
                       const float* edge_emb, const float* convE, float* EW2all){
  int i = blockIdx.x*256 + threadIdx.x;
  if(i < CHILDN*HH) hist2[i] = 0.f;
  if(i < CHILDN){ cnt[i] = 0.f; aden[i] = 0.f; amax[i] = 0x007FFFFFu; }
  if(i < PARENTN*HH) psum[i] = 0.f;
  if(i < PARENTN) pcnt[i] = 0.f;
  if(i < 5*NTY) cntall[i] = 0;
  if(i < N1DN) icnt1[i] = 0;
  if(i < TT)   icnt2[i] = 0;
  if(i < N4DN) icnt3[i] = 0;
  if(i < CHILDN*64){
    int c = i >> 6, k = (i & 63) + 64;
    sdia[i] = __sinf(dia_w[(size_t)c*HH+k] + dia_b[(size_t)c*HH+k]);
  }
  if(i < 64*16384){
    int m = i >> 14, im = i & 16383;
    int fam = m >> 4, lt = m & 15;
    const float* src = (fam==0?convK:fam==1?convV:fam==2?convQ:convO) + (size_t)lt*HH*HH;
    int j = im & 7, lane = (im>>3)&63, kc = (im>>9)&3, nt = im>>11;
    int k = kc*32 + (lane>>4)*8 + j;
    int n = nt*16 + (lane&15);
    Wsw[(size_t)m*16384 + im] = f2bf(src[k*HH+n]);
  }
  if(i < 4*16384){
    int m = i >> 14, im = i & 16383;
    const float* src = ipW + (size_t)m*HH*HH;
    int j = im & 7, lane = (im>>3)&63, kc = (im>>9)&3, nt = im>>11;
    int k = kc*32 + (lane>>4)*8 + j;
    int n = nt*16 + (lane&15);
    WswI[(size_t)m*16384 + im] = f2bf(src[k*HH+n]);
  }
  if(i < 4*50*HH){
    int layer = i/(50*HH), rr = (i/HH)%50, o = i%HH;
    const float* EWp = convE + (size_t)layer*32*HH;
    float acc = 0.f;
    for(int j=0;j<32;j++) acc += edge_emb[rr*32+j]*EWp[j*HH+o];
    EW2all[i] = acc;
  }
}

// ---------------- Stage A: feature expansion (tiled: 32 tokens/block) ----------------
__global__ __launch_bounds__(512) void k_featx2(const int* __restrict__ seq, const int* __restrict__ dur,
                        const int* __restrict__ stime, const int* __restrict__ etime,
                        const float* __restrict__ emb, const float* __restrict__ dia_w, const float* __restrict__ dia_b,
                        const float* __restrict__ t2v_w, const float* __restrict__ t2v_b,
                        const float* __restrict__ exp_W, const float* __restrict__ exp_b, float* __restrict__ xout){
  __shared__ float feat[32*273];           // [st(128) | et(128) | tv(16)] per token, stride 273
  int base = blockIdx.x*32;
  int j = threadIdx.x >> 4;                // token 0..31
  int p = threadIdx.x & 15;                // 16 threads/token, 8 cols each
  int row = base + j;
  int node = seq[row];
  float ts = (float)stime[row], te = (float)etime[row];
  const float* ep = emb + (size_t)node*HH;
  float* fr = feat + j*273;
  int o0 = p*8;
  #pragma unroll
  for(int ii=0; ii<8; ii+=4){
    int o = o0 + ii;
    float4 e = *(const float4*)(ep + o);
    float4 st = e, et = e;
    if(o >= D2C){
      float4 w = *(const float4*)(dia_w + (size_t)node*HH + o);
      float4 b = *(const float4*)(dia_b + (size_t)node*HH + o);
      st.x = e.x*__sinf(w.x*ts+b.x); st.y = e.y*__sinf(w.y*ts+b.y);
      st.z = e.z*__sinf(w.z*ts+b.z); st.w = e.w*__sinf(w.w*ts+b.w);
      et.x = e.x*__sinf(w.x*te+b.x); et.y = e.y*__sinf(w.y*te+b.y);
      et.z = e.z*__sinf(w.z*te+b.z); et.w = e.w*__sinf(w.w*te+b.w);
    }
    fr[o] = st.x; fr[o+1] = st.y; fr[o+2] = st.z; fr[o+3] = st.w;
    fr[128+o] = et.x; fr[128+o+1] = et.y; fr[128+o+2] = et.z; fr[128+o+3] = et.w;
  }
  if(p == 0){
    float td = (float)dur[row];
    #pragma unroll
    for(int i=0;i<16;i++){
      float w = t2v_w[i], b = t2v_b[i];
      fr[256+i] = (i==0) ? (w*td + b) : __sinf(w*td + b);
    }
  }
  __syncthreads();
  // GEMM: 32x272 @ 272x128, each thread: 2 rows x 4 cols
  int oc = (threadIdx.x & 31)*4;
  int jg = threadIdx.x >> 5;               // 0..15
  const float* f0 = feat + (jg*2)*273;
  const float* f1 = feat + (jg*2+1)*273;
  float4 a0 = {0,0,0,0}, a1 = {0,0,0,0};
  for(int k=0;k<272;k++){
    float4 w = *(const float4*)(exp_W + (size_t)k*HH + oc);
    float x0 = f0[k], x1 = f1[k];
    a0.x += x0*w.x; a0.y += x0*w.y; a0.z += x0*w.z; a0.w += x0*w.w;
    a1.x += x1*w.x; a1.y += x1*w.y; a1.z += x1*w.z; a1.w += x1*w.w;
  }
  float4 bv = *(const float4*)(exp_b + oc);
  a0.x = fmaxf(a0.x+bv.x, 0.f); a0.y = fmaxf(a0.y+bv.y, 0.f);
  a0.z = fmaxf(a0.z+bv.z, 0.f); a0.w = fmaxf(a0.w+bv.w, 0.f);
  a1.x = fmaxf(a1.x+bv.x, 0.f); a1.y = fmaxf(a1.y+bv.y, 0.f);
  a1.z = fmaxf(a1.z+bv.z, 0.f); a1.w = fmaxf(a1.w+bv.w, 0.f);
  *(float4*)(xout + (size_t)(base + jg*2  )*HH + oc) = a0;
  *(float4*)(xout + (size_t)(base + jg*2+1)*HH + oc) = a1;
}

// tiled x @ Wi + b -> gpre: 16 rows x 512 cols per block; perm=1 reads x in (l*BB+b) layout
__global__ void k_xwi2(const float* x, const float* Wi, const float* bias, float* gpre, int rows, int perm){
  int base = blockIdx.x*16;
  __shared__ float xs[128*17];
  int tid = threadIdx.x;
  #pragma unroll
  for(int s=0;s<8;s++){
    int elem = tid + 256*s;
    int k = elem & 127, j = elem >> 7;
    int r = base + j;
    int src = r;
    if(perm) src = (r % LL)*BB + (r / LL);
    xs[k*17 + j] = (r < rows) ? x[(size_t)src*HH + k] : 0.f;
  }
  __syncthreads();
  int o4 = (tid & 127)*4;
  int ng = tid >> 7;
  float4 a[8];
  #pragma unroll
  for(int j=0;j<8;j++) a[j]=make_float4(0,0,0,0);
  for(int k=0;k<HH;k++){
    float4 w = *(const float4*)(Wi + (size_t)k*512 + o4);
    const float* xr = xs + k*17 + ng*8;
    #pragma unroll
    for(int j=0;j<8;j++){
      float xv = xr[j];
      a[j].x += xv*w.x; a[j].y += xv*w.y; a[j].z += xv*w.z; a[j].w += xv*w.w;
    }
  }
  float4 bv = *(const float4*)(bias + o4);
  #pragma unroll
  for(int j=0;j<8;j++){
    int r = base + ng*8 + j;
    if(r < rows){
      float4 v = a[j];
      v.x += bv.x; v.y += bv.y; v.z += bv.z; v.w += bv.w;
      *(float4*)(gpre + (size_t)r*512 + o4) = v;
    }
  }
}

// fused 20-step LSTM: one block per batch row, Wh column in registers, gpre
// prefetched into registers, activations spread across all 512 threads.
__global__ __launch_bounds__(512, 2) void k_lstm_fused(const float* __restrict__ gpre,
                                                       const float* __restrict__ Wh,
                                                       float* __restrict__ hout,
                                                       float* __restrict__ hout2){
  int b = blockIdx.x;
  int o = threadIdx.x;
  __shared__ float hs[HH];
  __shared__ float act[512];
  float wr[HH];
  #pragma unroll
  for(int h=0;h<HH;h++) wr[h] = Wh[(size_t)h*512 + o];
  float gv[LL];
  const float* gp = gpre + (size_t)b*LL*512 + o;
  #pragma unroll
  for(int l=0;l<LL;l++) gv[l] = gp[(size_t)l*512];
  if(o < HH) hs[o] = 0.f;
  float cc = 0.f;
  int quad = o >> 7;                        // 0=i, 1=f, 2=g, 3=o
  __syncthreads();
  for(int l=0;l<LL;l++){
    float a0=0.f,a1=0.f,a2=0.f,a3=0.f;
    #pragma unroll
    for(int h=0;h<HH;h+=4){
      float4 hv = *(const float4*)&hs[h];
      a0 += hv.x*wr[h];   a1 += hv.y*wr[h+1];
      a2 += hv.z*wr[h+2]; a3 += hv.w*wr[h+3];
    }
    float g = gv[l] + ((a0+a1)+(a2+a3));
    act[o] = (quad==2) ? tanhfast(g) : sigfast(g);
    __syncthreads();
    if(o < HH){
      cc = act[HH+o]*cc + act[o]*act[2*HH+o];
      float hh = act[3*HH+o]*tanhfast(cc);
      hs[o] = hh;
      size_t bi = ((size_t)b*LL + l)*HH + o;
      hout[bi] = hh;
      if(hout2) hout2[bi] = hh;
    }
    __syncthreads();
  }
}

// ---------------- merged scatters + edge histograms (block ranges) ----------------
__global__ void k_scatall(const int* __restrict__ g1_nt, const int* __restrict__ seq,
                          const int* __restrict__ seq_nt, const int* __restrict__ g2_sel,
                          const int* __restrict__ g1_nid,
                          int* __restrict__ tokid, int* __restrict__ toknt, int* __restrict__ gnid2,
                          int* __restrict__ cntall,
                          int* __restrict__ idxS1, int* __restrict__ idxS2, int* __restrict__ idxS5,
                          int* __restrict__ idxS4, int* __restrict__ idxS3,
                          const int* __restrict__ e1d, int* __restrict__ icnt1, int* __restrict__ rank1,
                          const int* __restrict__ e2d, int* __restrict__ icnt2, int* __restrict__ rank2,
                          const int* __restrict__ e3d, int* __restrict__ icnt3, int* __restrict__ rank3){
  const int B1 = (N1SN+255)/256;
  const int B2 = (TT+255)/256;
  const int B3 = (N2N+255)/256;
  const int BE1 = (E1N+255)/256;
  const int BE2 = (E2N+255)/256;
  __shared__ int h[3][NTY];
  __shared__ int bs[3][NTY];
  int bx = blockIdx.x;
  if(bx < B1){
    int i = bx*256 + threadIdx.x;
    if(threadIdx.x < 3*NTY) (&h[0][0])[threadIdx.x] = 0;
    __syncthreads();
    int t = 0, r1 = 0, r2 = 0, r3 = 0;
    bool a1 = (i < N1SN), a2 = (i < N1DN), a3 = (i < N4DN);
    if(a1){
      t = g1_nt[i];
      r1 = atomicAdd(&h[0][t], 1);
      if(a2) r2 = atomicAdd(&h[1][t], 1);
      if(a3) r3 = atomicAdd(&h[2][t], 1);
    }
    __syncthreads();
    if(threadIdx.x < NTY){
      int ty = threadIdx.x;
      if(h[0][ty] > 0) bs[0][ty] = atomicAdd(&cntall[0*NTY+ty], h[0][ty]);
      if(h[1][ty] > 0) bs[1][ty] = atomicAdd(&cntall[1*NTY+ty], h[1][ty]);
      if(h[2][ty] > 0) bs[2][ty] = atomicAdd(&cntall[4*NTY+ty], h[2][ty]);
    }
    __syncthreads();
    if(a1) idxS1[t*N1SN + bs[0][t] + r1] = i;
    if(a2) idxS2[t*N1DN + bs[1][t] + r2] = i;
    if(a3) idxS5[t*N4DN + bs[2][t] + r3] = i;
  } else if(bx < B1 + B2){
    int i = (bx - B1)*256 + threadIdx.x;
    if(threadIdx.x < NTY) h[0][threadIdx.x] = 0;
    __syncthreads();
    int nt = 0, r = 0;
    bool act = (i < TT);
    if(act){
      int b = i % BB, l = i / BB;
      tokid[i] = seq[b*LL+l];
      nt = seq_nt[b*LL+l];
      toknt[i] = nt;
      r = atomicAdd(&h[0][nt], 1);
    }
    __syncthreads();
    if(threadIdx.x < NTY && h[0][threadIdx.x] > 0)
      bs[0][threadIdx.x] = atomicAdd(&cntall[3*NTY+threadIdx.x], h[0][threadIdx.x]);
    __syncthreads();
    if(act) idxS4[nt*TT + bs[0][nt] + r] = i;
  } else if(bx < B1 + B2 + B3){
    int i = (bx - B1 - B2)*256 + threadIdx.x;
    if(threadIdx.x < NTY) h[0][threadIdx.x] = 0;
    __syncthreads();
    int nt = 0, r = 0;
    bool act = (i < N2N);
    if(act){
      int s = g2_sel[i];
      gnid2[i] = g1_nid[s];
      nt = g1_nt[s];
      r = atomicAdd(&h[0][nt], 1);
    }
    __syncthreads();
    if(threadIdx.x < NTY && h[0][threadIdx.x] > 0)
      bs[0][threadIdx.x] = atomicAdd(&cntall[2*NTY+threadIdx.x], h[0][threadIdx.x]);
    __syncthreads();
    if(act) idxS3[nt*N2N + bs[0][nt] + r] = i;
  } else if(bx < B1 + B2 + B3 + BE1){
    int e = (bx - B1 - B2 - B3)*256 + threadIdx.x;
    if(e < E1N) rank1[e] = atomicAdd(&icnt1[e1d[e]], 1);
  } else if(bx < B1 + B2 + B3 + BE1 + BE2){
    int e = (bx - B1 - B2 - B3 - BE1)*256 + threadIdx.x;
    if(e < E2N) rank2[e] = atomicAdd(&icnt2[e2d[e]], 1);
  } else {
    int e = (bx - B1 - B2 - B3 - BE1 - BE2)*256 + threadIdx.x;
    if(e < E4N) rank3[e] = atomicAdd(&icnt3[e3d[e]], 1);
  }
}

__global__ void k_dst2(const int* tok_sel, const float* xg, const float* h1, float* dst2){
  int t = blockIdx.x; int o = threadIdx.x;
  int b = t % BB, l = t / BB;
  dst2[t*HH+o] = xg[tok_sel[t]*HH+o] + h1[(b*LL+l)*HH+o];
}

// skip-mixed input with histfix fused (cnt==0 -> hist_emb fallback)
__global__ void k_x0(const int* nid, const int* ntype, const float* emb, const float* hist2,
                     const float* cnt, const float* hist_emb, const float* skip, float* srcbuf){
  int i = blockIdx.x; int o = threadIdx.x;
  float a = sigfast(skip[ntype[i]]);
  int nd = nid[i];
  float hv = (cnt[nd] > 0.f) ? hist2[(size_t)nd*HH+o] : hist_emb[(size_t)nd*HH+o];
  srcbuf[i*HH+o] = emb[(size_t)nd*HH+o]*a + hv*(1.f-a);
}

// ---- tile-descriptor builder: compacted work lists for the 3 unique conv configs.
__global__ void k_mktiles(const int* __restrict__ cntall, int* __restrict__ tdesc, int* __restrict__ tcnt){
  __shared__ int start[3][2][NTY];
  if(threadIdx.x == 0){
    const int srcg[3] = {0,2,1};
    const int dstg[3] = {1,3,4};
    for(int c=0;c<3;c++){
      int acc = 0;
      for(int z=0;z<2;z++){
        int g = (z==0) ? srcg[c] : dstg[c];
        int zacc = 0;
        for(int t=0;t<NTY;t++){
          start[c][z][t] = acc;
          int tiles = (cntall[g*NTY+t]+31)>>5;
          acc += tiles; zacc += tiles;
        }
        tcnt[c*2+z] = zacc;
      }
    }
  }
  __syncthreads();
  const int srcg[3] = {0,2,1};
  const int dstg[3] = {1,3,4};
  for(int c=0;c<3;c++){
    for(int z=0;z<2;z++){
      int g = (z==0) ? srcg[c] : dstg[c];
      for(int t=0;t<NTY;t++){
        int tiles = (cntall[g*NTY+t]+31)>>5;
        for(int i=threadIdx.x; i<tiles; i+=blockDim.x)
          tdesc[c*TDSTRIDE + start[c][z][t] + i] = (int)(((unsigned)z<<31) | ((unsigned)t<<28) | (unsigned)(i<<5));
      }
    }
  }
}

// ---- fused KV (z=0) + Q (z=1) projection via MFMA; compacted 1-D tile list,
// float4 staging, warp-level LN reduce (float4 LDS reads), float4 normalize pass.
__global__ __launch_bounds__(256) void k_gemm_kvq(
    const int* __restrict__ tdesc, const int* __restrict__ tcnt,
    const float* __restrict__ Xs, const int* __restrict__ src_nid, const int* __restrict__ smap,
    const float* __restrict__ sdia,
    const int* __restrict__ idxs, const int* __restrict__ cnts_s, int stride_s,
    const bfrag* __restrict__ WK, const bfrag* __restrict__ WV, unsigned* __restrict__ KVp,
    const float* __restrict__ Xq, const int* __restrict__ qmap,
    const int* __restrict__ idxd, const int* __restrict__ cnts_d, int stride_d,
    const bfrag* __restrict__ WQ, float* __restrict__ Qbuf){
  __shared__ float xs[32*132];
  __shared__ float mean_s[32], inv_s[32];
  __shared__ int sid[32], nid[32], xrow[32];
  int ntk = tcnt[0], ntq = tcnt[1];
  int bid = blockIdx.x;
  if(bid >= ntk + ntq) return;
  unsigned ud = (unsigned)tdesc[bid];
  int isQ = ud >> 31;
  int t = (ud >> 28) & 7;
  int base = ud & 0x0FFFFFFF;
  int tid = threadIdx.x;
  int cnt = isQ ? cnts_d[t] : cnts_s[t];
  if(base >= cnt) return;
  int nn = min(32, cnt - base);
  const float* X = isQ ? Xq : Xs;
  const int* map = isQ ? qmap : smap;
  const int* ids = (isQ ? idxd + (size_t)t*stride_d : idxs + (size_t)t*stride_s) + base;
  if(tid < 32){
    int s_ = (tid < nn) ? ids[tid] : ids[0];
    sid[tid] = s_;
    if(!isQ) nid[tid] = src_nid[s_];
    xrow[tid] = map ? map[s_] : s_;
  }
  __syncthreads();
  // float4 staging: 1024 float4 = 32 rows x 128 cols
  #pragma unroll
  for(int s=0;s<4;s++){
    int e4 = tid + 256*s;
    int j = e4 >> 5, c4 = (e4 & 31)*4;
    *(float4*)&xs[j*132 + c4] = *(const float4*)&X[(size_t)xrow[j]*HH + c4];
  }
  __syncthreads();
  // warp-level LN reduce: 8 lanes per row, float4 LDS reads, shfl_xor over p
  {
    int wid = tid >> 6, lane = tid & 63;
    int row = wid*8 + (lane>>3), p = lane & 7;
    const float* xr = xs + row*132 + p*16;
    float sm=0.f, sq=0.f;
    #pragma unroll
    for(int i=0;i<4;i++){
      float4 v = *(const float4*)(xr + i*4);
      sm += (v.x+v.y)+(v.z+v.w);
      sq += (v.x*v.x+v.y*v.y)+(v.z*v.z+v.w*v.w);
    }
    sm += __shfl_xor(sm, 1, 64); sq += __shfl_xor(sq, 1, 64);
    sm += __shfl_xor(sm, 2, 64); sq += __shfl_xor(sq, 2, 64);
    sm += __shfl_xor(sm, 4, 64); sq += __shfl_xor(sq, 4, 64);
    if(p == 0){
      float mean = sm*(1.f/128.f);
      float var = sq*(1.f/128.f) - mean*mean;
      mean_s[row] = mean;
      inv_s[row] = 1.f/sqrtf(fmaxf(var,0.f)+1e-5f);
    }
  }
  __syncthreads();
  // float4 normalize pass (+ sdia time-mod on cols 64..127 for the KV path)
  #pragma unroll
  for(int s=0;s<4;s++){
    int e4 = tid + 256*s;
    int j = e4 >> 5, c4 = (e4 & 31)*4;
    float* px = &xs[j*132 + c4];
    float4 v = *(float4*)px;
    float mj = mean_s[j], ij = inv_s[j];
    v.x = (v.x-mj)*ij; v.y = (v.y-mj)*ij; v.z = (v.z-mj)*ij; v.w = (v.w-mj)*ij;
    if(!isQ && c4 >= D2C){
      float4 sd = *(const float4*)(sdia + (size_t)nid[j]*64 + (c4 - D2C));
      v.x *= sd.x; v.y *= sd.y; v.z *= sd.z; v.w *= sd.w;
    }
    *(float4*)px = v;
  }
  __syncthreads();
  int lane = tid & 63, w = tid >> 6;
  int mt = w & 1, ng0 = (w>>1)*4;
  int arow = mt*16 + (lane & 15);
  int koff = (lane >> 4)*8;
  int tb = t*2048;
  if(!isQ){
    ffrag aK[4], aV[4];
    #pragma unroll
    for(int i=0;i<4;i++){ aK[i] = (ffrag){0.f,0.f,0.f,0.f}; aV[i] = (ffrag){0.f,0.f,0.f,0.f}; }
    #pragma unroll
    for(int kc=0;kc<4;kc++){
      const float* ap = xs + arow*132 + kc*32 + koff;
      bfrag a;
      #pragma unroll
      for(int j=0;j<8;j++) a[j] = f2bf(ap[j]);
      #pragma unroll
      for(int nt=0;nt<4;nt++){
        int fi = tb + ((ng0+nt)*4 + kc)*64 + lane;
        bfrag bk = WK[fi];
        bfrag bv = WV[fi];
        aK[nt] = __builtin_amdgcn_mfma_f32_16x16x32_bf16(a, bk, aK[nt], 0, 0, 0);
        aV[nt] = __builtin_amdgcn_mfma_f32_16x16x32_bf16(a, bv, aV[nt], 0, 0, 0);
      }
    }
    int col0 = lane & 15;
    int rb = mt*16 + (lane>>4)*4;
    #pragma unroll
    for(int nt=0;nt<4;nt++){
      int col = (ng0+nt)*16 + col0;
      #pragma unroll
      for(int i=0;i<4;i++){
        int n = rb + i;
        if(n < nn){
          unsigned pk = (unsigned short)f2bf(aK[nt][i]);
          unsigned pv = (unsigned short)f2bf(aV[nt][i]);
          KVp[(size_t)sid[n]*HH + col] = (pv<<16) | pk;
        }
      }
    }
  } else {
    ffrag acc[4];
    #pragma unroll
    for(int i=0;i<4;i++) acc[i] = (ffrag){0.f,0.f,0.f,0.f};
    #pragma unroll
    for(int kc=0;kc<4;kc++){
      const float* ap = xs + arow*132 + kc*32 + koff;
      bfrag a;
      #pragma unroll
      for(int j=0;j<8;j++) a[j] = f2bf(ap[j]);
      #pragma unroll
      for(int nt=0;nt<4;nt++){
        bfrag b = WQ[tb + ((ng0+nt)*4 + kc)*64 + lane];
        acc[nt] = __builtin_amdgcn_mfma_f32_16x16x32_bf16(a, b, acc[nt], 0, 0, 0);
      }
    }
    int col0 = lane & 15;
    int rb = mt*16 + (lane>>4)*4;
    #pragma unroll
    for(int nt=0;nt<4;nt++){
      int col = (ng0+nt)*16 + col0;
      #pragma unroll
      for(int i=0;i<4;i++){
        int n = rb + i;
        if(n < nn) Qbuf[(size_t)sid[n]*HH + col] = acc[nt][i];
      }
    }
  }
}

// ---- O projection via MFMA (resid+relu, optional copy); compacted dst tile list.
__global__ __launch_bounds__(256) void k_gemm_t5(
    const int* __restrict__ tdesc, const int* __restrict__ tcnt,
    const float* X, const int* idxb, const int* cnts, int stride,
    const bfrag* W, const float* resid, const int* rmap, float* Y, float* Y2,
    int relu){
  __shared__ float xs[32*132];
  __shared__ int sid[32], rrow[32];
  int ntk = tcnt[0], ntq = tcnt[1];
  if(blockIdx.x >= ntq) return;
  unsigned ud = (unsigned)tdesc[ntk + blockIdx.x];
  int t = (ud >> 28) & 7;
  int base = ud & 0x0FFFFFFF;
  int cnt = cnts[t];
  if(base >= cnt) return;
  int nn = min(32, cnt - base);
  const int* ids = idxb + (size_t)t*stride + base;
  int tid = threadIdx.x;
  if(tid < 32){
    int s_ = (tid < nn) ? ids[tid] : ids[0];
    sid[tid] = s_;
    rrow[tid] = rmap ? rmap[s_] : s_;
  }
  __syncthreads();
  #pragma unroll
  for(int s=0;s<4;s++){
    int e4 = tid + 256*s;
    int j = e4 >> 5, c4 = (e4 & 31)*4;
    *(float4*)&xs[j*132 + c4] = *(const float4*)&X[(size_t)sid[j]*HH + c4];
  }
  __syncthreads();
  int lane = tid & 63, w = tid >> 6;
  int mt = w & 1, ng0 = (w>>1)*4;
  int arow = mt*16 + (lane & 15);
  int koff = (lane >> 4)*8;
  int tb = t*2048;
  ffrag acc[4];
  #pragma unroll
  for(int i=0;i<4;i++) acc[i] = (ffrag){0.f,0.f,0.f,0.f};
  #pragma unroll
  for(int kc=0;kc<4;kc++){
    const float* ap = xs + arow*132 + kc*32 + koff;
    bfrag a;
    #pragma unroll
    for(int j=0;j<8;j++) a[j] = f2bf(ap[j]);
    #pragma unroll
    for(int nt=0;nt<4;nt++){
      bfrag b = W[tb + ((ng0+nt)*4 + kc)*64 + lane];
      acc[nt] = __builtin_amdgcn_mfma_f32_16x16x32_bf16(a, b, acc[nt], 0, 0, 0);
    }
  }
  int col0 = lane & 15;
  int rb = mt*16 + (lane>>4)*4;
  #pragma unroll
  for(int nt=0;nt<4;nt++){
    int col = (ng0+nt)*16 + col0;
    #pragma unroll
    for(int i=0;i<4;i++){
      int n = rb + i;
      if(n < nn){
        size_t r = (size_t)sid[n]*HH + col;
        float v = acc[nt][i];
        if(resid){
          v += resid[(size_t)rrow[n]*HH + col];
          if(relu) v = fmaxf(v, 0.f);
        }
        Y[r] = v;
        if(Y2) Y2[r] = v;
      }
    }
  }
}

// ---- token attention pooling via MFMA: 32-token tiles from cfg1 dst list.
// abuf[tok] = sum_o tanh((h2[tok] @ ipW[nt])[o]) * iaW[nt][o]; amax updated.
__global__ __launch_bounds__(256) void k_tokatt2(
    const int* __restrict__ tdesc, const int* __restrict__ tcnt,
    const float* __restrict__ h2f, const int* __restrict__ idxd, const int* __restrict__ cnts_d,
    const bfrag* __restrict__ WI, const float* __restrict__ iaW,
    const int* __restrict__ tokid, float* __restrict__ abuf, unsigned* __restrict__ amax){
  __shared__ float xs[32*132];
  __shared__ float red[32];
  __shared__ int sid[32];
  int ntk = tcnt[0], ntq = tcnt[1];
  if(blockIdx.x >= ntq) return;
  unsigned ud = (unsigned)tdesc[ntk + blockIdx.x];
  int t = (ud >> 28) & 7;
  int base = ud & 0x0FFFFFFF;
  int cnt = cnts_d[t];
  if(base >= cnt) return;
  int nn = min(32, cnt - base);
  const int* ids = idxd + (size_t)t*TT + base;
  int tid = threadIdx.x;
  if(tid < 32){
    sid[tid] = (tid < nn) ? ids[tid] : ids[0];
    red[tid] = 0.f;
  }
  __syncthreads();
  #pragma unroll
  for(int s=0;s<4;s++){
    int e4 = tid + 256*s;
    int j = e4 >> 5, c4 = (e4 & 31)*4;
    int tok = sid[j];
    int b = tok % BB, l = tok / BB;
    *(float4*)&xs[j*132 + c4] = *(const float4*)&h2f[((size_t)(b*LL+l))*HH + c4];
  }
  __syncthreads();
  int lane = tid & 63, w = tid >> 6;
  int mt = w & 1, ng0 = (w>>1)*4;
  int arow = mt*16 + (lane & 15);
  int koff = (lane >> 4)*8;
  int tb = t*2048;
  ffrag acc[4];
  #pragma unroll
  for(int i=0;i<4;i++) acc[i] = (ffrag){0.f,0.f,0.f,0.f};
  #pragma unroll
  for(int kc=0;kc<4;kc++){
    const float* ap = xs + arow*132 + kc*32 + koff;
    bfrag a;
    #pragma unroll
    for(int j=0;j<8;j++) a[j] = f2bf(ap[j]);
    #pragma unroll
    for(int nt=0;nt<4;nt++){
      bfrag b = WI[tb + ((ng0+nt)*4 + kc)*64 + lane];
      acc[nt] = __builtin_amdgcn_mfma_f32_16x16x32_bf16(a, b, acc[nt], 0, 0, 0);
    }
  }
  int col0 = lane & 15;
  int rb = mt*16 + (lane>>4)*4;
  float rsum[4] = {0.f, 0.f, 0.f, 0.f};
  #pragma unroll
  for(int nt=0;nt<4;nt++){
    int col = (ng0+nt)*16 + col0;
    float wia = iaW[t*HH + col];
    #pragma unroll
    for(int i=0;i<4;i++) rsum[i] += tanhfast(acc[nt][i]) * wia;
  }
  #pragma unroll
  for(int i=0;i<4;i++){
    rsum[i] += __shfl_xor(rsum[i], 1, 64);
    rsum[i] += __shfl_xor(rsum[i], 2, 64);
    rsum[i] += __shfl_xor(rsum[i], 4, 64);
    rsum[i] += __shfl_xor(rsum[i], 8, 64);
  }
  if(col0 == 0){
    #pragma unroll
    for(int i=0;i<4;i++) atomicAdd(&red[rb+i], rsum[i]);
  }
  __syncthreads();
  if(tid < nn){
    int tok = sid[tid];
    float a = red[tid];
    abuf[tok] = a;
    atomicMax(&amax[tokid[tok]], fenc(a));
  }
}

// one block per graph: exclusive scan of counts -> row_ptr
__global__ void k_scan3(const int* c1, int n1, int* r1,
                        const int* c2, int n2, int* r2,
                        const int* c3, int n3, int* r3){
  __shared__ int tsum[1024];
  const int* cnt; int n; int* row_ptr;
  if(blockIdx.x == 0){ cnt=c1; n=n1; row_ptr=r1; }
  else if(blockIdx.x == 1){ cnt=c2; n=n2; row_ptr=r2; }
  else { cnt=c3; n=n3; row_ptr=r3; }
  int tid = threadIdx.x;
  int per = (n + 1023) / 1024;
  int start = tid*per; int end = min(start+per, n);
  int s = 0;
  for(int i=start;i<end;i++) s += cnt[i];
  tsum[tid] = s; __syncthreads();
  for(int off=1;off<1024;off<<=1){
    int v = (tid>=off) ? tsum[tid-off] : 0;
    __syncthreads();
    tsum[tid] += v;
    __syncthreads();
  }
  int run = (tid==0) ? 0 : tsum[tid-1];
  for(int i=start;i<end;i++){ row_ptr[i]=run; run += cnt[i]; }
  if(end == n) row_ptr[n] = run;
}
// merged fill over 3 graphs using precomputed ranks: pos = row_ptr[dst] + rank
__global__ void k_fillperm3(const int* d1, const int* s1, const int* w1, const int* t1,
                            const int* rp1, const int* rk1, int2* m1,
                            const int* d2, const int* s2, const int* w2, const int* t2,
                            const int* rp2, const int* rk2, int2* m2,
                            const int* d3, const int* s3, const int* w3, const int* t3,
                            const int* rp3, const int* rk3, int2* m3){
  const int B1 = (E1N+255)/256, B2 = (E2N+255)/256;
  int bx = blockIdx.x;
  if(bx < B1){
    int e = bx*256 + threadIdx.x;
    if(e < E1N){ int pos = rp1[d1[e]] + rk1[e]; m1[pos] = make_int2(s1[e], w1[e] | (t1[e]<<16)); }
  } else if(bx < B1+B2){
    int e = (bx-B1)*256 + threadIdx.x;
    if(e < E2N){ int pos = rp2[d2[e]] + rk2[e]; m2[pos] = make_int2(s2[e], w2[e] | (t2[e]<<16)); }
  } else {
    int e = (bx-B1-B2)*256 + threadIdx.x;
    if(e < E4N){ int pos = rp3[d3[e]] + rk3[e]; m3[pos] = make_int2(s3[e], w3[e] | (t3[e]<<16)); }
  }
}

// single-pass attention on packed bf16 KV; 8-edge ILP, packed int2 edge meta,
// 0.25 scale folded into q.
__global__ void k_attn_fused8(const int* __restrict__ row_ptr, const int2* __restrict__ meta,
                              const unsigned* __restrict__ KVp, const float* __restrict__ Qbuf,
                              const float* __restrict__ EW2, const float* __restrict__ mu,
                              float* __restrict__ Abuf){
  int d = blockIdx.x; int o = threadIdx.x;
  int r0 = row_ptr[d], r1 = row_ptr[d+1];
  __shared__ float q[HH];
  q[o] = Qbuf[(size_t)d*HH+o]*0.25f;
  __syncthreads();
  int h = o >> 4;
  float qo = q[o];
  float dn0=0.f, dn1=0.f, dn2=0.f, dn3=0.f;
  float ac0=0.f, ac1=0.f, ac2=0.f, ac3=0.f;
  int r = r0;
  for(; r+7 < r1; r += 8){
    int2 m[8]; unsigned u[8]; float e[8]; float p[8];
    #pragma unroll
    for(int j=0;j<8;j++) m[j] = meta[r+j];
    #pragma unroll
    for(int j=0;j<8;j++) u[j] = KVp[(size_t)m[j].x*HH + o];
    #pragma unroll
    for(int j=0;j<8;j++) e[j] = EW2[(m[j].y & 0xffff)*HH + o];
    #pragma unroll
    for(int j=0;j<8;j++) p[j] = qo*(__uint_as_float(u[j]<<16) + e[j]);
    #pragma unroll
    for(int j=0;j<8;j++) p[j] += __shfl_xor(p[j], 1, 64);
    #pragma unroll
    for(int j=0;j<8;j++) p[j] += __shfl_xor(p[j], 2, 64);
    #pragma unroll
    for(int j=0;j<8;j++) p[j] += __shfl_xor(p[j], 4, 64);
    #pragma unroll
    for(int j=0;j<8;j++) p[j] += __shfl_xor(p[j], 8, 64);
    float ex[8];
    #pragma unroll
    for(int j=0;j<8;j++) ex[j] = __expf(p[j]*mu[(m[j].y>>16)*NH+h]);
    dn0 += ex[0]+ex[4]; dn1 += ex[1]+ex[5]; dn2 += ex[2]+ex[6]; dn3 += ex[3]+ex[7];
    ac0 += ex[0]*__uint_as_float(u[0]&0xffff0000u) + ex[4]*__uint_as_float(u[4]&0xffff0000u);
    ac1 += ex[1]*__uint_as_float(u[1]&0xffff0000u) + ex[5]*__uint_as_float(u[5]&0xffff0000u);
    ac2 += ex[2]*__uint_as_float(u[2]&0xffff0000u) + ex[6]*__uint_as_float(u[6]&0xffff0000u);
    ac3 += ex[3]*__uint_as_float(u[3]&0xffff0000u) + ex[7]*__uint_as_float(u[7]&0xffff0000u);
  }
  for(; r+3 < r1; r += 4){
    int2 m[4]; unsigned u[4]; float e[4]; float p[4];
    #pragma unroll
    for(int j=0;j<4;j++) m[j] = meta[r+j];
    #pragma unroll
    for(int j=0;j<4;j++) u[j] = KVp[(size_t)m[j].x*HH + o];
    #pragma unroll
    for(int j=0;j<4;j++) e[j] = EW2[(m[j].y & 0xffff)*HH + o];
    #pragma unroll
    for(int j=0;j<4;j++) p[j] = qo*(__uint_as_float(u[j]<<16) + e[j]);
    #pragma unroll
    for(int j=0;j<4;j++) p[j] += __shfl_xor(p[j], 1, 64);
    #pragma unroll
    for(int j=0;j<4;j++) p[j] += __shfl_xor(p[j], 2, 64);
    #pragma unroll
    for(int j=0;j<4;j++) p[j] += __shfl_xor(p[j], 4, 64);
    #pragma unroll
    for(int j=0;j<4;j++) p[j] += __shfl_xor(p[j], 8, 64);
    float ex[4];
    #pragma unroll
    for(int j=0;j<4;j++) ex[j] = __expf(p[j]*mu[(m[j].y>>16)*NH+h]);
    dn0 += ex[0]; dn1 += ex[1]; dn2 += ex[2]; dn3 += ex[3];
    ac0 += ex[0]*__uint_as_float(u[0]&0xffff0000u);
    ac1 += ex[1]*__uint_as_float(u[1]&0xffff0000u);
    ac2 += ex[2]*__uint_as_float(u[2]&0xffff0000u);
    ac3 += ex[3]*__uint_as_float(u[3]&0xffff0000u);
  }
  for(; r < r1; r++){
    int2 m = meta[r];
    unsigned u = KVp[(size_t)m.x*HH + o];
    float p = qo*(__uint_as_float(u<<16) + EW2[(m.y & 0xffff)*HH + o]);
    p += __shfl_xor(p, 1, 64);
    p += __shfl_xor(p, 2, 64);
    p += __shfl_xor(p, 4, 64);
    p += __shfl_xor(p, 8, 64);
    float ex = __expf(p*mu[(m.y>>16)*NH+h]);
    dn0 += ex; ac0 += ex*__uint_as_float(u&0xffff0000u);
  }
  float dd = (dn0+dn1)+(dn2+dn3), acc = (ac0+ac1)+(ac2+ac3);
  Abuf[(size_t)d*HH + o] = acc / fmaxf(dd, 1e-9f);
}

// ---------------- stage D: token pooling (post-attention) ----------------
__global__ void k_tokexp(const int* tokid, float* abuf, const unsigned* amax, float* aden, float* cnt){
  int t = blockIdx.x*blockDim.x + threadIdx.x;
  if(t >= TT) return;
  int c = tokid[t];
  float ex = __expf(abuf[t]-fdec(amax[c]));
  abuf[t] = ex;
  atomicAdd(&aden[c], ex);
  atomicAdd(&cnt[c], 1.f);
}

__global__ void k_tokagg(const int* tokid, const float* abuf, const float* aden,
                         const float* h2f, float* hist2){
  int t = blockIdx.x; int o = threadIdx.x;
  int c = tokid[t];
  float w = abuf[t]/fmaxf(aden[c],1e-9f);
  int b = t % BB, l = t / BB;
  atomicAdd(&hist2[c*HH+o], w*h2f[(b*LL+l)*HH+o]);
}

// ---------------- parent pooling ----------------
__global__ void k_peagg(const int* pe_p, const int* pe_c, const float* cef, float* psum, float* pcnt){
  int i = blockIdx.x; int o = threadIdx.x;
  int p = pe_p[i], c = pe_c[i];
  atomicAdd(&psum[p*HH+o], cef[c*HH+o]);
  if(o==0) atomicAdd(&pcnt[p], 1.f);
}

__global__ void k_parent(const float* psum, const float* pcnt, float* out){
  int i = blockIdx.x; int o = threadIdx.x;
  out[i*HH+o] = psum[i*HH+o]/fmaxf(pcnt[i],1.f);
}

extern "C" void kernel_launch(void* const* d_in, const int* in_sizes, int n_in,
                              void* d_out, int out_size, void* d_ws, size_t ws_size,
                              hipStream_t stream){
  const int* seq     = (const int*)d_in[0];
  const int* seq_nt  = (const int*)d_in[1];
  const int* dur     = (const int*)d_in[2];
  const int* stime   = (const int*)d_in[3];
  const int* etime   = (const int*)d_in[4];
  const int* g1_nid  = (const int*)d_in[5];
  const int* g1_nt   = (const int*)d_in[6];
  const int* g1_esrc = (const int*)d_in[7];
  const int* g1_edst = (const int*)d_in[8];
  const int* g1_ety  = (const int*)d_in[9];
  const int* g1_ew   = (const int*)d_in[10];
  const int* g2_sel  = (const int*)d_in[11];
  const int* g2_esrc = (const int*)d_in[12];
  const int* g2_edst = (const int*)d_in[13];
  const int* g2_ety  = (const int*)d_in[14];
  const int* g2_ew   = (const int*)d_in[15];
  const int* tok_sel = (const int*)d_in[16];
  const int* g4_esrc = (const int*)d_in[17];
  const int* g4_edst = (const int*)d_in[18];
  const int* g4_ety  = (const int*)d_in[19];
  const int* g4_ew   = (const int*)d_in[20];
  const int* pe_p    = (const int*)d_in[21];
  const int* pe_c    = (const int*)d_in[22];
  const float* emb     = (const float*)d_in[23];
  const float* hist_emb= (const float*)d_in[24];
  const float* edge_emb= (const float*)d_in[25];
  const float* dia_w   = (const float*)d_in[26];
  const float* dia_b   = (const float*)d_in[27];
  const float* t2v_w   = (const float*)d_in[28];
  const float* t2v_b   = (const float*)d_in[29];
  const float* exp_W   = (const float*)d_in[30];
  const float* exp_b   = (const float*)d_in[31];
  const float* l1Wi    = (const float*)d_in[32];
  const float* l1Wh    = (const float*)d_in[33];
  const float* l1b     = (const float*)d_in[34];
  const float* l2Wi    = (const float*)d_in[35];
  const float* l2Wh    = (const float*)d_in[36];
  const float* l2b     = (const float*)d_in[37];
  const float* convK   = (const float*)d_in[38];
  const float* convQ   = (const float*)d_in[39];
  const float* convV   = (const float*)d_in[40];
  const float* convO   = (const float*)d_in[41];
  const float* convE   = (const float*)d_in[42];
  const float* convMu  = (const float*)d_in[43];
  const float* ipW     = (const float*)d_in[44];
  const float* iaW     = (const float*)d_in[45];
  const float* skip    = (const float*)d_in[46];
  float* outp = (float*)d_out;

  // workspace arena
  char* wsp = (char*)d_ws;
  size_t off = 0;
  auto A = [&](size_t nbytes)->char*{ char* p = wsp+off; off += (nbytes+255)&~(size_t)255; return p; };
  float*    srcbuf = (float*)   A((size_t)N1SN*HH*4);
  unsigned* KVp    = (unsigned*)A((size_t)N1SN*HH*4);    // packed bf16 [V|K]
  float*    Qbuf   = (float*)   A((size_t)N1DN*HH*4);
  float*    Abuf   = (float*)   A((size_t)N1DN*HH*4);
  float*    xbuf   = (float*)   A((size_t)TT*HH*4);
  float*    gpre   = (float*)   A((size_t)TT*512*4);
  float*    h1     = (float*)   A((size_t)TT*HH*4);
  float*    dst2   = (float*)   A((size_t)TT*HH*4);
  float*    xg     = (float*)   A((size_t)N1DN*HH*4);
  float*    x2     = (float*)   A((size_t)TT*HH*4);
  float*    h2f    = (float*)   A((size_t)TT*HH*4);
  float*    hist2  = (float*)   A((size_t)CHILDN*HH*4);
  float*    cnt    = (float*)   A((size_t)CHILDN*4);
  float*    abuf   = (float*)   A((size_t)TT*4);
  unsigned* amax   = (unsigned*)A((size_t)CHILDN*4);
  float*    aden   = (float*)   A((size_t)CHILDN*4);
  float*    x3     = (float*)   A((size_t)N1DN*HH*4);
  float*    cef    = (float*)   A((size_t)N4DN*HH*4);
  float*    psum   = (float*)   A((size_t)PARENTN*HH*4);
  float*    pcnt   = (float*)   A((size_t)PARENTN*4);
  float*    sdia   = (float*)   A((size_t)CHILDN*64*4);  // sin(dia_w+dia_b) cols 64..127
  int*      tokid  = (int*)     A((size_t)TT*4);
  int*      toknt  = (int*)     A((size_t)TT*4);
  int*      gnid2  = (int*)     A((size_t)N2N*4);
  int*      idxS1  = (int*)     A((size_t)NTY*N1SN*4);
  int*      idxS2  = (int*)     A((size_t)NTY*N1DN*4);
  int*      idxS3  = (int*)     A((size_t)NTY*N2N*4);
  int*      idxS4  = (int*)     A((size_t)NTY*TT*4);
  int*      idxS5  = (int*)     A((size_t)NTY*N4DN*4);
  int*      cntall = (int*)     A((size_t)5*NTY*4);
  int*      tdesc  = (int*)     A((size_t)3*TDSTRIDE*4);
  int*      tcnt   = (int*)     A((size_t)8*4);
  float*    EW2all = (float*)   A((size_t)4*50*HH*4);
  short*    Wsw    = (short*)   A((size_t)64*16384*2);   // bf16-swizzled conv weights
  short*    WswI   = (short*)   A((size_t)4*16384*2);    // bf16-swizzled ipW
  int*      g1row  = (int*)     A((size_t)(N1DN+1)*4);
  int2*     g1meta = (int2*)    A((size_t)E1N*8);
  int*      g1rank = (int*)     A((size_t)E1N*4);
  int*      g2row  = (int*)     A((size_t)(TT+1)*4);
  int2*     g2meta = (int2*)    A((size_t)E2N*8);
  int*      g2rank = (int*)     A((size_t)E2N*4);
  int*      g4row  = (int*)     A((size_t)(N4DN+1)*4);
  int2*     g4meta = (int2*)    A((size_t)E4N*8);
  int*      g4rank = (int*)     A((size_t)E4N*4);
  int*      icnt1  = (int*)     A((size_t)(N1DN+1)*4);
  int*      icnt2  = (int*)     A((size_t)(TT+1)*4);
  int*      icnt3  = (int*)     A((size_t)(N4DN+1)*4);
  if(off > ws_size) return;  // insufficient scratch: output stays zero

  auto run_conv = [&](int cfg, int gkvq, int gq,
                      const float* src_X, const int* src_nid, const int* srcmap,
                      const int* idx_src, int* cnt_src, int stride_src,
                      const float* q_X, const int* q_map,
                      const float* resid_X, const int* r_map, int ndst,
                      const int* idx_dst, int* cnt_dst, int stride_dst,
                      const int* rowp, const int2* meta,
                      int layer, float* outbuf, float* out2, int relu){
    const bfrag* WB = (const bfrag*)Wsw;
    const bfrag* WK = WB + (size_t)( 0 + layer*4)*2048;
    const bfrag* WV = WB + (size_t)(16 + layer*4)*2048;
    const bfrag* WQ = WB + (size_t)(32 + layer*4)*2048;
    const bfrag* WO = WB + (size_t)(48 + layer*4)*2048;
    const float* MU  = convMu + (size_t)layer*NRL*NH;
    const float* EW2 = EW2all + (size_t)layer*50*HH;
    const int* td = tdesc + (size_t)cfg*TDSTRIDE;
    const int* tc = tcnt + cfg*2;
    k_gemm_kvq<<<gkvq, 256, 0, stream>>>(td, tc, src_X, src_nid, srcmap, sdia,
                                         idx_src, cnt_src, stride_src, WK, WV, KVp,
                                         q_X, q_map, idx_dst, cnt_dst, stride_dst, WQ, Qbuf);
    k_attn_fused8<<<ndst, HH, 0, stream>>>(rowp, meta, KVp, Qbuf, EW2, MU, Abuf);
    k_gemm_t5<<<gq, 256, 0, stream>>>(td, tc, Abuf, idx_dst, cnt_dst, stride_dst, WO,
                                      resid_X, r_map, outbuf, out2, relu);
  };

  // ---- upfront: merged init, merged scatters+hists, tiles, scan, fill ----
  k_init<<<(CHILDN*HH+255)/256, 256, 0, stream>>>(hist2, cnt, amax, aden, psum, pcnt, cntall,
                                                  icnt1, icnt2, icnt3,
                                                  dia_w, dia_b, sdia,
                                                  convK, convV, convQ, convO, Wsw,
                                                  ipW, WswI,
                                                  edge_emb, convE, EW2all);
  {
    const int B1 = (N1SN+255)/256, B2 = (TT+255)/256, B3 = (N2N+255)/256;
    const int BE1 = (E1N+255)/256, BE2 = (E2N+255)/256, BE3 = (E4N+255)/256;
    k_scatall<<<B1+B2+B3+BE1+BE2+BE3, 256, 0, stream>>>(g1_nt, seq, seq_nt, g2_sel, g1_nid,
                                            tokid, toknt, gnid2, cntall,
                                            idxS1, idxS2, idxS5, idxS4, idxS3,
                                            g1_edst, icnt1, g1rank,
                                            g2_edst, icnt2, g2rank,
                                            g4_edst, icnt3, g4rank);
  }
  k_mktiles<<<1, 256, 0, stream>>>(cntall, tdesc, tcnt);
  k_scan3<<<3, 1024, 0, stream>>>(icnt1, N1DN, g1row,
                                  icnt2, TT,   g2row,
                                  icnt3, N4DN, g4row);
  {
    const int BE1 = (E1N+255)/256, BE2 = (E2N+255)/256, BE3 = (E4N+255)/256;
    k_fillperm3<<<BE1+BE2+BE3, 256, 0, stream>>>(g1_edst, g1_esrc, g1_ew, g1_ety, g1row, g1rank, g1meta,
                                                 g2_edst, g2_esrc, g2_ew, g2_ety, g2row, g2rank, g2meta,
                                                 g4_edst, g4_esrc, g4_ew, g4_ety, g4row, g4rank, g4meta);
  }

  // ---- stage A: features + LSTM1 (fused scan) ----
  k_featx2<<<TT/32, 512, 0, stream>>>(seq, dur, stime, etime, emb, dia_w, dia_b, t2v_w, t2v_b, exp_W, exp_b, xbuf);
  k_xwi2<<<(TT+15)/16, 256, 0, stream>>>(xbuf, l1Wi, l1b, gpre, TT, 0);
  k_lstm_fused<<<BB, 512, 0, stream>>>(gpre, l1Wh, h1, (float*)nullptr);

  // grid bounds (true tile counts are device-side; these are safe upper bounds)
  const int GKVQ_A = (N1SN+N1DN)/32 + 8;   // conv1 / conv3
  const int GKVQ_B = (N2N+TT)/32 + 8;      // conv2
  const int GKVQ_C = (N1DN+N4DN)/32 + 8;   // conv4
  const int GQ_A   = (N1DN+31)/32 + 4;
  const int GQ_B   = (TT+31)/32 + 4;
  const int GQ_C   = (N4DN+31)/32 + 4;

  // ---- conv1 on g1 (src/dst features gathered from emb via g1_nid in the gemms) ----
  run_conv(0, GKVQ_A, GQ_A,
           emb, g1_nid, g1_nid, idxS1, cntall+0*NTY, N1SN,
           emb, g1_nid,
           emb, g1_nid, N1DN, idxS2, cntall+1*NTY, N1DN,
           g1row, g1meta, 0, xg, (float*)nullptr, 1);

  // ---- conv2 on g2 (src features gathered from xg via g2_sel in the gemm) ----
  k_dst2<<<TT, HH, 0, stream>>>(tok_sel, xg, h1, dst2);
  run_conv(1, GKVQ_B, GQ_B,
           xg, gnid2, g2_sel, idxS3, cntall+2*NTY, N2N,
           dst2, (const int*)nullptr,
           dst2, (const int*)nullptr, TT, idxS4, cntall+3*NTY, TT,
           g2row, g2meta, 1, x2, (float*)nullptr, 1);

  // ---- LSTM2 (h2 is output 0); x2 read directly with permuted layout ----
  k_xwi2<<<(TT+15)/16, 256, 0, stream>>>(x2, l2Wi, l2b, gpre, TT, 1);
  k_lstm_fused<<<BB, 512, 0, stream>>>(gpre, l2Wh, h2f, outp);

  // ---- stage D: token attention pooling -> hist2 (MFMA tokatt; histfix fused in k_x0) ----
  k_tokatt2<<<GQ_B, 256, 0, stream>>>(tdesc + (size_t)1*TDSTRIDE, tcnt + 2,
                                      h2f, idxS4, cntall+3*NTY,
                                      (const bfrag*)WswI, iaW, tokid, abuf, amax);
  k_tokexp<<<(TT+255)/256, 256, 0, stream>>>(tokid, abuf, amax, aden, cnt);
  k_tokagg<<<TT, HH, 0, stream>>>(tokid, abuf, aden, h2f, hist2);

  // ---- conv3 on g1 with skip-mixed input (g1 CSR + scatters + tiles reused) ----
  k_x0<<<N1SN, HH, 0, stream>>>(g1_nid, g1_nt, emb, hist2, cnt, hist_emb, skip, srcbuf);
  run_conv(0, GKVQ_A, GQ_A,
           srcbuf, g1_nid, (const int*)nullptr, idxS1, cntall+0*NTY, N1SN,
           srcbuf, (const int*)nullptr,
           srcbuf, (const int*)nullptr, N1DN, idxS2, cntall+1*NTY, N1DN,
           g1row, g1meta, 2, x3, (float*)nullptr, 1);

  // ---- conv4 on g4 (child_embed = output 1, no relu) ----
  run_conv(2, GKVQ_C, GQ_C,
           x3, g1_nid, (const int*)nullptr, idxS2, cntall+1*NTY, N1DN,
           x3, (const int*)nullptr,
           x3, (const int*)nullptr, N4DN, idxS5, cntall+4*NTY, N4DN,
           g4row, g4meta, 3, cef, outp + (size_t)TT*HH, 0);

  // ---- parent pooling (output 2) ----
  k_peagg<<<EC2PN, HH, 0, stream>>>(pe_p, pe_c, cef, psum, pcnt);
  k_parent<<<PARENTN, HH, 0, stream>>>(psum, pcnt, outp + (size_t)TT*HH + (size_t)N4DN*HH);
}

// Round 12
// 672.880 us; speedup vs baseline: 1.1863x; 1.0089x over previous
//
#include <hip/hip_runtime.h>
#include <math.h>

#define BB 256
#define LL 20
#define HH 128
#define NH 8
#define D2C 64
#define NTY 4
#define NRL 4
#define CHILDN 30001
#define PARENTN 500
#define N1SN 50000
#define N1DN 20000
#define E1N 300000
#define N2N 20000
#define E2N 200000
#define TT (BB*LL)
#define N4DN 5000
#define E4N 150000
#define EC2PN 8000
#define TDSTRIDE 2304

typedef __attribute__((ext_vector_type(8))) short bfrag;   // 8 bf16 in 4 VGPRs
typedef __attribute__((ext_vector_type(4))) float ffrag;   // MFMA accumulator

__device__ __forceinline__ unsigned fenc(float f){ unsigned u=__float_as_uint(f); return (u&0x80000000u)? ~u : (u|0x80000000u); }
__device__ __forceinline__ float fdec(unsigned u){ return (u&0x80000000u)? __uint_as_float(u^0x80000000u) : __uint_as_float(~u); }
__device__ __forceinline__ float sigfast(float x){ return 1.f/(1.f+__expf(-x)); }
__device__ __forceinline__ float tanhfast(float x){ float e = __expf(-2.f*x); return (1.f-e)/(1.f+e); }
__device__ __forceinline__ short f2bf(float f){
  unsigned u = __float_as_uint(f);
  unsigned r = u + 0x7FFFu + ((u>>16)&1u);   // round-to-nearest-even
  return (short)(r>>16);
}

// ---------------- upfront init: zero/poison buffers + sin table + weight prepack
// (conv K/V/Q/O + ipW) + edge tables, all folded into one grid ----------------
__global__ void k_init(float* hist2, float* cnt, unsigned* amax, float* aden,
                       float* psum, float* pcnt, int* cntall,
                       int* icnt1, int* icnt2, int* icnt3,
                       const float* __restrict__ dia_w, const float* __restrict__ dia_b,
                       float* __restrict__ sdia,
                       const float* convK, const float* convV, const float* convQ,
                       const float* convO, short* Wsw,
                       const float* ipW, short* WswI,
                       const float* edge_emb, const float* convE, float* EW2all){
  int i = blockIdx.x*256 + threadIdx.x;
  if(i < CHILDN*HH) hist2[i] = 0.f;
  if(i < CHILDN){ cnt[i] = 0.f; aden[i] = 0.f; amax[i] = 0x007FFFFFu; }
  if(i < PARENTN*HH) psum[i] = 0.f;
  if(i < PARENTN) pcnt[i] = 0.f;
  if(i < 5*NTY) cntall[i] = 0;
  if(i < N1DN) icnt1[i] = 0;
  if(i < TT)   icnt2[i] = 0;
  if(i < N4DN) icnt3[i] = 0;
  if(i < CHILDN*64){
    int c = i >> 6, k = (i & 63) + 64;
    sdia[i] = __sinf(dia_w[(size_t)c*HH+k] + dia_b[(size_t)c*HH+k]);
  }
  if(i < 64*16384){
    int m = i >> 14, im = i & 16383;
    int fam = m >> 4, lt = m & 15;
    const float* src = (fam==0?convK:fam==1?convV:fam==2?convQ:convO) + (size_t)lt*HH*HH;
    int j = im & 7, lane = (im>>3)&63, kc = (im>>9)&3, nt = im>>11;
    int k = kc*32 + (lane>>4)*8 + j;
    int n = nt*16 + (lane&15);
    Wsw[(size_t)m*16384 + im] = f2bf(src[k*HH+n]);
  }
  if(i < 4*16384){
    int m = i >> 14, im = i & 16383;
    const float* src = ipW + (size_t)m*HH*HH;
    int j = im & 7, lane = (im>>3)&63, kc = (im>>9)&3, nt = im>>11;
    int k = kc*32 + (lane>>4)*8 + j;
    int n = nt*16 + (lane&15);
    WswI[(size_t)m*16384 + im] = f2bf(src[k*HH+n]);
  }
  if(i < 4*50*HH){
    int layer = i/(50*HH), rr = (i/HH)%50, o = i%HH;
    const float* EWp = convE + (size_t)layer*32*HH;
    float acc = 0.f;
    for(int j=0;j<32;j++) acc += edge_emb[rr*32+j]*EWp[j*HH+o];
    EW2all[i] = acc;
  }
}

// ---------------- stage1: featx2 (blocks [0,160)) + scatters + edge-rank hists
// (block-range dispatch, 512 threads) ----------------
#define S1_BF   (TT/32)             // 160 featx blocks
#define S1_B1   ((N1SN+511)/512)    // 98
#define S1_B2   ((TT+511)/512)      // 10
#define S1_B3   ((N2N+511)/512)     // 40
#define S1_BE1  ((E1N+511)/512)     // 586
#define S1_BE2  ((E2N+511)/512)     // 391
#define S1_BE3  ((E4N+511)/512)     // 293
__global__ __launch_bounds__(512) void k_stage1(
    const int* __restrict__ seq, const int* __restrict__ dur,
    const int* __restrict__ stime, const int* __restrict__ etime,
    const float* __restrict__ emb, const float* __restrict__ dia_w, const float* __restrict__ dia_b,
    const float* __restrict__ t2v_w, const float* __restrict__ t2v_b,
    const float* __restrict__ exp_W, const float* __restrict__ exp_b, float* __restrict__ xout,
    const int* __restrict__ g1_nt, const int* __restrict__ seq_nt, const int* __restrict__ g2_sel,
    const int* __restrict__ g1_nid,
    int* __restrict__ tokid, int* __restrict__ toknt, int* __restrict__ gnid2,
    int* __restrict__ cntall,
    int* __restrict__ idxS1, int* __restrict__ idxS2, int* __restrict__ idxS5,
    int* __restrict__ idxS4, int* __restrict__ idxS3,
    const int* __restrict__ e1d, int* __restrict__ icnt1, int* __restrict__ rank1,
    const int* __restrict__ e2d, int* __restrict__ icnt2, int* __restrict__ rank2,
    const int* __restrict__ e3d, int* __restrict__ icnt3, int* __restrict__ rank3){
  int bxx = blockIdx.x;
  if(bxx < S1_BF){
    // ---- featx2 body ----
    __shared__ float feat[32*273];
    int base = bxx*32;
    int j = threadIdx.x >> 4;
    int p = threadIdx.x & 15;
    int row = base + j;
    int node = seq[row];
    float ts = (float)stime[row], te = (float)etime[row];
    const float* ep = emb + (size_t)node*HH;
    float* fr = feat + j*273;
    int o0 = p*8;
    #pragma unroll
    for(int ii=0; ii<8; ii+=4){
      int o = o0 + ii;
      float4 e = *(const float4*)(ep + o);
      float4 st = e, et = e;
      if(o >= D2C){
        float4 w = *(const float4*)(dia_w + (size_t)node*HH + o);
        float4 b = *(const float4*)(dia_b + (size_t)node*HH + o);
        st.x = e.x*__sinf(w.x*ts+b.x); st.y = e.y*__sinf(w.y*ts+b.y);
        st.z = e.z*__sinf(w.z*ts+b.z); st.w = e.w*__sinf(w.w*ts+b.w);
        et.x = e.x*__sinf(w.x*te+b.x); et.y = e.y*__sinf(w.y*te+b.y);
        et.z = e.z*__sinf(w.z*te+b.z); et.w = e.w*__sinf(w.w*te+b.w);
      }
      fr[o] = st.x; fr[o+1] = st.y; fr[o+2] = st.z; fr[o+3] = st.w;
      fr[128+o] = et.x; fr[128+o+1] = et.y; fr[128+o+2] = et.z; fr[128+o+3] = et.w;
    }
    if(p == 0){
      float td = (float)dur[row];
      #pragma unroll
      for(int i=0;i<16;i++){
        float w = t2v_w[i], b = t2v_b[i];
        fr[256+i] = (i==0) ? (w*td + b) : __sinf(w*td + b);
      }
    }
    __syncthreads();
    int oc = (threadIdx.x & 31)*4;
    int jg = threadIdx.x >> 5;
    const float* f0 = feat + (jg*2)*273;
    const float* f1 = feat + (jg*2+1)*273;
    float4 a0 = {0,0,0,0}, a1 = {0,0,0,0};
    for(int k=0;k<272;k++){
      float4 w = *(const float4*)(exp_W + (size_t)k*HH + oc);
      float x0 = f0[k], x1 = f1[k];
      a0.x += x0*w.x; a0.y += x0*w.y; a0.z += x0*w.z; a0.w += x0*w.w;
      a1.x += x1*w.x; a1.y += x1*w.y; a1.z += x1*w.z; a1.w += x1*w.w;
    }
    float4 bv = *(const float4*)(exp_b + oc);
    a0.x = fmaxf(a0.x+bv.x, 0.f); a0.y = fmaxf(a0.y+bv.y, 0.f);
    a0.z = fmaxf(a0.z+bv.z, 0.f); a0.w = fmaxf(a0.w+bv.w, 0.f);
    a1.x = fmaxf(a1.x+bv.x, 0.f); a1.y = fmaxf(a1.y+bv.y, 0.f);
    a1.z = fmaxf(a1.z+bv.z, 0.f); a1.w = fmaxf(a1.w+bv.w, 0.f);
    *(float4*)(xout + (size_t)(base + jg*2  )*HH + oc) = a0;
    *(float4*)(xout + (size_t)(base + jg*2+1)*HH + oc) = a1;
    return;
  }
  __shared__ int h[3][NTY];
  __shared__ int bs[3][NTY];
  int bx = bxx - S1_BF;
  if(bx < S1_B1){
    int i = bx*512 + threadIdx.x;
    if(threadIdx.x < 3*NTY) (&h[0][0])[threadIdx.x] = 0;
    __syncthreads();
    int t = 0, r1 = 0, r2 = 0, r3 = 0;
    bool a1 = (i < N1SN), a2 = (i < N1DN), a3 = (i < N4DN);
    if(a1){
      t = g1_nt[i];
      r1 = atomicAdd(&h[0][t], 1);
      if(a2) r2 = atomicAdd(&h[1][t], 1);
      if(a3) r3 = atomicAdd(&h[2][t], 1);
    }
    __syncthreads();
    if(threadIdx.x < NTY){
      int ty = threadIdx.x;
      if(h[0][ty] > 0) bs[0][ty] = atomicAdd(&cntall[0*NTY+ty], h[0][ty]);
      if(h[1][ty] > 0) bs[1][ty] = atomicAdd(&cntall[1*NTY+ty], h[1][ty]);
      if(h[2][ty] > 0) bs[2][ty] = atomicAdd(&cntall[4*NTY+ty], h[2][ty]);
    }
    __syncthreads();
    if(a1) idxS1[t*N1SN + bs[0][t] + r1] = i;
    if(a2) idxS2[t*N1DN + bs[1][t] + r2] = i;
    if(a3) idxS5[t*N4DN + bs[2][t] + r3] = i;
  } else if(bx < S1_B1 + S1_B2){
    int i = (bx - S1_B1)*512 + threadIdx.x;
    if(threadIdx.x < NTY) h[0][threadIdx.x] = 0;
    __syncthreads();
    int nt = 0, r = 0;
    bool act = (i < TT);
    if(act){
      int b = i % BB, l = i / BB;
      tokid[i] = seq[b*LL+l];
      nt = seq_nt[b*LL+l];
      toknt[i] = nt;
      r = atomicAdd(&h[0][nt], 1);
    }
    __syncthreads();
    if(threadIdx.x < NTY && h[0][threadIdx.x] > 0)
      bs[0][threadIdx.x] = atomicAdd(&cntall[3*NTY+threadIdx.x], h[0][threadIdx.x]);
    __syncthreads();
    if(act) idxS4[nt*TT + bs[0][nt] + r] = i;
  } else if(bx < S1_B1 + S1_B2 + S1_B3){
    int i = (bx - S1_B1 - S1_B2)*512 + threadIdx.x;
    if(threadIdx.x < NTY) h[0][threadIdx.x] = 0;
    __syncthreads();
    int nt = 0, r = 0;
    bool act = (i < N2N);
    if(act){
      int s = g2_sel[i];
      gnid2[i] = g1_nid[s];
      nt = g1_nt[s];
      r = atomicAdd(&h[0][nt], 1);
    }
    __syncthreads();
    if(threadIdx.x < NTY && h[0][threadIdx.x] > 0)
      bs[0][threadIdx.x] = atomicAdd(&cntall[2*NTY+threadIdx.x], h[0][threadIdx.x]);
    __syncthreads();
    if(act) idxS3[nt*N2N + bs[0][nt] + r] = i;
  } else if(bx < S1_B1 + S1_B2 + S1_B3 + S1_BE1){
    int e = (bx - S1_B1 - S1_B2 - S1_B3)*512 + threadIdx.x;
    if(e < E1N) rank1[e] = atomicAdd(&icnt1[e1d[e]], 1);
  } else if(bx < S1_B1 + S1_B2 + S1_B3 + S1_BE1 + S1_BE2){
    int e = (bx - S1_B1 - S1_B2 - S1_B3 - S1_BE1)*512 + threadIdx.x;
    if(e < E2N) rank2[e] = atomicAdd(&icnt2[e2d[e]], 1);
  } else {
    int e = (bx - S1_B1 - S1_B2 - S1_B3 - S1_BE1 - S1_BE2)*512 + threadIdx.x;
    if(e < E4N) rank3[e] = atomicAdd(&icnt3[e3d[e]], 1);
  }
}

// ---------------- stage2: xwi2 (blocks [0,rows/16)) + scan3 (3 blocks) + mktiles (1 block),
// 256 threads ----------------
__device__ __forceinline__ void scan_one(const int* cnt, int n, int* row_ptr){
  __shared__ int tsum[256];
  int tid = threadIdx.x;
  int per = (n + 255) / 256;
  int start = tid*per; int end = min(start+per, n);
  int s = 0;
  for(int i=start;i<end;i++) s += cnt[i];
  tsum[tid] = s; __syncthreads();
  for(int off=1;off<256;off<<=1){
    int v = (tid>=off) ? tsum[tid-off] : 0;
    __syncthreads();
    tsum[tid] += v;
    __syncthreads();
  }
  int run = (tid==0) ? 0 : tsum[tid-1];
  for(int i=start;i<end;i++){ row_ptr[i]=run; run += cnt[i]; }
  if(end == n) row_ptr[n] = run;
}

__global__ __launch_bounds__(256) void k_stage2(
    const float* x, const float* Wi, const float* bias, float* gpre, int rows, int perm,
    const int* c1, int* r1, const int* c2, int* r2, const int* c3, int* r3,
    const int* __restrict__ cntall, int* __restrict__ tdesc, int* __restrict__ tcnt){
  int nxwi = (rows+15)/16;
  int bxx = blockIdx.x;
  if(bxx < nxwi){
    int base = bxx*16;
    __shared__ float xs[128*17];
    int tid = threadIdx.x;
    #pragma unroll
    for(int s=0;s<8;s++){
      int elem = tid + 256*s;
      int k = elem & 127, j = elem >> 7;
      int r = base + j;
      int src = r;
      if(perm) src = (r % LL)*BB + (r / LL);
      xs[k*17 + j] = (r < rows) ? x[(size_t)src*HH + k] : 0.f;
    }
    __syncthreads();
    int o4 = (tid & 127)*4;
    int ng = tid >> 7;
    float4 a[8];
    #pragma unroll
    for(int j=0;j<8;j++) a[j]=make_float4(0,0,0,0);
    for(int k=0;k<HH;k++){
      float4 w = *(const float4*)(Wi + (size_t)k*512 + o4);
      const float* xr = xs + k*17 + ng*8;
      #pragma unroll
      for(int j=0;j<8;j++){
        float xv = xr[j];
        a[j].x += xv*w.x; a[j].y += xv*w.y; a[j].z += xv*w.z; a[j].w += xv*w.w;
      }
    }
    float4 bv = *(const float4*)(bias + o4);
    #pragma unroll
    for(int j=0;j<8;j++){
      int r = base + ng*8 + j;
      if(r < rows){
        float4 v = a[j];
        v.x += bv.x; v.y += bv.y; v.z += bv.z; v.w += bv.w;
        *(float4*)(gpre + (size_t)r*512 + o4) = v;
      }
    }
    return;
  }
  int bx = bxx - nxwi;
  if(bx == 0){ scan_one(c1, N1DN, r1); }
  else if(bx == 1){ scan_one(c2, TT, r2); }
  else if(bx == 2){ scan_one(c3, N4DN, r3); }
  else {
    // mktiles
    __shared__ int start[3][2][NTY];
    if(threadIdx.x == 0){
      const int srcg[3] = {0,2,1};
      const int dstg[3] = {1,3,4};
      for(int c=0;c<3;c++){
        int acc = 0;
        for(int z=0;z<2;z++){
          int g = (z==0) ? srcg[c] : dstg[c];
          int zacc = 0;
          for(int t=0;t<NTY;t++){
            start[c][z][t] = acc;
            int tiles = (cntall[g*NTY+t]+31)>>5;
            acc += tiles; zacc += tiles;
          }
          tcnt[c*2+z] = zacc;
        }
      }
    }
    __syncthreads();
    const int srcg[3] = {0,2,1};
    const int dstg[3] = {1,3,4};
    for(int c=0;c<3;c++){
      for(int z=0;z<2;z++){
        int g = (z==0) ? srcg[c] : dstg[c];
        for(int t=0;t<NTY;t++){
          int tiles = (cntall[g*NTY+t]+31)>>5;
          for(int i=threadIdx.x; i<tiles; i+=blockDim.x)
            tdesc[c*TDSTRIDE + start[c][z][t] + i] = (int)(((unsigned)z<<31) | ((unsigned)t<<28) | (unsigned)(i<<5));
        }
      }
    }
  }
}

// fused 20-step LSTM (blocks [0,BB)) + rank-based CSR fill (blocks >= BB, 512 thr).
#define LF_BE1 ((E1N+511)/512)
#define LF_BE2 ((E2N+511)/512)
#define LF_BE3 ((E4N+511)/512)
__global__ __launch_bounds__(512, 2) void k_lstm_fused(const float* __restrict__ gpre,
                                                       const float* __restrict__ Wh,
                                                       float* __restrict__ hout,
                                                       float* __restrict__ hout2,
    const int* d1, const int* s1, const int* w1, const int* t1,
    const int* rp1, const int* rk1, int2* m1,
    const int* d2, const int* s2, const int* w2, const int* t2,
    const int* rp2, const int* rk2, int2* m2,
    const int* d3, const int* s3, const int* w3, const int* t3,
    const int* rp3, const int* rk3, int2* m3){
  if(blockIdx.x >= BB){
    int bx = blockIdx.x - BB;
    int tid = threadIdx.x;
    if(bx < LF_BE1){
      int e = bx*512 + tid;
      if(e < E1N){ int pos = rp1[d1[e]] + rk1[e]; m1[pos] = make_int2(s1[e], w1[e] | (t1[e]<<16)); }
    } else if(bx < LF_BE1 + LF_BE2){
      int e = (bx - LF_BE1)*512 + tid;
      if(e < E2N){ int pos = rp2[d2[e]] + rk2[e]; m2[pos] = make_int2(s2[e], w2[e] | (t2[e]<<16)); }
    } else {
      int e = (bx - LF_BE1 - LF_BE2)*512 + tid;
      if(e < E4N){ int pos = rp3[d3[e]] + rk3[e]; m3[pos] = make_int2(s3[e], w3[e] | (t3[e]<<16)); }
    }
    return;
  }
  int b = blockIdx.x;
  int o = threadIdx.x;
  __shared__ float hs[HH];
  __shared__ float act[512];
  float wr[HH];
  #pragma unroll
  for(int h=0;h<HH;h++) wr[h] = Wh[(size_t)h*512 + o];
  float gv[LL];
  const float* gp = gpre + (size_t)b*LL*512 + o;
  #pragma unroll
  for(int l=0;l<LL;l++) gv[l] = gp[(size_t)l*512];
  if(o < HH) hs[o] = 0.f;
  float cc = 0.f;
  int quad = o >> 7;                        // 0=i, 1=f, 2=g, 3=o
  __syncthreads();
  for(int l=0;l<LL;l++){
    float a0=0.f,a1=0.f,a2=0.f,a3=0.f;
    #pragma unroll
    for(int h=0;h<HH;h+=4){
      float4 hv = *(const float4*)&hs[h];
      a0 += hv.x*wr[h];   a1 += hv.y*wr[h+1];
      a2 += hv.z*wr[h+2]; a3 += hv.w*wr[h+3];
    }
    float g = gv[l] + ((a0+a1)+(a2+a3));
    act[o] = (quad==2) ? tanhfast(g) : sigfast(g);
    __syncthreads();
    if(o < HH){
      cc = act[HH+o]*cc + act[o]*act[2*HH+o];
      float hh = act[3*HH+o]*tanhfast(cc);
      hs[o] = hh;
      size_t bi = ((size_t)b*LL + l)*HH + o;
      hout[bi] = hh;
      if(hout2) hout2[bi] = hh;
    }
    __syncthreads();
  }
}

__global__ void k_dst2(const int* tok_sel, const float* xg, const float* h1, float* dst2){
  int t = blockIdx.x; int o = threadIdx.x;
  int b = t % BB, l = t / BB;
  dst2[t*HH+o] = xg[tok_sel[t]*HH+o] + h1[(b*LL+l)*HH+o];
}

// skip-mixed input with histfix fused (cnt==0 -> hist_emb fallback)
__global__ void k_x0(const int* nid, const int* ntype, const float* emb, const float* hist2,
                     const float* cnt, const float* hist_emb, const float* skip, float* srcbuf){
  int i = blockIdx.x; int o = threadIdx.x;
  float a = sigfast(skip[ntype[i]]);
  int nd = nid[i];
  float hv = (cnt[nd] > 0.f) ? hist2[(size_t)nd*HH+o] : hist_emb[(size_t)nd*HH+o];
  srcbuf[i*HH+o] = emb[(size_t)nd*HH+o]*a + hv*(1.f-a);
}

// ---- fused KV (z=0) + Q (z=1) projection via MFMA; compacted 1-D tile list,
// float4 staging, warp-level LN reduce (float4 LDS reads), float4 normalize pass.
__global__ __launch_bounds__(256) void k_gemm_kvq(
    const int* __restrict__ tdesc, const int* __restrict__ tcnt,
    const float* __restrict__ Xs, const int* __restrict__ src_nid, const int* __restrict__ smap,
    const float* __restrict__ sdia,
    const int* __restrict__ idxs, const int* __restrict__ cnts_s, int stride_s,
    const bfrag* __restrict__ WK, const bfrag* __restrict__ WV, unsigned* __restrict__ KVp,
    const float* __restrict__ Xq, const int* __restrict__ qmap,
    const int* __restrict__ idxd, const int* __restrict__ cnts_d, int stride_d,
    const bfrag* __restrict__ WQ, float* __restrict__ Qbuf){
  __shared__ float xs[32*132];
  __shared__ float mean_s[32], inv_s[32];
  __shared__ int sid[32], nid[32], xrow[32];
  int ntk = tcnt[0], ntq = tcnt[1];
  int bid = blockIdx.x;
  if(bid >= ntk + ntq) return;
  unsigned ud = (unsigned)tdesc[bid];
  int isQ = ud >> 31;
  int t = (ud >> 28) & 7;
  int base = ud & 0x0FFFFFFF;
  int tid = threadIdx.x;
  int cnt = isQ ? cnts_d[t] : cnts_s[t];
  if(base >= cnt) return;
  int nn = min(32, cnt - base);
  const float* X = isQ ? Xq : Xs;
  const int* map = isQ ? qmap : smap;
  const int* ids = (isQ ? idxd + (size_t)t*stride_d : idxs + (size_t)t*stride_s) + base;
  if(tid < 32){
    int s_ = (tid < nn) ? ids[tid] : ids[0];
    sid[tid] = s_;
    if(!isQ) nid[tid] = src_nid[s_];
    xrow[tid] = map ? map[s_] : s_;
  }
  __syncthreads();
  // float4 staging: 1024 float4 = 32 rows x 128 cols
  #pragma unroll
  for(int s=0;s<4;s++){
    int e4 = tid + 256*s;
    int j = e4 >> 5, c4 = (e4 & 31)*4;
    *(float4*)&xs[j*132 + c4] = *(const float4*)&X[(size_t)xrow[j]*HH + c4];
  }
  __syncthreads();
  // warp-level LN reduce: 8 lanes per row, float4 LDS reads, shfl_xor over p
  {
    int wid = tid >> 6, lane = tid & 63;
    int row = wid*8 + (lane>>3), p = lane & 7;
    const float* xr = xs + row*132 + p*16;
    float sm=0.f, sq=0.f;
    #pragma unroll
    for(int i=0;i<4;i++){
      float4 v = *(const float4*)(xr + i*4);
      sm += (v.x+v.y)+(v.z+v.w);
      sq += (v.x*v.x+v.y*v.y)+(v.z*v.z+v.w*v.w);
    }
    sm += __shfl_xor(sm, 1, 64); sq += __shfl_xor(sq, 1, 64);
    sm += __shfl_xor(sm, 2, 64); sq += __shfl_xor(sq, 2, 64);
    sm += __shfl_xor(sm, 4, 64); sq += __shfl_xor(sq, 4, 64);
    if(p == 0){
      float mean = sm*(1.f/128.f);
      float var = sq*(1.f/128.f) - mean*mean;
      mean_s[row] = mean;
      inv_s[row] = 1.f/sqrtf(fmaxf(var,0.f)+1e-5f);
    }
  }
  __syncthreads();
  // float4 normalize pass (+ sdia time-mod on cols 64..127 for the KV path)
  #pragma unroll
  for(int s=0;s<4;s++){
    int e4 = tid + 256*s;
    int j = e4 >> 5, c4 = (e4 & 31)*4;
    float* px = &xs[j*132 + c4];
    float4 v = *(float4*)px;
    float mj = mean_s[j], ij = inv_s[j];
    v.x = (v.x-mj)*ij; v.y = (v.y-mj)*ij; v.z = (v.z-mj)*ij; v.w = (v.w-mj)*ij;
    if(!isQ && c4 >= D2C){
      float4 sd = *(const float4*)(sdia + (size_t)nid[j]*64 + (c4 - D2C));
      v.x *= sd.x; v.y *= sd.y; v.z *= sd.z; v.w *= sd.w;
    }
    *(float4*)px = v;
  }
  __syncthreads();
  int lane = tid & 63, w = tid >> 6;
  int mt = w & 1, ng0 = (w>>1)*4;
  int arow = mt*16 + (lane & 15);
  int koff = (lane >> 4)*8;
  int tb = t*2048;
  if(!isQ){
    ffrag aK[4], aV[4];
    #pragma unroll
    for(int i=0;i<4;i++){ aK[i] = (ffrag){0.f,0.f,0.f,0.f}; aV[i] = (ffrag){0.f,0.f,0.f,0.f}; }
    #pragma unroll
    for(int kc=0;kc<4;kc++){
      const float* ap = xs + arow*132 + kc*32 + koff;
      bfrag a;
      #pragma unroll
      for(int j=0;j<8;j++) a[j] = f2bf(ap[j]);
      #pragma unroll
      for(int nt=0;nt<4;nt++){
        int fi = tb + ((ng0+nt)*4 + kc)*64 + lane;
        bfrag bk = WK[fi];
        bfrag bv = WV[fi];
        aK[nt] = __builtin_amdgcn_mfma_f32_16x16x32_bf16(a, bk, aK[nt], 0, 0, 0);
        aV[nt] = __builtin_amdgcn_mfma_f32_16x16x32_bf16(a, bv, aV[nt], 0, 0, 0);
      }
    }
    int col0 = lane & 15;
    int rb = mt*16 + (lane>>4)*4;
    #pragma unroll
    for(int nt=0;nt<4;nt++){
      int col = (ng0+nt)*16 + col0;
      #pragma unroll
      for(int i=0;i<4;i++){
        int n = rb + i;
        if(n < nn){
          unsigned pk = (unsigned short)f2bf(aK[nt][i]);
          unsigned pv = (unsigned short)f2bf(aV[nt][i]);
          KVp[(size_t)sid[n]*HH + col] = (pv<<16) | pk;
        }
      }
    }
  } else {
    ffrag acc[4];
    #pragma unroll
    for(int i=0;i<4;i++) acc[i] = (ffrag){0.f,0.f,0.f,0.f};
    #pragma unroll
    for(int kc=0;kc<4;kc++){
      const float* ap = xs + arow*132 + kc*32 + koff;
      bfrag a;
      #pragma unroll
      for(int j=0;j<8;j++) a[j] = f2bf(ap[j]);
      #pragma unroll
      for(int nt=0;nt<4;nt++){
        bfrag b = WQ[tb + ((ng0+nt)*4 + kc)*64 + lane];
        acc[nt] = __builtin_amdgcn_mfma_f32_16x16x32_bf16(a, b, acc[nt], 0, 0, 0);
      }
    }
    int col0 = lane & 15;
    int rb = mt*16 + (lane>>4)*4;
    #pragma unroll
    for(int nt=0;nt<4;nt++){
      int col = (ng0+nt)*16 + col0;
      #pragma unroll
      for(int i=0;i<4;i++){
        int n = rb + i;
        if(n < nn) Qbuf[(size_t)sid[n]*HH + col] = acc[nt][i];
      }
    }
  }
}

// ---- O projection via MFMA (resid+relu, optional copy); compacted dst tile list.
__global__ __launch_bounds__(256) void k_gemm_t5(
    const int* __restrict__ tdesc, const int* __restrict__ tcnt,
    const float* X, const int* idxb, const int* cnts, int stride,
    const bfrag* W, const float* resid, const int* rmap, float* Y, float* Y2,
    int relu){
  __shared__ float xs[32*132];
  __shared__ int sid[32], rrow[32];
  int ntk = tcnt[0], ntq = tcnt[1];
  if(blockIdx.x >= ntq) return;
  unsigned ud = (unsigned)tdesc[ntk + blockIdx.x];
  int t = (ud >> 28) & 7;
  int base = ud & 0x0FFFFFFF;
  int cnt = cnts[t];
  if(base >= cnt) return;
  int nn = min(32, cnt - base);
  const int* ids = idxb + (size_t)t*stride + base;
  int tid = threadIdx.x;
  if(tid < 32){
    int s_ = (tid < nn) ? ids[tid] : ids[0];
    sid[tid] = s_;
    rrow[tid] = rmap ? rmap[s_] : s_;
  }
  __syncthreads();
  #pragma unroll
  for(int s=0;s<4;s++){
    int e4 = tid + 256*s;
    int j = e4 >> 5, c4 = (e4 & 31)*4;
    *(float4*)&xs[j*132 + c4] = *(const float4*)&X[(size_t)sid[j]*HH + c4];
  }
  __syncthreads();
  int lane = tid & 63, w = tid >> 6;
  int mt = w & 1, ng0 = (w>>1)*4;
  int arow = mt*16 + (lane & 15);
  int koff = (lane >> 4)*8;
  int tb = t*2048;
  ffrag acc[4];
  #pragma unroll
  for(int i=0;i<4;i++) acc[i] = (ffrag){0.f,0.f,0.f,0.f};
  #pragma unroll
  for(int kc=0;kc<4;kc++){
    const float* ap = xs + arow*132 + kc*32 + koff;
    bfrag a;
    #pragma unroll
    for(int j=0;j<8;j++) a[j] = f2bf(ap[j]);
    #pragma unroll
    for(int nt=0;nt<4;nt++){
      bfrag b = W[tb + ((ng0+nt)*4 + kc)*64 + lane];
      acc[nt] = __builtin_amdgcn_mfma_f32_16x16x32_bf16(a, b, acc[nt], 0, 0, 0);
    }
  }
  int col0 = lane & 15;
  int rb = mt*16 + (lane>>4)*4;
  #pragma unroll
  for(int nt=0;nt<4;nt++){
    int col = (ng0+nt)*16 + col0;
    #pragma unroll
    for(int i=0;i<4;i++){
      int n = rb + i;
      if(n < nn){
        size_t r = (size_t)sid[n]*HH + col;
        float v = acc[nt][i];
        if(resid){
          v += resid[(size_t)rrow[n]*HH + col];
          if(relu) v = fmaxf(v, 0.f);
        }
        Y[r] = v;
        if(Y2) Y2[r] = v;
      }
    }
  }
}

// ---- token attention pooling via MFMA: 32-token tiles from cfg1 dst list.
__global__ __launch_bounds__(256) void k_tokatt2(
    const int* __restrict__ tdesc, const int* __restrict__ tcnt,
    const float* __restrict__ h2f, const int* __restrict__ idxd, const int* __restrict__ cnts_d,
    const bfrag* __restrict__ WI, const float* __restrict__ iaW,
    const int* __restrict__ tokid, float* __restrict__ abuf, unsigned* __restrict__ amax){
  __shared__ float xs[32*132];
  __shared__ float red[32];
  __shared__ int sid[32];
  int ntk = tcnt[0], ntq = tcnt[1];
  if(blockIdx.x >= ntq) return;
  unsigned ud = (unsigned)tdesc[ntk + blockIdx.x];
  int t = (ud >> 28) & 7;
  int base = ud & 0x0FFFFFFF;
  int cnt = cnts_d[t];
  if(base >= cnt) return;
  int nn = min(32, cnt - base);
  const int* ids = idxd + (size_t)t*TT + base;
  int tid = threadIdx.x;
  if(tid < 32){
    sid[tid] = (tid < nn) ? ids[tid] : ids[0];
    red[tid] = 0.f;
  }
  __syncthreads();
  #pragma unroll
  for(int s=0;s<4;s++){
    int e4 = tid + 256*s;
    int j = e4 >> 5, c4 = (e4 & 31)*4;
    int tok = sid[j];
    int b = tok % BB, l = tok / BB;
    *(float4*)&xs[j*132 + c4] = *(const float4*)&h2f[((size_t)(b*LL+l))*HH + c4];
  }
  __syncthreads();
  int lane = tid & 63, w = tid >> 6;
  int mt = w & 1, ng0 = (w>>1)*4;
  int arow = mt*16 + (lane & 15);
  int koff = (lane >> 4)*8;
  int tb = t*2048;
  ffrag acc[4];
  #pragma unroll
  for(int i=0;i<4;i++) acc[i] = (ffrag){0.f,0.f,0.f,0.f};
  #pragma unroll
  for(int kc=0;kc<4;kc++){
    const float* ap = xs + arow*132 + kc*32 + koff;
    bfrag a;
    #pragma unroll
    for(int j=0;j<8;j++) a[j] = f2bf(ap[j]);
    #pragma unroll
    for(int nt=0;nt<4;nt++){
      bfrag b = WI[tb + ((ng0+nt)*4 + kc)*64 + lane];
      acc[nt] = __builtin_amdgcn_mfma_f32_16x16x32_bf16(a, b, acc[nt], 0, 0, 0);
    }
  }
  int col0 = lane & 15;
  int rb = mt*16 + (lane>>4)*4;
  float rsum[4] = {0.f, 0.f, 0.f, 0.f};
  #pragma unroll
  for(int nt=0;nt<4;nt++){
    int col = (ng0+nt)*16 + col0;
    float wia = iaW[t*HH + col];
    #pragma unroll
    for(int i=0;i<4;i++) rsum[i] += tanhfast(acc[nt][i]) * wia;
  }
  #pragma unroll
  for(int i=0;i<4;i++){
    rsum[i] += __shfl_xor(rsum[i], 1, 64);
    rsum[i] += __shfl_xor(rsum[i], 2, 64);
    rsum[i] += __shfl_xor(rsum[i], 4, 64);
    rsum[i] += __shfl_xor(rsum[i], 8, 64);
  }
  if(col0 == 0){
    #pragma unroll
    for(int i=0;i<4;i++) atomicAdd(&red[rb+i], rsum[i]);
  }
  __syncthreads();
  if(tid < nn){
    int tok = sid[tid];
    float a = red[tid];
    abuf[tok] = a;
    atomicMax(&amax[tokid[tok]], fenc(a));
  }
}

// single-pass attention on packed bf16 KV; 8-edge ILP, packed int2 edge meta,
// 0.25 scale folded into q.
__global__ void k_attn_fused8(const int* __restrict__ row_ptr, const int2* __restrict__ meta,
                              const unsigned* __restrict__ KVp, const float* __restrict__ Qbuf,
                              const float* __restrict__ EW2, const float* __restrict__ mu,
                              float* __restrict__ Abuf){
  int d = blockIdx.x; int o = threadIdx.x;
  int r0 = row_ptr[d], r1 = row_ptr[d+1];
  __shared__ float q[HH];
  q[o] = Qbuf[(size_t)d*HH+o]*0.25f;
  __syncthreads();
  int h = o >> 4;
  float qo = q[o];
  float dn0=0.f, dn1=0.f, dn2=0.f, dn3=0.f;
  float ac0=0.f, ac1=0.f, ac2=0.f, ac3=0.f;
  int r = r0;
  for(; r+7 < r1; r += 8){
    int2 m[8]; unsigned u[8]; float e[8]; float p[8];
    #pragma unroll
    for(int j=0;j<8;j++) m[j] = meta[r+j];
    #pragma unroll
    for(int j=0;j<8;j++) u[j] = KVp[(size_t)m[j].x*HH + o];
    #pragma unroll
    for(int j=0;j<8;j++) e[j] = EW2[(m[j].y & 0xffff)*HH + o];
    #pragma unroll
    for(int j=0;j<8;j++) p[j] = qo*(__uint_as_float(u[j]<<16) + e[j]);
    #pragma unroll
    for(int j=0;j<8;j++) p[j] += __shfl_xor(p[j], 1, 64);
    #pragma unroll
    for(int j=0;j<8;j++) p[j] += __shfl_xor(p[j], 2, 64);
    #pragma unroll
    for(int j=0;j<8;j++) p[j] += __shfl_xor(p[j], 4, 64);
    #pragma unroll
    for(int j=0;j<8;j++) p[j] += __shfl_xor(p[j], 8, 64);
    float ex[8];
    #pragma unroll
    for(int j=0;j<8;j++) ex[j] = __expf(p[j]*mu[(m[j].y>>16)*NH+h]);
    dn0 += ex[0]+ex[4]; dn1 += ex[1]+ex[5]; dn2 += ex[2]+ex[6]; dn3 += ex[3]+ex[7];
    ac0 += ex[0]*__uint_as_float(u[0]&0xffff0000u) + ex[4]*__uint_as_float(u[4]&0xffff0000u);
    ac1 += ex[1]*__uint_as_float(u[1]&0xffff0000u) + ex[5]*__uint_as_float(u[5]&0xffff0000u);
    ac2 += ex[2]*__uint_as_float(u[2]&0xffff0000u) + ex[6]*__uint_as_float(u[6]&0xffff0000u);
    ac3 += ex[3]*__uint_as_float(u[3]&0xffff0000u) + ex[7]*__uint_as_float(u[7]&0xffff0000u);
  }
  for(; r+3 < r1; r += 4){
    int2 m[4]; unsigned u[4]; float e[4]; float p[4];
    #pragma unroll
    for(int j=0;j<4;j++) m[j] = meta[r+j];
    #pragma unroll
    for(int j=0;j<4;j++) u[j] = KVp[(size_t)m[j].x*HH + o];
    #pragma unroll
    for(int j=0;j<4;j++) e[j] = EW2[(m[j].y & 0xffff)*HH + o];
    #pragma unroll
    for(int j=0;j<4;j++) p[j] = qo*(__uint_as_float(u[j]<<16) + e[j]);
    #pragma unroll
    for(int j=0;j<4;j++) p[j] += __shfl_xor(p[j], 1, 64);
    #pragma unroll
    for(int j=0;j<4;j++) p[j] += __shfl_xor(p[j], 2, 64);
    #pragma unroll
    for(int j=0;j<4;j++) p[j] += __shfl_xor(p[j], 4, 64);
    #pragma unroll
    for(int j=0;j<4;j++) p[j] += __shfl_xor(p[j], 8, 64);
    float ex[4];
    #pragma unroll
    for(int j=0;j<4;j++) ex[j] = __expf(p[j]*mu[(m[j].y>>16)*NH+h]);
    dn0 += ex[0]; dn1 += ex[1]; dn2 += ex[2]; dn3 += ex[3];
    ac0 += ex[0]*__uint_as_float(u[0]&0xffff0000u);
    ac1 += ex[1]*__uint_as_float(u[1]&0xffff0000u);
    ac2 += ex[2]*__uint_as_float(u[2]&0xffff0000u);
    ac3 += ex[3]*__uint_as_float(u[3]&0xffff0000u);
  }
  for(; r < r1; r++){
    int2 m = meta[r];
    unsigned u = KVp[(size_t)m.x*HH + o];
    float p = qo*(__uint_as_float(u<<16) + EW2[(m.y & 0xffff)*HH + o]);
    p += __shfl_xor(p, 1, 64);
    p += __shfl_xor(p, 2, 64);
    p += __shfl_xor(p, 4, 64);
    p += __shfl_xor(p, 8, 64);
    float ex = __expf(p*mu[(m.y>>16)*NH+h]);
    dn0 += ex; ac0 += ex*__uint_as_float(u&0xffff0000u);
  }
  float dd = (dn0+dn1)+(dn2+dn3), acc = (ac0+ac1)+(ac2+ac3);
  Abuf[(size_t)d*HH + o] = acc / fmaxf(dd, 1e-9f);
}

// ---------------- stage D: token pooling (post-attention) ----------------
__global__ void k_tokexp(const int* tokid, float* abuf, const unsigned* amax, float* aden, float* cnt){
  int t = blockIdx.x*blockDim.x + threadIdx.x;
  if(t >= TT) return;
  int c = tokid[t];
  float ex = __expf(abuf[t]-fdec(amax[c]));
  abuf[t] = ex;
  atomicAdd(&aden[c], ex);
  atomicAdd(&cnt[c], 1.f);
}

__global__ void k_tokagg(const int* tokid, const float* abuf, const float* aden,
                         const float* h2f, float* hist2){
  int t = blockIdx.x; int o = threadIdx.x;
  int c = tokid[t];
  float w = abuf[t]/fmaxf(aden[c],1e-9f);
  int b = t % BB, l = t / BB;
  atomicAdd(&hist2[c*HH+o], w*h2f[(b*LL+l)*HH+o]);
}

// ---------------- parent pooling ----------------
__global__ void k_peagg(const int* pe_p, const int* pe_c, const float* cef, float* psum, float* pcnt){
  int i = blockIdx.x; int o = threadIdx.x;
  int p = pe_p[i], c = pe_c[i];
  atomicAdd(&psum[p*HH+o], cef[c*HH+o]);
  if(o==0) atomicAdd(&pcnt[p], 1.f);
}

__global__ void k_parent(const float* psum, const float* pcnt, float* out){
  int i = blockIdx.x; int o = threadIdx.x;
  out[i*HH+o] = psum[i*HH+o]/fmaxf(pcnt[i],1.f);
}

extern "C" void kernel_launch(void* const* d_in, const int* in_sizes, int n_in,
                              void* d_out, int out_size, void* d_ws, size_t ws_size,
                              hipStream_t stream){
  const int* seq     = (const int*)d_in[0];
  const int* seq_nt  = (const int*)d_in[1];
  const int* dur     = (const int*)d_in[2];
  const int* stime   = (const int*)d_in[3];
  const int* etime   = (const int*)d_in[4];
  const int* g1_nid  = (const int*)d_in[5];
  const int* g1_nt   = (const int*)d_in[6];
  const int* g1_esrc = (const int*)d_in[7];
  const int* g1_edst = (const int*)d_in[8];
  const int* g1_ety  = (const int*)d_in[9];
  const int* g1_ew   = (const int*)d_in[10];
  const int* g2_sel  = (const int*)d_in[11];
  const int* g2_esrc = (const int*)d_in[12];
  const int* g2_edst = (const int*)d_in[13];
  const int* g2_ety  = (const int*)d_in[14];
  const int* g2_ew   = (const int*)d_in[15];
  const int* tok_sel = (const int*)d_in[16];
  const int* g4_esrc = (const int*)d_in[17];
  const int* g4_edst = (const int*)d_in[18];
  const int* g4_ety  = (const int*)d_in[19];
  const int* g4_ew   = (const int*)d_in[20];
  const int* pe_p    = (const int*)d_in[21];
  const int* pe_c    = (const int*)d_in[22];
  const float* emb     = (const float*)d_in[23];
  const float* hist_emb= (const float*)d_in[24];
  const float* edge_emb= (const float*)d_in[25];
  const float* dia_w   = (const float*)d_in[26];
  const float* dia_b   = (const float*)d_in[27];
  const float* t2v_w   = (const float*)d_in[28];
  const float* t2v_b   = (const float*)d_in[29];
  const float* exp_W   = (const float*)d_in[30];
  const float* exp_b   = (const float*)d_in[31];
  const float* l1Wi    = (const float*)d_in[32];
  const float* l1Wh    = (const float*)d_in[33];
  const float* l1b     = (const float*)d_in[34];
  const float* l2Wi    = (const float*)d_in[35];
  const float* l2Wh    = (const float*)d_in[36];
  const float* l2b     = (const float*)d_in[37];
  const float* convK   = (const float*)d_in[38];
  const float* convQ   = (const float*)d_in[39];
  const float* convV   = (const float*)d_in[40];
  const float* convO   = (const float*)d_in[41];
  const float* convE   = (const float*)d_in[42];
  const float* convMu  = (const float*)d_in[43];
  const float* ipW     = (const float*)d_in[44];
  const float* iaW     = (const float*)d_in[45];
  const float* skip    = (const float*)d_in[46];
  float* outp = (float*)d_out;

  // workspace arena
  char* wsp = (char*)d_ws;
  size_t off = 0;
  auto A = [&](size_t nbytes)->char*{ char* p = wsp+off; off += (nbytes+255)&~(size_t)255; return p; };
  float*    srcbuf = (float*)   A((size_t)N1SN*HH*4);
  unsigned* KVp    = (unsigned*)A((size_t)N1SN*HH*4);    // packed bf16 [V|K]
  float*    Qbuf   = (float*)   A((size_t)N1DN*HH*4);
  float*    Abuf   = (float*)   A((size_t)N1DN*HH*4);
  float*    xbuf   = (float*)   A((size_t)TT*HH*4);
  float*    gpre   = (float*)   A((size_t)TT*512*4);
  float*    h1     = (float*)   A((size_t)TT*HH*4);
  float*    dst2   = (float*)   A((size_t)TT*HH*4);
  float*    xg     = (float*)   A((size_t)N1DN*HH*4);
  float*    x2     = (float*)   A((size_t)TT*HH*4);
  float*    h2f    = (float*)   A((size_t)TT*HH*4);
  float*    hist2  = (float*)   A((size_t)CHILDN*HH*4);
  float*    cnt    = (float*)   A((size_t)CHILDN*4);
  float*    abuf   = (float*)   A((size_t)TT*4);
  unsigned* amax   = (unsigned*)A((size_t)CHILDN*4);
  float*    aden   = (float*)   A((size_t)CHILDN*4);
  float*    x3     = (float*)   A((size_t)N1DN*HH*4);
  float*    cef    = (float*)   A((size_t)N4DN*HH*4);
  float*    psum   = (float*)   A((size_t)PARENTN*HH*4);
  float*    pcnt   = (float*)   A((size_t)PARENTN*4);
  float*    sdia   = (float*)   A((size_t)CHILDN*64*4);  // sin(dia_w+dia_b) cols 64..127
  int*      tokid  = (int*)     A((size_t)TT*4);
  int*      toknt  = (int*)     A((size_t)TT*4);
  int*      gnid2  = (int*)     A((size_t)N2N*4);
  int*      idxS1  = (int*)     A((size_t)NTY*N1SN*4);
  int*      idxS2  = (int*)     A((size_t)NTY*N1DN*4);
  int*      idxS3  = (int*)     A((size_t)NTY*N2N*4);
  int*      idxS4  = (int*)     A((size_t)NTY*TT*4);
  int*      idxS5  = (int*)     A((size_t)NTY*N4DN*4);
  int*      cntall = (int*)     A((size_t)5*NTY*4);
  int*      tdesc  = (int*)     A((size_t)3*TDSTRIDE*4);
  int*      tcnt   = (int*)     A((size_t)8*4);
  float*    EW2all = (float*)   A((size_t)4*50*HH*4);
  short*    Wsw    = (short*)   A((size_t)64*16384*2);   // bf16-swizzled conv weights
  short*    WswI   = (short*)   A((size_t)4*16384*2);    // bf16-swizzled ipW
  int*      g1row  = (int*)     A((size_t)(N1DN+1)*4);
  int2*     g1meta = (int2*)    A((size_t)E1N*8);
  int*      g1rank = (int*)     A((size_t)E1N*4);
  int*      g2row  = (int*)     A((size_t)(TT+1)*4);
  int2*     g2meta = (int2*)    A((size_t)E2N*8);
  int*      g2rank = (int*)     A((size_t)E2N*4);
  int*      g4row  = (int*)     A((size_t)(N4DN+1)*4);
  int2*     g4meta = (int2*)    A((size_t)E4N*8);
  int*      g4rank = (int*)     A((size_t)E4N*4);
  int*      icnt1  = (int*)     A((size_t)(N1DN+1)*4);
  int*      icnt2  = (int*)     A((size_t)(TT+1)*4);
  int*      icnt3  = (int*)     A((size_t)(N4DN+1)*4);
  if(off > ws_size) return;  // insufficient scratch: output stays zero

  auto run_conv = [&](int cfg, int gkvq, int gq,
                      const float* src_X, const int* src_nid, const int* srcmap,
                      const int* idx_src, int* cnt_src, int stride_src,
                      const float* q_X, const int* q_map,
                      const float* resid_X, const int* r_map, int ndst,
                      const int* idx_dst, int* cnt_dst, int stride_dst,
                      const int* rowp, const int2* meta,
                      int layer, float* outbuf, float* out2, int relu){
    const bfrag* WB = (const bfrag*)Wsw;
    const bfrag* WK = WB + (size_t)( 0 + layer*4)*2048;
    const bfrag* WV = WB + (size_t)(16 + layer*4)*2048;
    const bfrag* WQ = WB + (size_t)(32 + layer*4)*2048;
    const bfrag* WO = WB + (size_t)(48 + layer*4)*2048;
    const float* MU  = convMu + (size_t)layer*NRL*NH;
    const float* EW2 = EW2all + (size_t)layer*50*HH;
    const int* td = tdesc + (size_t)cfg*TDSTRIDE;
    const int* tc = tcnt + cfg*2;
    k_gemm_kvq<<<gkvq, 256, 0, stream>>>(td, tc, src_X, src_nid, srcmap, sdia,
                                         idx_src, cnt_src, stride_src, WK, WV, KVp,
                                         q_X, q_map, idx_dst, cnt_dst, stride_dst, WQ, Qbuf);
    k_attn_fused8<<<ndst, HH, 0, stream>>>(rowp, meta, KVp, Qbuf, EW2, MU, Abuf);
    k_gemm_t5<<<gq, 256, 0, stream>>>(td, tc, Abuf, idx_dst, cnt_dst, stride_dst, WO,
                                      resid_X, r_map, outbuf, out2, relu);
  };

  // ---- upfront: merged init; stage1 = featx + scatters + rank hists ----
  k_init<<<(CHILDN*HH+255)/256, 256, 0, stream>>>(hist2, cnt, amax, aden, psum, pcnt, cntall,
                                                  icnt1, icnt2, icnt3,
                                                  dia_w, dia_b, sdia,
                                                  convK, convV, convQ, convO, Wsw,
                                                  ipW, WswI,
                                                  edge_emb, convE, EW2all);
  {
    const int G1 = S1_BF + S1_B1 + S1_B2 + S1_B3 + S1_BE1 + S1_BE2 + S1_BE3;
    k_stage1<<<G1, 512, 0, stream>>>(seq, dur, stime, etime, emb, dia_w, dia_b,
                                     t2v_w, t2v_b, exp_W, exp_b, xbuf,
                                     g1_nt, seq_nt, g2_sel, g1_nid,
                                     tokid, toknt, gnid2, cntall,
                                     idxS1, idxS2, idxS5, idxS4, idxS3,
                                     g1_edst, icnt1, g1rank,
                                     g2_edst, icnt2, g2rank,
                                     g4_edst, icnt3, g4rank);
  }
  // ---- stage2 = xwi2(LSTM1) + scan3 + mktiles ----
  k_stage2<<<(TT+15)/16 + 4, 256, 0, stream>>>(xbuf, l1Wi, l1b, gpre, TT, 0,
                                               icnt1, g1row, icnt2, g2row, icnt3, g4row,
                                               cntall, tdesc, tcnt);
  // ---- LSTM1 + CSR fill merged ----
  k_lstm_fused<<<BB + LF_BE1 + LF_BE2 + LF_BE3, 512, 0, stream>>>(gpre, l1Wh, h1, (float*)nullptr,
      g1_edst, g1_esrc, g1_ew, g1_ety, g1row, g1rank, g1meta,
      g2_edst, g2_esrc, g2_ew, g2_ety, g2row, g2rank, g2meta,
      g4_edst, g4_esrc, g4_ew, g4_ety, g4row, g4rank, g4meta);

  // grid bounds (true tile counts are device-side; these are safe upper bounds)
  const int GKVQ_A = (N1SN+N1DN)/32 + 8;   // conv1 / conv3
  const int GKVQ_B = (N2N+TT)/32 + 8;      // conv2
  const int GKVQ_C = (N1DN+N4DN)/32 + 8;   // conv4
  const int GQ_A   = (N1DN+31)/32 + 4;
  const int GQ_B   = (TT+31)/32 + 4;
  const int GQ_C   = (N4DN+31)/32 + 4;

  // ---- conv1 on g1 (src/dst features gathered from emb via g1_nid in the gemms) ----
  run_conv(0, GKVQ_A, GQ_A,
           emb, g1_nid, g1_nid, idxS1, cntall+0*NTY, N1SN,
           emb, g1_nid,
           emb, g1_nid, N1DN, idxS2, cntall+1*NTY, N1DN,
           g1row, g1meta, 0, xg, (float*)nullptr, 1);

  // ---- conv2 on g2 (src features gathered from xg via g2_sel in the gemm) ----
  k_dst2<<<TT, HH, 0, stream>>>(tok_sel, xg, h1, dst2);
  run_conv(1, GKVQ_B, GQ_B,
           xg, gnid2, g2_sel, idxS3, cntall+2*NTY, N2N,
           dst2, (const int*)nullptr,
           dst2, (const int*)nullptr, TT, idxS4, cntall+3*NTY, TT,
           g2row, g2meta, 1, x2, (float*)nullptr, 1);

  // ---- LSTM2 (h2 is output 0); x2 read directly with permuted layout ----
  k_stage2<<<(TT+15)/16, 256, 0, stream>>>(x2, l2Wi, l2b, gpre, TT, 1,
                                           icnt1, g1row, icnt2, g2row, icnt3, g4row,
                                           cntall, tdesc, tcnt);
  k_lstm_fused<<<BB, 512, 0, stream>>>(gpre, l2Wh, h2f, outp,
      g1_edst, g1_esrc, g1_ew, g1_ety, g1row, g1rank, g1meta,
      g2_edst, g2_esrc, g2_ew, g2_ety, g2row, g2rank, g2meta,
      g4_edst, g4_esrc, g4_ew, g4_ety, g4row, g4rank, g4meta);

  // ---- stage D: token attention pooling -> hist2 (MFMA tokatt; histfix fused in k_x0) ----
  k_tokatt2<<<GQ_B, 256, 0, stream>>>(tdesc + (size_t)1*TDSTRIDE, tcnt + 2,
                                      h2f, idxS4, cntall+3*NTY,
                                      (const bfrag*)WswI, iaW, tokid, abuf, amax);
  k_tokexp<<<(TT+255)/256, 256, 0, stream>>>(tokid, abuf, amax, aden, cnt);
  k_tokagg<<<TT, HH, 0, stream>>>(tokid, abuf, aden, h2f, hist2);

  // ---- conv3 on g1 with skip-mixed input (g1 CSR + scatters + tiles reused) ----
  k_x0<<<N1SN, HH, 0, stream>>>(g1_nid, g1_nt, emb, hist2, cnt, hist_emb, skip, srcbuf);
  run_conv(0, GKVQ_A, GQ_A,
           srcbuf, g1_nid, (const int*)nullptr, idxS1, cntall+0*NTY, N1SN,
           srcbuf, (const int*)nullptr,
           srcbuf, (const int*)nullptr, N1DN, idxS2, cntall+1*NTY, N1DN,
           g1row, g1meta, 2, x3, (float*)nullptr, 1);

  // ---- conv4 on g4 (child_embed = output 1, no relu) ----
  run_conv(2, GKVQ_C, GQ_C,
           x3, g1_nid, (const int*)nullptr, idxS2, cntall+1*NTY, N1DN,
           x3, (const int*)nullptr,
           x3, (const int*)nullptr, N4DN, idxS5, cntall+4*NTY, N4DN,
           g4row, g4meta, 3, cef, outp + (size_t)TT*HH, 0);

  // ---- parent pooling (output 2) ----
  k_peagg<<<EC2PN, HH, 0, stream>>>(pe_p, pe_c, cef, psum, pcnt);
  k_parent<<<PARENTN, HH, 0, stream>>>(psum, pcnt, outp + (size_t)TT*HH + (size_t)N4DN*HH);
}